// Round 5
// baseline (1258.095 us; speedup 1.0000x reference)
//
#include <hip/hip_runtime.h>
#include <math.h>

#define N_NODES 100000
#define N_EDGES 3200000
#define NBLK_SCAN 98   // ceil(100000/1024)
#define NBINS 782      // ceil(100000/128), 128 nodes per bin
#define NSUB  (NBINS*8)

// ---------------- workspace layout ----------------
constexpr size_t al512(size_t x){ return (x + 511) & ~size_t(511); }
constexpr size_t o_wp   = 0;                                          // int[N]  write-ptrs / histogram
constexpr size_t o_off  = al512(o_wp   + (size_t)N_NODES*4);          // int[N+1] CSR offsets
constexpr size_t o_bs   = al512(o_off  + ((size_t)N_NODES+1)*4);      // int[128] scan block sums
constexpr size_t o_bwp  = al512(o_bs   + 128*4);                      // int[NSUB] sub-bin counts -> write ptrs
constexpr size_t o_srcp = al512(o_bwp  + (size_t)NSUB*4);             // int[E] src permuted by dst
constexpr size_t o_epk  = al512(o_srcp + (size_t)N_EDGES*4);          // uint2[E] {e2:f32, (e1|e0):bf16x2}; DEAD after kinject
constexpr size_t o_U1   = al512(o_epk  + (size_t)N_EDGES*8);          // f[N*16]
constexpr size_t o_U2   = al512(o_U1   + (size_t)N_NODES*16*4);       // f[N*64]
constexpr size_t o_U3   = o_U2 + (size_t)N_NODES*64*4;                // f[N*64] (contiguous after U2; 25.6e6 % 512 == 0)
constexpr size_t o_gs   = al512(o_U3   + (size_t)N_NODES*64*4);       // f[N] gate sums
constexpr size_t o_h1   = al512(o_gs   + (size_t)N_NODES*4);          // f[N*16]
constexpr size_t o_m1   = al512(o_h1   + (size_t)N_NODES*16*4);       // f[N*16]
constexpr size_t o_h3   = al512(o_m1   + (size_t)N_NODES*16*4);       // f[N*64] own region
// aliases into dead regions (sequential-stream liveness):
constexpr size_t o_rec  = o_U2;    // uint4[E] bin-staged records (51.2 MB = U2+U3 exactly); dead once kinject writes U2/U3
constexpr size_t o_h2   = o_epk;   // epk dead after kinject; h2 = N*64*4 = 25.6 MB = epk size exactly
constexpr size_t o_m2   = o_U2;    // U2 dead after kdense1
constexpr size_t o_m3   = o_U2;    // m2 dead after kdense2

#define BN_RSQRT 0.9999950000374997f   // 1/sqrt(1+1e-5)

__device__ __forceinline__ float4 ld4(const float* p){ return *(const float4*)p; }
__device__ __forceinline__ float fc(const float4& v, int i){ return ((const float*)&v)[i]; }

// f32 -> bf16 bits, round-to-nearest-even (inputs are finite normals)
__device__ __forceinline__ unsigned f2bf(float x){
    unsigned u = __float_as_uint(x);
    u += 0x7fffu + ((u >> 16) & 1u);
    return u >> 16;
}

// ---------------- CSR build ----------------
__global__ void khist(const int* __restrict__ dst, int* __restrict__ wp){
    int i = blockIdx.x*256 + threadIdx.x;
    if(i < N_EDGES) atomicAdd(&wp[dst[i]], 1);
}

// per-(bin, xcd-key) histogram; xcd key = (block index % 8) of the kbin1 writer
__global__ void khist2(const int* __restrict__ dst, int* __restrict__ bwp){
    int i = blockIdx.x*256 + threadIdx.x;
    if(i < N_EDGES){
        int b = dst[i] >> 7;
        atomicAdd(&bwp[b*8 + ((i >> 8) & 7)], 1);
    }
}

__global__ void kscanA(const int* __restrict__ cnt, int* __restrict__ bs){
    __shared__ int s[256];
    int t = threadIdx.x;
    int base = blockIdx.x*1024 + t*4;
    int v = 0;
    #pragma unroll
    for(int k=0;k<4;k++){ int i = base+k; if(i < N_NODES) v += cnt[i]; }
    s[t] = v; __syncthreads();
    for(int off=128; off>0; off>>=1){ if(t<off) s[t] += s[t+off]; __syncthreads(); }
    if(t==0) bs[blockIdx.x] = s[0];
}

__global__ void kscanB(int* __restrict__ bs){
    __shared__ int s[128];
    int t = threadIdx.x;
    int v = (t < NBLK_SCAN) ? bs[t] : 0;
    s[t] = v; __syncthreads();
    for(int off=1; off<128; off<<=1){
        int add = (t>=off) ? s[t-off] : 0;
        __syncthreads(); s[t] += add; __syncthreads();
    }
    bs[t] = (t==0) ? 0 : s[t-1];
}

__global__ void kscanC(const int* __restrict__ cnt, const int* __restrict__ bs,
                       int* __restrict__ offs){
    __shared__ int s[256];
    int t = threadIdx.x;
    int base = blockIdx.x*1024 + t*4;
    int c0=0,c1=0,c2=0,c3=0;
    if(base+0 < N_NODES) c0 = cnt[base+0];
    if(base+1 < N_NODES) c1 = cnt[base+1];
    if(base+2 < N_NODES) c2 = cnt[base+2];
    if(base+3 < N_NODES) c3 = cnt[base+3];
    int v = c0+c1+c2+c3;
    s[t] = v; __syncthreads();
    for(int off=1; off<256; off<<=1){
        int add = (t>=off) ? s[t-off] : 0;
        __syncthreads(); s[t] += add; __syncthreads();
    }
    int ebase = bs[blockIdx.x] + ((t==0) ? 0 : s[t-1]);
    int run = 0;
    run += c0; if(base+0 < N_NODES) offs[base+1] = ebase+run;
    run += c1; if(base+1 < N_NODES) offs[base+2] = ebase+run;
    run += c2; if(base+2 < N_NODES) offs[base+3] = ebase+run;
    run += c3; if(base+3 < N_NODES) offs[base+4] = ebase+run;
    if(blockIdx.x==0 && t==0) offs[0] = 0;
}

// convert sub-bin counts (bwp) into write pointers using CSR offs (in place)
__global__ void kbinoff(const int* __restrict__ offs, int* __restrict__ bwp){
    int b = blockIdx.x*256 + threadIdx.x;
    if(b >= NBINS) return;
    int base = offs[b*128];
    int c[8];
    #pragma unroll
    for(int x=0;x<8;x++) c[x] = bwp[b*8+x];
    #pragma unroll
    for(int x=0;x<8;x++){ bwp[b*8+x] = base; base += c[x]; }
}

// pass 1: scatter edges into bin-contiguous staging records.
// Sub-bin per writer-XCD-key keeps each frontier line written by one XCD -> dense writes.
__global__ void kbin1(const int* __restrict__ src, const int* __restrict__ dst,
                      const float* __restrict__ ea,
                      int* __restrict__ bwp, uint4* __restrict__ rec){
    int i = blockIdx.x*256 + threadIdx.x;
    if(i >= N_EDGES) return;
    int d = dst[i];
    float e0 = ea[i*3+0], e1 = ea[i*3+1], e2 = ea[i*3+2];
    int sub = (d >> 7)*8 + ((i >> 8) & 7);
    int slot = atomicAdd(&bwp[sub], 1);
    rec[slot] = make_uint4((unsigned)src[i], (f2bf(e1)<<16) | f2bf(e0),
                           __float_as_uint(e2), (unsigned)d);
}

// pass 2: one workgroup per bin; place staged records at exact CSR slots.
// All writes land in this bin's ~48 KB final window -> stays L2-resident.
__global__ void kbin2(const uint4* __restrict__ rec, const int* __restrict__ offs,
                      int* __restrict__ wp, int* __restrict__ srcp,
                      uint2* __restrict__ epk){
    int b = blockIdx.x;
    int beg = offs[b*128];
    int hi  = (b+1)*128; if(hi > N_NODES) hi = N_NODES;
    int end = offs[hi];
    for(int s = beg + threadIdx.x; s < end; s += 256){
        uint4 r = rec[s];
        int f = atomicAdd(&wp[r.w], 1);
        srcp[f] = (int)r.x;
        epk[f]  = make_uint2(r.z, r.y);
    }
}

// ---------------- fused 3-inject edge accumulation (one wave per node) ----------------
struct InjW { float wa1,wb1,wc1,bb1, wa2,wb2,wc2,bb2, wa3,wb3,wc3,bb3; };

__device__ __forceinline__ void edge_acc(unsigned w0, unsigned w1, const InjW& W,
                                         float& a1, float& a2, float& a3, float& g){
    float e2 = __uint_as_float(w0);
    float e0 = __uint_as_float(w1 << 16);
    float e1 = __uint_as_float(w1 & 0xffff0000u);
    float gate = __builtin_amdgcn_rcpf(1.f + __expf(-e2));
    a1 += fmaxf(fmaf(e2,W.wc1,fmaf(e1,W.wb1,fmaf(e0,W.wa1,W.bb1))),0.f)*gate;
    a2 += fmaxf(fmaf(e2,W.wc2,fmaf(e1,W.wb2,fmaf(e0,W.wa2,W.bb2))),0.f)*gate;
    a3 += fmaxf(fmaf(e2,W.wc3,fmaf(e1,W.wb3,fmaf(e0,W.wa3,W.bb3))),0.f)*gate;
    g  += gate;
}

__global__ void kinject(const uint2* __restrict__ epk, const int* __restrict__ offs,
                        const float* __restrict__ w11, const float* __restrict__ b11,
                        const float* __restrict__ w12, const float* __restrict__ b12,
                        const float* __restrict__ w13, const float* __restrict__ b13,
                        float* __restrict__ U1, float* __restrict__ U2,
                        float* __restrict__ U3, float* __restrict__ gsum){
    int gid = blockIdx.x*blockDim.x + threadIdx.x;
    int node = gid >> 6;
    if(node >= N_NODES) return;
    int lane = threadIdx.x & 63;
    int l16  = lane & 15;
    InjW W;
    W.wa1=w11[l16];  W.wb1=w11[16+l16];  W.wc1=w11[32+l16];  W.bb1=b11[l16];
    W.wa2=w12[lane]; W.wb2=w12[64+lane]; W.wc2=w12[128+lane]; W.bb2=b12[lane];
    W.wa3=w13[lane]; W.wb3=w13[64+lane]; W.wc3=w13[128+lane]; W.bb3=b13[lane];
    int beg = offs[node], end = offs[node+1];
    float a1=0.f, a2=0.f, a3=0.f, g=0.f;
    int e = beg;
    if((e & 1) && e < end){
        uint2 p = epk[e];
        edge_acc(p.x, p.y, W, a1, a2, a3, g);
        ++e;
    }
    for(; e+2<=end; e+=2){
        uint4 p = *(const uint4*)(epk + e);
        edge_acc(p.x, p.y, W, a1, a2, a3, g);
        edge_acc(p.z, p.w, W, a1, a2, a3, g);
    }
    if(e < end){
        uint2 p = epk[e];
        edge_acc(p.x, p.y, W, a1, a2, a3, g);
    }
    U2[(size_t)node*64 + lane] = a2;
    U3[(size_t)node*64 + lane] = a3;
    if(lane < 16) U1[node*16 + l16] = a1;
    if(lane == 0) gsum[node] = g;
}

// ---------------- SAGE mean gathers (one wave per node) ----------------
__global__ void kgather16(const float* __restrict__ h, const int* __restrict__ srcp,
                          const int* __restrict__ offs, float* __restrict__ m){
    int gid = blockIdx.x*blockDim.x + threadIdx.x;
    int node = gid >> 6;
    if(node >= N_NODES) return;
    int lane = threadIdx.x & 63;
    int q = lane >> 4, d = lane & 15;
    int beg = offs[node], end = offs[node+1];
    float acc = 0.f;
    for(int e=beg+q; e<end; e+=4) acc += h[(size_t)srcp[e]*16 + d];
    acc += __shfl_down(acc, 32);
    acc += __shfl_down(acc, 16);
    if(lane < 16){
        float c = fmaxf((float)(end-beg), 1.f);
        m[node*16 + lane] = acc / c;
    }
}

__global__ void kgather64(const float* __restrict__ h, const int* __restrict__ srcp,
                          const int* __restrict__ offs, float* __restrict__ m){
    int gid = blockIdx.x*blockDim.x + threadIdx.x;
    int node = gid >> 6;
    if(node >= N_NODES) return;
    int lane = threadIdx.x & 63;
    int beg = offs[node], end = offs[node+1];
    float acc = 0.f;
    int e = beg;
    for(; e+4<=end; e+=4){
        int s0=srcp[e], s1=srcp[e+1], s2=srcp[e+2], s3=srcp[e+3];
        acc += h[(size_t)s0*64 + lane];
        acc += h[(size_t)s1*64 + lane];
        acc += h[(size_t)s2*64 + lane];
        acc += h[(size_t)s3*64 + lane];
    }
    for(; e<end; ++e) acc += h[(size_t)srcp[e]*64 + lane];
    float c = fmaxf((float)(end-beg), 1.f);
    m[(size_t)node*64 + lane] = acc / c;
}

// ---------------- dense per-node kernels (LDS weights + 4x4 register tiles) ----------------

// h1 = x + U1 @ w2_1 + gs * b2_1            [N,16]
__global__ __launch_bounds__(256) void kdense0(const float* __restrict__ x, const float* __restrict__ U1,
                        const float* __restrict__ gs, const float* __restrict__ w2,
                        const float* __restrict__ b2, float* __restrict__ h1){
    __shared__ float sw[256];
    int t = threadIdx.x;
    sw[t] = w2[t];
    __syncthreads();
    int idx = blockIdx.x*256 + t;
    int n = idx >> 4, j = idx & 15;
    float acc = x[idx] + gs[n]*b2[j];
    const float4* row = (const float4*)(U1 + n*16);
    #pragma unroll
    for(int i4=0;i4<4;i4++){
        float4 r = row[i4];
        acc += r.x*sw[(i4*4+0)*16 + j];
        acc += r.y*sw[(i4*4+1)*16 + j];
        acc += r.z*sw[(i4*4+2)*16 + j];
        acc += r.w*sw[(i4*4+3)*16 + j];
    }
    h1[idx] = acc;
}

// h2 = relu(bn1(m1@wl + h1@wr + bl)) + U2@w2_2 + gs*b2_2    [N,64]
__global__ __launch_bounds__(256) void kdense1(const float* __restrict__ m1, const float* __restrict__ h1,
                        const float* __restrict__ U2, const float* __restrict__ gs,
                        const float* __restrict__ wl, const float* __restrict__ bl,
                        const float* __restrict__ wr,
                        const float* __restrict__ w2, const float* __restrict__ b2,
                        const float* __restrict__ bnw, const float* __restrict__ bnb,
                        float* __restrict__ h2){
    __shared__ float4 swl[16*16];
    __shared__ float4 swr[16*16];
    __shared__ float4 sw2[64*16];
    int t = threadIdx.x;
    swl[t] = ((const float4*)wl)[t];
    swr[t] = ((const float4*)wr)[t];
    #pragma unroll
    for(int k=0;k<4;k++) sw2[t + 256*k] = ((const float4*)w2)[t + 256*k];
    __syncthreads();

    int w = t>>6, l = t&63;
    int jg = l&15, j0 = jg*4, ng = l>>4;
    int nb = blockIdx.x*64 + w*16 + ng*4;
    int nn[4];
    #pragma unroll
    for(int k=0;k<4;k++) nn[k] = (nb+k < N_NODES) ? nb+k : N_NODES-1;

    float a[4][4], b[4][4];
    float4 blv = ld4(bl + j0);
    float4 b2v = ld4(b2 + j0);
    #pragma unroll
    for(int k=0;k<4;k++){
        float g = gs[nn[k]];
        a[k][0]=blv.x; a[k][1]=blv.y; a[k][2]=blv.z; a[k][3]=blv.w;
        b[k][0]=g*b2v.x; b[k][1]=g*b2v.y; b[k][2]=g*b2v.z; b[k][3]=g*b2v.w;
    }
    #pragma unroll
    for(int i=0;i<16;i+=4){
        float4 rm[4], rh[4];
        #pragma unroll
        for(int k=0;k<4;k++){ rm[k] = ld4(m1 + nn[k]*16 + i); rh[k] = ld4(h1 + nn[k]*16 + i); }
        #pragma unroll
        for(int ii=0;ii<4;ii++){
            float4 wL = swl[(i+ii)*16 + jg];
            float4 wR = swr[(i+ii)*16 + jg];
            #pragma unroll
            for(int k=0;k<4;k++){
                float vm = fc(rm[k],ii), vh = fc(rh[k],ii);
                a[k][0] = fmaf(vm,wL.x, fmaf(vh,wR.x, a[k][0]));
                a[k][1] = fmaf(vm,wL.y, fmaf(vh,wR.y, a[k][1]));
                a[k][2] = fmaf(vm,wL.z, fmaf(vh,wR.z, a[k][2]));
                a[k][3] = fmaf(vm,wL.w, fmaf(vh,wR.w, a[k][3]));
            }
        }
    }
    #pragma unroll 4
    for(int i=0;i<64;i+=4){
        float4 ru[4];
        #pragma unroll
        for(int k=0;k<4;k++) ru[k] = ld4(U2 + (size_t)nn[k]*64 + i);
        #pragma unroll
        for(int ii=0;ii<4;ii++){
            float4 wv = sw2[(i+ii)*16 + jg];
            #pragma unroll
            for(int k=0;k<4;k++){
                float vu = fc(ru[k],ii);
                b[k][0] = fmaf(vu,wv.x,b[k][0]);
                b[k][1] = fmaf(vu,wv.y,b[k][1]);
                b[k][2] = fmaf(vu,wv.z,b[k][2]);
                b[k][3] = fmaf(vu,wv.w,b[k][3]);
            }
        }
    }
    float4 bw = ld4(bnw + j0), bb = ld4(bnb + j0);
    #pragma unroll
    for(int k=0;k<4;k++){
        if(nb+k < N_NODES){
            float4 o;
            o.x = fmaxf(a[k][0]*(bw.x*BN_RSQRT)+bb.x,0.f) + b[k][0];
            o.y = fmaxf(a[k][1]*(bw.y*BN_RSQRT)+bb.y,0.f) + b[k][1];
            o.z = fmaxf(a[k][2]*(bw.z*BN_RSQRT)+bb.z,0.f) + b[k][2];
            o.w = fmaxf(a[k][3]*(bw.w*BN_RSQRT)+bb.w,0.f) + b[k][3];
            *(float4*)(h2 + (size_t)(nb+k)*64 + j0) = o;
        }
    }
}

// h3 = relu(bn2(m2@wl + h2@wr + bl)) + U3@w2_3 + gs*b2_3    [N,64]
__global__ __launch_bounds__(256) void kdense2(const float* __restrict__ m2, const float* __restrict__ h2,
                        const float* __restrict__ U3, const float* __restrict__ gs,
                        const float* __restrict__ wl, const float* __restrict__ bl,
                        const float* __restrict__ wr,
                        const float* __restrict__ w2, const float* __restrict__ b2,
                        const float* __restrict__ bnw, const float* __restrict__ bnb,
                        float* __restrict__ h3){
    __shared__ float4 swl[64*16];
    __shared__ float4 swr[64*16];
    __shared__ float4 sw2[64*16];
    int t = threadIdx.x;
    #pragma unroll
    for(int k=0;k<4;k++){
        swl[t + 256*k] = ((const float4*)wl)[t + 256*k];
        swr[t + 256*k] = ((const float4*)wr)[t + 256*k];
        sw2[t + 256*k] = ((const float4*)w2)[t + 256*k];
    }
    __syncthreads();

    int w = t>>6, l = t&63;
    int jg = l&15, j0 = jg*4, ng = l>>4;
    int nb = blockIdx.x*64 + w*16 + ng*4;
    int nn[4];
    #pragma unroll
    for(int k=0;k<4;k++) nn[k] = (nb+k < N_NODES) ? nb+k : N_NODES-1;

    float a[4][4], b[4][4];
    float4 blv = ld4(bl + j0);
    float4 b2v = ld4(b2 + j0);
    #pragma unroll
    for(int k=0;k<4;k++){
        float g = gs[nn[k]];
        a[k][0]=blv.x; a[k][1]=blv.y; a[k][2]=blv.z; a[k][3]=blv.w;
        b[k][0]=g*b2v.x; b[k][1]=g*b2v.y; b[k][2]=g*b2v.z; b[k][3]=g*b2v.w;
    }
    #pragma unroll 4
    for(int i=0;i<64;i+=4){
        float4 rm[4], rh[4];
        #pragma unroll
        for(int k=0;k<4;k++){ rm[k] = ld4(m2 + (size_t)nn[k]*64 + i); rh[k] = ld4(h2 + (size_t)nn[k]*64 + i); }
        #pragma unroll
        for(int ii=0;ii<4;ii++){
            float4 wL = swl[(i+ii)*16 + jg];
            float4 wR = swr[(i+ii)*16 + jg];
            #pragma unroll
            for(int k=0;k<4;k++){
                float vm = fc(rm[k],ii), vh = fc(rh[k],ii);
                a[k][0] = fmaf(vm,wL.x, fmaf(vh,wR.x, a[k][0]));
                a[k][1] = fmaf(vm,wL.y, fmaf(vh,wR.y, a[k][1]));
                a[k][2] = fmaf(vm,wL.z, fmaf(vh,wR.z, a[k][2]));
                a[k][3] = fmaf(vm,wL.w, fmaf(vh,wR.w, a[k][3]));
            }
        }
    }
    #pragma unroll 4
    for(int i=0;i<64;i+=4){
        float4 ru[4];
        #pragma unroll
        for(int k=0;k<4;k++) ru[k] = ld4(U3 + (size_t)nn[k]*64 + i);
        #pragma unroll
        for(int ii=0;ii<4;ii++){
            float4 wv = sw2[(i+ii)*16 + jg];
            #pragma unroll
            for(int k=0;k<4;k++){
                float vu = fc(ru[k],ii);
                b[k][0] = fmaf(vu,wv.x,b[k][0]);
                b[k][1] = fmaf(vu,wv.y,b[k][1]);
                b[k][2] = fmaf(vu,wv.z,b[k][2]);
                b[k][3] = fmaf(vu,wv.w,b[k][3]);
            }
        }
    }
    float4 bw = ld4(bnw + j0), bb = ld4(bnb + j0);
    #pragma unroll
    for(int k=0;k<4;k++){
        if(nb+k < N_NODES){
            float4 o;
            o.x = fmaxf(a[k][0]*(bw.x*BN_RSQRT)+bb.x,0.f) + b[k][0];
            o.y = fmaxf(a[k][1]*(bw.y*BN_RSQRT)+bb.y,0.f) + b[k][1];
            o.z = fmaxf(a[k][2]*(bw.z*BN_RSQRT)+bb.z,0.f) + b[k][2];
            o.w = fmaxf(a[k][3]*(bw.w*BN_RSQRT)+bb.w,0.f) + b[k][3];
            *(float4*)(h3 + (size_t)(nb+k)*64 + j0) = o;
        }
    }
}

// out = relu(bn3(m3@wl + h3@wr + bl))        [N,32]
__global__ __launch_bounds__(256) void kdense3(const float* __restrict__ m3, const float* __restrict__ h3,
                        const float* __restrict__ wl, const float* __restrict__ bl,
                        const float* __restrict__ wr,
                        const float* __restrict__ bnw, const float* __restrict__ bnb,
                        float* __restrict__ out){
    __shared__ float4 swl[64*8];
    __shared__ float4 swr[64*8];
    int t = threadIdx.x;
    #pragma unroll
    for(int k=0;k<2;k++){
        swl[t + 256*k] = ((const float4*)wl)[t + 256*k];
        swr[t + 256*k] = ((const float4*)wr)[t + 256*k];
    }
    __syncthreads();

    int w = t>>6, l = t&63;
    int jg = l&7, j0 = jg*4, ng = l>>3;
    int nb = blockIdx.x*128 + w*32 + ng*4;
    int nn[4];
    #pragma unroll
    for(int k=0;k<4;k++) nn[k] = (nb+k < N_NODES) ? nb+k : N_NODES-1;

    float a[4][4];
    float4 blv = ld4(bl + j0);
    #pragma unroll
    for(int k=0;k<4;k++){ a[k][0]=blv.x; a[k][1]=blv.y; a[k][2]=blv.z; a[k][3]=blv.w; }
    #pragma unroll 4
    for(int i=0;i<64;i+=4){
        float4 rm[4], rh[4];
        #pragma unroll
        for(int k=0;k<4;k++){ rm[k] = ld4(m3 + (size_t)nn[k]*64 + i); rh[k] = ld4(h3 + (size_t)nn[k]*64 + i); }
        #pragma unroll
        for(int ii=0;ii<4;ii++){
            float4 wL = swl[(i+ii)*8 + jg];
            float4 wR = swr[(i+ii)*8 + jg];
            #pragma unroll
            for(int k=0;k<4;k++){
                float vm = fc(rm[k],ii), vh = fc(rh[k],ii);
                a[k][0] = fmaf(vm,wL.x, fmaf(vh,wR.x, a[k][0]));
                a[k][1] = fmaf(vm,wL.y, fmaf(vh,wR.y, a[k][1]));
                a[k][2] = fmaf(vm,wL.z, fmaf(vh,wR.z, a[k][2]));
                a[k][3] = fmaf(vm,wL.w, fmaf(vh,wR.w, a[k][3]));
            }
        }
    }
    float4 bw = ld4(bnw + j0), bb = ld4(bnb + j0);
    #pragma unroll
    for(int k=0;k<4;k++){
        if(nb+k < N_NODES){
            float4 o;
            o.x = fmaxf(a[k][0]*(bw.x*BN_RSQRT)+bb.x,0.f);
            o.y = fmaxf(a[k][1]*(bw.y*BN_RSQRT)+bb.y,0.f);
            o.z = fmaxf(a[k][2]*(bw.z*BN_RSQRT)+bb.z,0.f);
            o.w = fmaxf(a[k][3]*(bw.w*BN_RSQRT)+bb.w,0.f);
            *(float4*)(out + (size_t)(nb+k)*32 + j0) = o;
        }
    }
}

// ---------------- launch ----------------
extern "C" void kernel_launch(void* const* d_in, const int* in_sizes, int n_in,
                              void* d_out, int out_size, void* d_ws, size_t ws_size,
                              hipStream_t stream){
    const float* x    = (const float*)d_in[0];
    const int*   ei   = (const int*)  d_in[1];
    const float* ea   = (const float*)d_in[2];
    const float* i1w1 = (const float*)d_in[3];
    const float* i1b1 = (const float*)d_in[4];
    const float* i1w2 = (const float*)d_in[5];
    const float* i1b2 = (const float*)d_in[6];
    const float* i2w1 = (const float*)d_in[7];
    const float* i2b1 = (const float*)d_in[8];
    const float* i2w2 = (const float*)d_in[9];
    const float* i2b2 = (const float*)d_in[10];
    const float* i3w1 = (const float*)d_in[11];
    const float* i3b1 = (const float*)d_in[12];
    const float* i3w2 = (const float*)d_in[13];
    const float* i3b2 = (const float*)d_in[14];
    const float* c1wl = (const float*)d_in[15];
    const float* c1bl = (const float*)d_in[16];
    const float* c1wr = (const float*)d_in[17];
    const float* c2wl = (const float*)d_in[18];
    const float* c2bl = (const float*)d_in[19];
    const float* c2wr = (const float*)d_in[20];
    const float* c3wl = (const float*)d_in[21];
    const float* c3bl = (const float*)d_in[22];
    const float* c3wr = (const float*)d_in[23];
    const float* bn1w = (const float*)d_in[24];
    const float* bn1b = (const float*)d_in[25];
    const float* bn2w = (const float*)d_in[26];
    const float* bn2b = (const float*)d_in[27];
    const float* bn3w = (const float*)d_in[28];
    const float* bn3b = (const float*)d_in[29];

    char* ws = (char*)d_ws;
    int*    wp   = (int*)   (ws + o_wp);
    int*    offs = (int*)   (ws + o_off);
    int*    bs   = (int*)   (ws + o_bs);
    int*    bwp  = (int*)   (ws + o_bwp);
    int*    srcp = (int*)   (ws + o_srcp);
    uint2*  epk  = (uint2*) (ws + o_epk);
    uint4*  rec  = (uint4*) (ws + o_rec);
    float*  U1   = (float*) (ws + o_U1);
    float*  U2   = (float*) (ws + o_U2);
    float*  U3   = (float*) (ws + o_U3);
    float*  gs   = (float*) (ws + o_gs);
    float*  h1   = (float*) (ws + o_h1);
    float*  m1   = (float*) (ws + o_m1);
    float*  h2   = (float*) (ws + o_h2);
    float*  m2   = (float*) (ws + o_m2);
    float*  h3   = (float*) (ws + o_h3);
    float*  m3   = (float*) (ws + o_m3);

    const int* src = ei;              // edge_index[0]
    const int* dst = ei + N_EDGES;    // edge_index[1]

    // CSR build
    hipMemsetAsync(wp,  0, (size_t)N_NODES*4, stream);
    hipMemsetAsync(bwp, 0, (size_t)NSUB*4,    stream);
    khist   <<<N_EDGES/256, 256, 0, stream>>>(dst, wp);
    khist2  <<<N_EDGES/256, 256, 0, stream>>>(dst, bwp);
    kscanA  <<<NBLK_SCAN,   256, 0, stream>>>(wp, bs);
    kscanB  <<<1,           128, 0, stream>>>(bs);
    kscanC  <<<NBLK_SCAN,   256, 0, stream>>>(wp, bs, offs);
    kbinoff <<<(NBINS+255)/256, 256, 0, stream>>>(offs, bwp);
    // binned two-pass scatter (dense write frontiers)
    kbin1   <<<N_EDGES/256, 256, 0, stream>>>(src, dst, ea, bwp, rec);
    hipMemcpyAsync(wp, offs, (size_t)N_NODES*4, hipMemcpyDeviceToDevice, stream);
    kbin2   <<<NBINS, 256, 0, stream>>>(rec, offs, wp, srcp, epk);

    // fused 3x inject edge accumulation (sequential epk reads, gate recomputed)
    kinject <<<N_NODES/4, 256, 0, stream>>>(epk, offs,
                                            i1w1, i1b1, i2w1, i2b1, i3w1, i3b1,
                                            U1, U2, U3, gs);
    // layer 1
    kdense0 <<<N_NODES*16/256, 256, 0, stream>>>(x, U1, gs, i1w2, i1b2, h1);
    kgather16<<<N_NODES/4, 256, 0, stream>>>(h1, srcp, offs, m1);
    kdense1 <<<(N_NODES+63)/64, 256, 0, stream>>>(m1, h1, U2, gs,
                                                 c1wl, c1bl, c1wr, i2w2, i2b2,
                                                 bn1w, bn1b, h2);
    // layer 2
    kgather64<<<N_NODES/4, 256, 0, stream>>>(h2, srcp, offs, m2);
    kdense2 <<<(N_NODES+63)/64, 256, 0, stream>>>(m2, h2, U3, gs,
                                                 c2wl, c2bl, c2wr, i3w2, i3b2,
                                                 bn2w, bn2b, h3);
    // layer 3
    kgather64<<<N_NODES/4, 256, 0, stream>>>(h3, srcp, offs, m3);
    kdense3 <<<(N_NODES+127)/128, 256, 0, stream>>>(m3, h3, c3wl, c3bl, c3wr,
                                                 bn3w, bn3b, (float*)d_out);
}

// Round 6
// 944.267 us; speedup vs baseline: 1.3324x; 1.3324x over previous
//
#include <hip/hip_runtime.h>
#include <math.h>

#define N_NODES 100000
#define N_EDGES 3200000
#define NBLK_SCAN 98   // ceil(100000/1024)
#define NB 391         // bins of 256 nodes: ceil(100000/256)
#define CHUNK 4096
#define NCHUNK 782     // ceil(3200000/4096)
#define CAPB 10240     // pass-B LDS capacity (mean 8184, +22 sigma)

// ---------------- workspace layout ----------------
constexpr size_t al512(size_t x){ return (x + 511) & ~size_t(511); }
constexpr size_t o_wp   = 0;                                          // int[N]  histogram
constexpr size_t o_off  = al512(o_wp   + (size_t)N_NODES*4);          // int[N+1] CSR offsets
constexpr size_t o_bs   = al512(o_off  + ((size_t)N_NODES+1)*4);      // int[128] scan block sums
constexpr size_t o_gb   = al512(o_bs   + 128*4);                      // int[512] per-bin global write base
constexpr size_t o_srcp = al512(o_gb   + 512*4);                      // int[E] src permuted by dst
constexpr size_t o_epk  = al512(o_srcp + (size_t)N_EDGES*4);          // uint2[E] {e2:f32,(e1|e0):bf16x2}; DEAD after kinject
constexpr size_t o_U1   = al512(o_epk  + (size_t)N_EDGES*8);          // f[N*16]
constexpr size_t o_U2   = al512(o_U1   + (size_t)N_NODES*16*4);       // f[N*64]
constexpr size_t o_U3   = o_U2 + (size_t)N_NODES*64*4;                // f[N*64] (contiguous after U2)
constexpr size_t o_gs   = al512(o_U3   + (size_t)N_NODES*64*4);       // f[N] gate sums
constexpr size_t o_h1   = al512(o_gs   + (size_t)N_NODES*4);          // f[N*16]
constexpr size_t o_m1   = al512(o_h1   + (size_t)N_NODES*16*4);       // f[N*16]
constexpr size_t o_h3   = al512(o_m1   + (size_t)N_NODES*16*4);       // f[N*64] own region
// aliases into dead regions (sequential-stream liveness):
constexpr size_t o_rec  = o_U2;    // dword[3E] bin-staged records (38.4 MB <= U2+U3 51.2 MB); consumed by kbinB before kinject writes U2/U3
constexpr size_t o_h2   = o_epk;   // epk dead after kinject; h2 = 25.6 MB = epk size
constexpr size_t o_m2   = o_U2;    // U2 dead after kdense1
constexpr size_t o_m3   = o_U2;    // m2 dead after kdense2

#define BN_RSQRT 0.9999950000374997f   // 1/sqrt(1+1e-5)

__device__ __forceinline__ float4 ld4(const float* p){ return *(const float4*)p; }
__device__ __forceinline__ float fc(const float4& v, int i){ return ((const float*)&v)[i]; }

// f32 -> bf16 bits, round-to-nearest-even
__device__ __forceinline__ unsigned f2bf(float x){
    unsigned u = __float_as_uint(x);
    u += 0x7fffu + ((u >> 16) & 1u);
    return u >> 16;
}

// ---------------- CSR build ----------------
__global__ void khist(const int* __restrict__ dst, int* __restrict__ wp){
    int i = blockIdx.x*256 + threadIdx.x;
    if(i < N_EDGES) atomicAdd(&wp[dst[i]], 1);
}

__global__ void kscanA(const int* __restrict__ cnt, int* __restrict__ bs){
    __shared__ int s[256];
    int t = threadIdx.x;
    int base = blockIdx.x*1024 + t*4;
    int v = 0;
    #pragma unroll
    for(int k=0;k<4;k++){ int i = base+k; if(i < N_NODES) v += cnt[i]; }
    s[t] = v; __syncthreads();
    for(int off=128; off>0; off>>=1){ if(t<off) s[t] += s[t+off]; __syncthreads(); }
    if(t==0) bs[blockIdx.x] = s[0];
}

__global__ void kscanB(int* __restrict__ bs){
    __shared__ int s[128];
    int t = threadIdx.x;
    int v = (t < NBLK_SCAN) ? bs[t] : 0;
    s[t] = v; __syncthreads();
    for(int off=1; off<128; off<<=1){
        int add = (t>=off) ? s[t-off] : 0;
        __syncthreads(); s[t] += add; __syncthreads();
    }
    bs[t] = (t==0) ? 0 : s[t-1];
}

__global__ void kscanC(const int* __restrict__ cnt, const int* __restrict__ bs,
                       int* __restrict__ offs){
    __shared__ int s[256];
    int t = threadIdx.x;
    int base = blockIdx.x*1024 + t*4;
    int c0=0,c1=0,c2=0,c3=0;
    if(base+0 < N_NODES) c0 = cnt[base+0];
    if(base+1 < N_NODES) c1 = cnt[base+1];
    if(base+2 < N_NODES) c2 = cnt[base+2];
    if(base+3 < N_NODES) c3 = cnt[base+3];
    int v = c0+c1+c2+c3;
    s[t] = v; __syncthreads();
    for(int off=1; off<256; off<<=1){
        int add = (t>=off) ? s[t-off] : 0;
        __syncthreads(); s[t] += add; __syncthreads();
    }
    int ebase = bs[blockIdx.x] + ((t==0) ? 0 : s[t-1]);
    int run = 0;
    run += c0; if(base+0 < N_NODES) offs[base+1] = ebase+run;
    run += c1; if(base+1 < N_NODES) offs[base+2] = ebase+run;
    run += c2; if(base+2 < N_NODES) offs[base+3] = ebase+run;
    run += c3; if(base+3 < N_NODES) offs[base+4] = ebase+run;
    if(blockIdx.x==0 && t==0) offs[0] = 0;
}

// gbase[b] = CSR start of bin b
__global__ void kginit(const int* __restrict__ offs, int* __restrict__ gbase){
    int b = blockIdx.x*256 + threadIdx.x;
    if(b < NB) gbase[b] = offs[b*256];
}

// ---------------- pass A: LDS-staged binning (all global writes dense) ----------------
// record (12 B, 3 dwords): {src | nib<<17, e1e0 bf16x2, e2 f32}, nib = dst & 255
__global__ __launch_bounds__(256) void kbinA(const int* __restrict__ src,
                                             const int* __restrict__ dst,
                                             const float* __restrict__ ea,
                                             int* __restrict__ gbase,
                                             unsigned* __restrict__ recD){
    __shared__ int cnt[NB], lofs[NB], gst[NB], lcnt[NB];
    __shared__ int sscan[256];
    __shared__ unsigned stage[CHUNK*3];
    __shared__ unsigned short binOf[CHUNK];
    int t = threadIdx.x;
    long e0i = (long)blockIdx.x*CHUNK;
    int nrem = (int)(N_EDGES - e0i); if(nrem > CHUNK) nrem = CHUNK;

    for(int b=t; b<NB; b+=256){ cnt[b]=0; lcnt[b]=0; }
    __syncthreads();
    // phase 1: count bins
    for(int k=t; k<nrem; k+=256)
        atomicAdd(&cnt[dst[e0i+k] >> 8], 1);
    __syncthreads();
    // exclusive prefix over NB bins (2 entries/thread, Hillis-Steele on 256 partials)
    int c0 = (2*t   < NB) ? cnt[2*t]   : 0;
    int c1 = (2*t+1 < NB) ? cnt[2*t+1] : 0;
    sscan[t] = c0 + c1;
    __syncthreads();
    for(int off=1; off<256; off<<=1){
        int v = (t>=off) ? sscan[t-off] : 0;
        __syncthreads(); sscan[t] += v; __syncthreads();
    }
    int base = (t==0) ? 0 : sscan[t-1];
    if(2*t   < NB) lofs[2*t]   = base;
    if(2*t+1 < NB) lofs[2*t+1] = base + c0;
    // reserve per-bin global runs (few atomics: NB per block)
    for(int b=t; b<NB; b+=256){
        int c = cnt[b];
        gst[b] = c ? atomicAdd(&gbase[b], c) : 0;
    }
    __syncthreads();
    // phase 2: place records bin-sorted in LDS
    for(int k=t; k<nrem; k+=256){
        long i = e0i + k;
        int d = dst[i];
        int s = src[i];
        float a0 = ea[i*3+0], a1 = ea[i*3+1], a2 = ea[i*3+2];
        int b = d >> 8;
        int p = lofs[b] + atomicAdd(&lcnt[b], 1);
        stage[3*p+0] = (unsigned)s | ((unsigned)(d & 255) << 17);
        stage[3*p+1] = (f2bf(a1)<<16) | f2bf(a0);
        stage[3*p+2] = __float_as_uint(a2);
        binOf[p] = (unsigned short)b;
    }
    __syncthreads();
    // write-out: consecutive LDS dwords -> dense per-bin global runs
    int total3 = nrem*3;
    for(int q=t; q<total3; q+=256){
        int p = q/3;
        int b = binOf[p];
        int g = gst[b] + (p - lofs[b]);
        recD[(size_t)3*g + (q - 3*p)] = stage[q];
    }
}

// ---------------- pass B: per-bucket LDS counting sort to exact CSR order ----------------
__global__ __launch_bounds__(512) void kbinB(const unsigned* __restrict__ recD,
                                             const int* __restrict__ offs,
                                             int* __restrict__ srcp,
                                             uint2* __restrict__ epk){
    __shared__ int nofs[257], lcnt[256];
    __shared__ int   srcA[CAPB];
    __shared__ uint2 epkA[CAPB];
    int t = threadIdx.x;
    int b = blockIdx.x;
    int n0 = b*256;
    int nn = N_NODES - n0; if(nn > 256) nn = 256;
    for(int i=t; i<=nn; i+=512) nofs[i] = offs[n0+i];
    for(int i=t; i<256; i+=512) lcnt[i] = 0;
    __syncthreads();
    int offs0 = nofs[0];
    int m = nofs[nn] - offs0;
    // read bucket records (contiguous) and place at exact in-bucket CSR slot
    for(int p=t; p<m; p+=512){
        size_t q = (size_t)3*(offs0 + p);
        unsigned w0 = recD[q], w1 = recD[q+1], w2 = recD[q+2];
        int nib = (int)((w0 >> 17) & 255u);
        int slot = (nofs[nib] - offs0) + atomicAdd(&lcnt[nib], 1);
        if(slot < CAPB){
            srcA[slot] = (int)(w0 & 0x1FFFFu);
            epkA[slot] = make_uint2(w2, w1);
        }
    }
    __syncthreads();
    // fully dense write-out
    for(int p=t; p<m; p+=512){
        srcp[offs0+p] = srcA[p];
        epk [offs0+p] = epkA[p];
    }
}

// ---------------- fused 3-inject edge accumulation (one wave per node) ----------------
struct InjW { float wa1,wb1,wc1,bb1, wa2,wb2,wc2,bb2, wa3,wb3,wc3,bb3; };

__device__ __forceinline__ void edge_acc(unsigned w0, unsigned w1, const InjW& W,
                                         float& a1, float& a2, float& a3, float& g){
    float e2 = __uint_as_float(w0);
    float e0 = __uint_as_float(w1 << 16);
    float e1 = __uint_as_float(w1 & 0xffff0000u);
    float gate = __builtin_amdgcn_rcpf(1.f + __expf(-e2));
    a1 += fmaxf(fmaf(e2,W.wc1,fmaf(e1,W.wb1,fmaf(e0,W.wa1,W.bb1))),0.f)*gate;
    a2 += fmaxf(fmaf(e2,W.wc2,fmaf(e1,W.wb2,fmaf(e0,W.wa2,W.bb2))),0.f)*gate;
    a3 += fmaxf(fmaf(e2,W.wc3,fmaf(e1,W.wb3,fmaf(e0,W.wa3,W.bb3))),0.f)*gate;
    g  += gate;
}

__global__ void kinject(const uint2* __restrict__ epk, const int* __restrict__ offs,
                        const float* __restrict__ w11, const float* __restrict__ b11,
                        const float* __restrict__ w12, const float* __restrict__ b12,
                        const float* __restrict__ w13, const float* __restrict__ b13,
                        float* __restrict__ U1, float* __restrict__ U2,
                        float* __restrict__ U3, float* __restrict__ gsum){
    int gid = blockIdx.x*blockDim.x + threadIdx.x;
    int node = gid >> 6;
    if(node >= N_NODES) return;
    int lane = threadIdx.x & 63;
    int l16  = lane & 15;
    InjW W;
    W.wa1=w11[l16];  W.wb1=w11[16+l16];  W.wc1=w11[32+l16];  W.bb1=b11[l16];
    W.wa2=w12[lane]; W.wb2=w12[64+lane]; W.wc2=w12[128+lane]; W.bb2=b12[lane];
    W.wa3=w13[lane]; W.wb3=w13[64+lane]; W.wc3=w13[128+lane]; W.bb3=b13[lane];
    int beg = offs[node], end = offs[node+1];
    float a1=0.f, a2=0.f, a3=0.f, g=0.f;
    int e = beg;
    if((e & 1) && e < end){
        uint2 p = epk[e];
        edge_acc(p.x, p.y, W, a1, a2, a3, g);
        ++e;
    }
    for(; e+2<=end; e+=2){
        uint4 p = *(const uint4*)(epk + e);
        edge_acc(p.x, p.y, W, a1, a2, a3, g);
        edge_acc(p.z, p.w, W, a1, a2, a3, g);
    }
    if(e < end){
        uint2 p = epk[e];
        edge_acc(p.x, p.y, W, a1, a2, a3, g);
    }
    U2[(size_t)node*64 + lane] = a2;
    U3[(size_t)node*64 + lane] = a3;
    if(lane < 16) U1[node*16 + l16] = a1;
    if(lane == 0) gsum[node] = g;
}

// ---------------- SAGE mean gathers (one wave per node) ----------------
__global__ void kgather16(const float* __restrict__ h, const int* __restrict__ srcp,
                          const int* __restrict__ offs, float* __restrict__ m){
    int gid = blockIdx.x*blockDim.x + threadIdx.x;
    int node = gid >> 6;
    if(node >= N_NODES) return;
    int lane = threadIdx.x & 63;
    int q = lane >> 4, d = lane & 15;
    int beg = offs[node], end = offs[node+1];
    float acc = 0.f;
    for(int e=beg+q; e<end; e+=4) acc += h[(size_t)srcp[e]*16 + d];
    acc += __shfl_down(acc, 32);
    acc += __shfl_down(acc, 16);
    if(lane < 16){
        float c = fmaxf((float)(end-beg), 1.f);
        m[node*16 + lane] = acc / c;
    }
}

__global__ void kgather64(const float* __restrict__ h, const int* __restrict__ srcp,
                          const int* __restrict__ offs, float* __restrict__ m){
    int gid = blockIdx.x*blockDim.x + threadIdx.x;
    int node = gid >> 6;
    if(node >= N_NODES) return;
    int lane = threadIdx.x & 63;
    int beg = offs[node], end = offs[node+1];
    float acc = 0.f;
    int e = beg;
    for(; e+4<=end; e+=4){
        int s0=srcp[e], s1=srcp[e+1], s2=srcp[e+2], s3=srcp[e+3];
        acc += h[(size_t)s0*64 + lane];
        acc += h[(size_t)s1*64 + lane];
        acc += h[(size_t)s2*64 + lane];
        acc += h[(size_t)s3*64 + lane];
    }
    for(; e<end; ++e) acc += h[(size_t)srcp[e]*64 + lane];
    float c = fmaxf((float)(end-beg), 1.f);
    m[(size_t)node*64 + lane] = acc / c;
}

// ---------------- dense per-node kernels (LDS weights + 4x4 register tiles) ----------------

// h1 = x + U1 @ w2_1 + gs * b2_1            [N,16]
__global__ __launch_bounds__(256) void kdense0(const float* __restrict__ x, const float* __restrict__ U1,
                        const float* __restrict__ gs, const float* __restrict__ w2,
                        const float* __restrict__ b2, float* __restrict__ h1){
    __shared__ float sw[256];
    int t = threadIdx.x;
    sw[t] = w2[t];
    __syncthreads();
    int idx = blockIdx.x*256 + t;
    int n = idx >> 4, j = idx & 15;
    float acc = x[idx] + gs[n]*b2[j];
    const float4* row = (const float4*)(U1 + n*16);
    #pragma unroll
    for(int i4=0;i4<4;i4++){
        float4 r = row[i4];
        acc += r.x*sw[(i4*4+0)*16 + j];
        acc += r.y*sw[(i4*4+1)*16 + j];
        acc += r.z*sw[(i4*4+2)*16 + j];
        acc += r.w*sw[(i4*4+3)*16 + j];
    }
    h1[idx] = acc;
}

// h2 = relu(bn1(m1@wl + h1@wr + bl)) + U2@w2_2 + gs*b2_2    [N,64]
__global__ __launch_bounds__(256) void kdense1(const float* __restrict__ m1, const float* __restrict__ h1,
                        const float* __restrict__ U2, const float* __restrict__ gs,
                        const float* __restrict__ wl, const float* __restrict__ bl,
                        const float* __restrict__ wr,
                        const float* __restrict__ w2, const float* __restrict__ b2,
                        const float* __restrict__ bnw, const float* __restrict__ bnb,
                        float* __restrict__ h2){
    __shared__ float4 swl[16*16];
    __shared__ float4 swr[16*16];
    __shared__ float4 sw2[64*16];
    int t = threadIdx.x;
    swl[t] = ((const float4*)wl)[t];
    swr[t] = ((const float4*)wr)[t];
    #pragma unroll
    for(int k=0;k<4;k++) sw2[t + 256*k] = ((const float4*)w2)[t + 256*k];
    __syncthreads();

    int w = t>>6, l = t&63;
    int jg = l&15, j0 = jg*4, ng = l>>4;
    int nb = blockIdx.x*64 + w*16 + ng*4;
    int nn[4];
    #pragma unroll
    for(int k=0;k<4;k++) nn[k] = (nb+k < N_NODES) ? nb+k : N_NODES-1;

    float a[4][4], b[4][4];
    float4 blv = ld4(bl + j0);
    float4 b2v = ld4(b2 + j0);
    #pragma unroll
    for(int k=0;k<4;k++){
        float g = gs[nn[k]];
        a[k][0]=blv.x; a[k][1]=blv.y; a[k][2]=blv.z; a[k][3]=blv.w;
        b[k][0]=g*b2v.x; b[k][1]=g*b2v.y; b[k][2]=g*b2v.z; b[k][3]=g*b2v.w;
    }
    #pragma unroll
    for(int i=0;i<16;i+=4){
        float4 rm[4], rh[4];
        #pragma unroll
        for(int k=0;k<4;k++){ rm[k] = ld4(m1 + nn[k]*16 + i); rh[k] = ld4(h1 + nn[k]*16 + i); }
        #pragma unroll
        for(int ii=0;ii<4;ii++){
            float4 wL = swl[(i+ii)*16 + jg];
            float4 wR = swr[(i+ii)*16 + jg];
            #pragma unroll
            for(int k=0;k<4;k++){
                float vm = fc(rm[k],ii), vh = fc(rh[k],ii);
                a[k][0] = fmaf(vm,wL.x, fmaf(vh,wR.x, a[k][0]));
                a[k][1] = fmaf(vm,wL.y, fmaf(vh,wR.y, a[k][1]));
                a[k][2] = fmaf(vm,wL.z, fmaf(vh,wR.z, a[k][2]));
                a[k][3] = fmaf(vm,wL.w, fmaf(vh,wR.w, a[k][3]));
            }
        }
    }
    #pragma unroll 4
    for(int i=0;i<64;i+=4){
        float4 ru[4];
        #pragma unroll
        for(int k=0;k<4;k++) ru[k] = ld4(U2 + (size_t)nn[k]*64 + i);
        #pragma unroll
        for(int ii=0;ii<4;ii++){
            float4 wv = sw2[(i+ii)*16 + jg];
            #pragma unroll
            for(int k=0;k<4;k++){
                float vu = fc(ru[k],ii);
                b[k][0] = fmaf(vu,wv.x,b[k][0]);
                b[k][1] = fmaf(vu,wv.y,b[k][1]);
                b[k][2] = fmaf(vu,wv.z,b[k][2]);
                b[k][3] = fmaf(vu,wv.w,b[k][3]);
            }
        }
    }
    float4 bw = ld4(bnw + j0), bb = ld4(bnb + j0);
    #pragma unroll
    for(int k=0;k<4;k++){
        if(nb+k < N_NODES){
            float4 o;
            o.x = fmaxf(a[k][0]*(bw.x*BN_RSQRT)+bb.x,0.f) + b[k][0];
            o.y = fmaxf(a[k][1]*(bw.y*BN_RSQRT)+bb.y,0.f) + b[k][1];
            o.z = fmaxf(a[k][2]*(bw.z*BN_RSQRT)+bb.z,0.f) + b[k][2];
            o.w = fmaxf(a[k][3]*(bw.w*BN_RSQRT)+bb.w,0.f) + b[k][3];
            *(float4*)(h2 + (size_t)(nb+k)*64 + j0) = o;
        }
    }
}

// h3 = relu(bn2(m2@wl + h2@wr + bl)) + U3@w2_3 + gs*b2_3    [N,64]
__global__ __launch_bounds__(256) void kdense2(const float* __restrict__ m2, const float* __restrict__ h2,
                        const float* __restrict__ U3, const float* __restrict__ gs,
                        const float* __restrict__ wl, const float* __restrict__ bl,
                        const float* __restrict__ wr,
                        const float* __restrict__ w2, const float* __restrict__ b2,
                        const float* __restrict__ bnw, const float* __restrict__ bnb,
                        float* __restrict__ h3){
    __shared__ float4 swl[64*16];
    __shared__ float4 swr[64*16];
    __shared__ float4 sw2[64*16];
    int t = threadIdx.x;
    #pragma unroll
    for(int k=0;k<4;k++){
        swl[t + 256*k] = ((const float4*)wl)[t + 256*k];
        swr[t + 256*k] = ((const float4*)wr)[t + 256*k];
        sw2[t + 256*k] = ((const float4*)w2)[t + 256*k];
    }
    __syncthreads();

    int w = t>>6, l = t&63;
    int jg = l&15, j0 = jg*4, ng = l>>4;
    int nb = blockIdx.x*64 + w*16 + ng*4;
    int nn[4];
    #pragma unroll
    for(int k=0;k<4;k++) nn[k] = (nb+k < N_NODES) ? nb+k : N_NODES-1;

    float a[4][4], b[4][4];
    float4 blv = ld4(bl + j0);
    float4 b2v = ld4(b2 + j0);
    #pragma unroll
    for(int k=0;k<4;k++){
        float g = gs[nn[k]];
        a[k][0]=blv.x; a[k][1]=blv.y; a[k][2]=blv.z; a[k][3]=blv.w;
        b[k][0]=g*b2v.x; b[k][1]=g*b2v.y; b[k][2]=g*b2v.z; b[k][3]=g*b2v.w;
    }
    #pragma unroll 4
    for(int i=0;i<64;i+=4){
        float4 rm[4], rh[4];
        #pragma unroll
        for(int k=0;k<4;k++){ rm[k] = ld4(m2 + (size_t)nn[k]*64 + i); rh[k] = ld4(h2 + (size_t)nn[k]*64 + i); }
        #pragma unroll
        for(int ii=0;ii<4;ii++){
            float4 wL = swl[(i+ii)*16 + jg];
            float4 wR = swr[(i+ii)*16 + jg];
            #pragma unroll
            for(int k=0;k<4;k++){
                float vm = fc(rm[k],ii), vh = fc(rh[k],ii);
                a[k][0] = fmaf(vm,wL.x, fmaf(vh,wR.x, a[k][0]));
                a[k][1] = fmaf(vm,wL.y, fmaf(vh,wR.y, a[k][1]));
                a[k][2] = fmaf(vm,wL.z, fmaf(vh,wR.z, a[k][2]));
                a[k][3] = fmaf(vm,wL.w, fmaf(vh,wR.w, a[k][3]));
            }
        }
    }
    #pragma unroll 4
    for(int i=0;i<64;i+=4){
        float4 ru[4];
        #pragma unroll
        for(int k=0;k<4;k++) ru[k] = ld4(U3 + (size_t)nn[k]*64 + i);
        #pragma unroll
        for(int ii=0;ii<4;ii++){
            float4 wv = sw2[(i+ii)*16 + jg];
            #pragma unroll
            for(int k=0;k<4;k++){
                float vu = fc(ru[k],ii);
                b[k][0] = fmaf(vu,wv.x,b[k][0]);
                b[k][1] = fmaf(vu,wv.y,b[k][1]);
                b[k][2] = fmaf(vu,wv.z,b[k][2]);
                b[k][3] = fmaf(vu,wv.w,b[k][3]);
            }
        }
    }
    float4 bw = ld4(bnw + j0), bb = ld4(bnb + j0);
    #pragma unroll
    for(int k=0;k<4;k++){
        if(nb+k < N_NODES){
            float4 o;
            o.x = fmaxf(a[k][0]*(bw.x*BN_RSQRT)+bb.x,0.f) + b[k][0];
            o.y = fmaxf(a[k][1]*(bw.y*BN_RSQRT)+bb.y,0.f) + b[k][1];
            o.z = fmaxf(a[k][2]*(bw.z*BN_RSQRT)+bb.z,0.f) + b[k][2];
            o.w = fmaxf(a[k][3]*(bw.w*BN_RSQRT)+bb.w,0.f) + b[k][3];
            *(float4*)(h3 + (size_t)(nb+k)*64 + j0) = o;
        }
    }
}

// out = relu(bn3(m3@wl + h3@wr + bl))        [N,32]
__global__ __launch_bounds__(256) void kdense3(const float* __restrict__ m3, const float* __restrict__ h3,
                        const float* __restrict__ wl, const float* __restrict__ bl,
                        const float* __restrict__ wr,
                        const float* __restrict__ bnw, const float* __restrict__ bnb,
                        float* __restrict__ out){
    __shared__ float4 swl[64*8];
    __shared__ float4 swr[64*8];
    int t = threadIdx.x;
    #pragma unroll
    for(int k=0;k<2;k++){
        swl[t + 256*k] = ((const float4*)wl)[t + 256*k];
        swr[t + 256*k] = ((const float4*)wr)[t + 256*k];
    }
    __syncthreads();

    int w = t>>6, l = t&63;
    int jg = l&7, j0 = jg*4, ng = l>>3;
    int nb = blockIdx.x*128 + w*32 + ng*4;
    int nn[4];
    #pragma unroll
    for(int k=0;k<4;k++) nn[k] = (nb+k < N_NODES) ? nb+k : N_NODES-1;

    float a[4][4];
    float4 blv = ld4(bl + j0);
    #pragma unroll
    for(int k=0;k<4;k++){ a[k][0]=blv.x; a[k][1]=blv.y; a[k][2]=blv.z; a[k][3]=blv.w; }
    #pragma unroll 4
    for(int i=0;i<64;i+=4){
        float4 rm[4], rh[4];
        #pragma unroll
        for(int k=0;k<4;k++){ rm[k] = ld4(m3 + (size_t)nn[k]*64 + i); rh[k] = ld4(h3 + (size_t)nn[k]*64 + i); }
        #pragma unroll
        for(int ii=0;ii<4;ii++){
            float4 wL = swl[(i+ii)*8 + jg];
            float4 wR = swr[(i+ii)*8 + jg];
            #pragma unroll
            for(int k=0;k<4;k++){
                float vm = fc(rm[k],ii), vh = fc(rh[k],ii);
                a[k][0] = fmaf(vm,wL.x, fmaf(vh,wR.x, a[k][0]));
                a[k][1] = fmaf(vm,wL.y, fmaf(vh,wR.y, a[k][1]));
                a[k][2] = fmaf(vm,wL.z, fmaf(vh,wR.z, a[k][2]));
                a[k][3] = fmaf(vm,wL.w, fmaf(vh,wR.w, a[k][3]));
            }
        }
    }
    float4 bw = ld4(bnw + j0), bb = ld4(bnb + j0);
    #pragma unroll
    for(int k=0;k<4;k++){
        if(nb+k < N_NODES){
            float4 o;
            o.x = fmaxf(a[k][0]*(bw.x*BN_RSQRT)+bb.x,0.f);
            o.y = fmaxf(a[k][1]*(bw.y*BN_RSQRT)+bb.y,0.f);
            o.z = fmaxf(a[k][2]*(bw.z*BN_RSQRT)+bb.z,0.f);
            o.w = fmaxf(a[k][3]*(bw.w*BN_RSQRT)+bb.w,0.f);
            *(float4*)(out + (size_t)(nb+k)*32 + j0) = o;
        }
    }
}

// ---------------- launch ----------------
extern "C" void kernel_launch(void* const* d_in, const int* in_sizes, int n_in,
                              void* d_out, int out_size, void* d_ws, size_t ws_size,
                              hipStream_t stream){
    const float* x    = (const float*)d_in[0];
    const int*   ei   = (const int*)  d_in[1];
    const float* ea   = (const float*)d_in[2];
    const float* i1w1 = (const float*)d_in[3];
    const float* i1b1 = (const float*)d_in[4];
    const float* i1w2 = (const float*)d_in[5];
    const float* i1b2 = (const float*)d_in[6];
    const float* i2w1 = (const float*)d_in[7];
    const float* i2b1 = (const float*)d_in[8];
    const float* i2w2 = (const float*)d_in[9];
    const float* i2b2 = (const float*)d_in[10];
    const float* i3w1 = (const float*)d_in[11];
    const float* i3b1 = (const float*)d_in[12];
    const float* i3w2 = (const float*)d_in[13];
    const float* i3b2 = (const float*)d_in[14];
    const float* c1wl = (const float*)d_in[15];
    const float* c1bl = (const float*)d_in[16];
    const float* c1wr = (const float*)d_in[17];
    const float* c2wl = (const float*)d_in[18];
    const float* c2bl = (const float*)d_in[19];
    const float* c2wr = (const float*)d_in[20];
    const float* c3wl = (const float*)d_in[21];
    const float* c3bl = (const float*)d_in[22];
    const float* c3wr = (const float*)d_in[23];
    const float* bn1w = (const float*)d_in[24];
    const float* bn1b = (const float*)d_in[25];
    const float* bn2w = (const float*)d_in[26];
    const float* bn2b = (const float*)d_in[27];
    const float* bn3w = (const float*)d_in[28];
    const float* bn3b = (const float*)d_in[29];

    char* ws = (char*)d_ws;
    int*      wp   = (int*)     (ws + o_wp);
    int*      offs = (int*)     (ws + o_off);
    int*      bs   = (int*)     (ws + o_bs);
    int*      gb   = (int*)     (ws + o_gb);
    int*      srcp = (int*)     (ws + o_srcp);
    uint2*    epk  = (uint2*)   (ws + o_epk);
    unsigned* recD = (unsigned*)(ws + o_rec);
    float*    U1   = (float*)   (ws + o_U1);
    float*    U2   = (float*)   (ws + o_U2);
    float*    U3   = (float*)   (ws + o_U3);
    float*    gs   = (float*)   (ws + o_gs);
    float*    h1   = (float*)   (ws + o_h1);
    float*    m1   = (float*)   (ws + o_m1);
    float*    h2   = (float*)   (ws + o_h2);
    float*    m2   = (float*)   (ws + o_m2);
    float*    h3   = (float*)   (ws + o_h3);
    float*    m3   = (float*)   (ws + o_m3);

    const int* src = ei;              // edge_index[0]
    const int* dst = ei + N_EDGES;    // edge_index[1]

    // CSR offsets
    hipMemsetAsync(wp, 0, (size_t)N_NODES*4, stream);
    khist  <<<N_EDGES/256, 256, 0, stream>>>(dst, wp);
    kscanA <<<NBLK_SCAN,   256, 0, stream>>>(wp, bs);
    kscanB <<<1,           128, 0, stream>>>(bs);
    kscanC <<<NBLK_SCAN,   256, 0, stream>>>(wp, bs, offs);
    kginit <<<2,           256, 0, stream>>>(offs, gb);
    // two-pass LDS-staged counting sort: all global writes dense
    kbinA  <<<NCHUNK, 256, 0, stream>>>(src, dst, ea, gb, recD);
    kbinB  <<<NB,     512, 0, stream>>>(recD, offs, srcp, epk);

    // fused 3x inject edge accumulation (sequential epk reads, gate recomputed)
    kinject <<<N_NODES/4, 256, 0, stream>>>(epk, offs,
                                            i1w1, i1b1, i2w1, i2b1, i3w1, i3b1,
                                            U1, U2, U3, gs);
    // layer 1
    kdense0 <<<N_NODES*16/256, 256, 0, stream>>>(x, U1, gs, i1w2, i1b2, h1);
    kgather16<<<N_NODES/4, 256, 0, stream>>>(h1, srcp, offs, m1);
    kdense1 <<<(N_NODES+63)/64, 256, 0, stream>>>(m1, h1, U2, gs,
                                                 c1wl, c1bl, c1wr, i2w2, i2b2,
                                                 bn1w, bn1b, h2);
    // layer 2
    kgather64<<<N_NODES/4, 256, 0, stream>>>(h2, srcp, offs, m2);
    kdense2 <<<(N_NODES+63)/64, 256, 0, stream>>>(m2, h2, U3, gs,
                                                 c2wl, c2bl, c2wr, i3w2, i3b2,
                                                 bn2w, bn2b, h3);
    // layer 3
    kgather64<<<N_NODES/4, 256, 0, stream>>>(h3, srcp, offs, m3);
    kdense3 <<<(N_NODES+127)/128, 256, 0, stream>>>(m3, h3, c3wl, c3bl, c3wr,
                                                 bn3w, bn3b, (float*)d_out);
}

// Round 7
// 895.781 us; speedup vs baseline: 1.4045x; 1.0541x over previous
//
#include <hip/hip_runtime.h>
#include <math.h>

#define N_NODES 100000
#define N_EDGES 3200000
#define NBLK_SCAN 98   // ceil(100000/1024)
#define NB 391         // bins of 256 nodes: ceil(100000/256)
#define CHUNK 3072
#define NCHUNK 1042    // ceil(3200000/3072)
#define CAPB 10240     // pass-B perm capacity (mean 8192, sigma 90 -> huge margin)

// ---------------- workspace layout ----------------
constexpr size_t al512(size_t x){ return (x + 511) & ~size_t(511); }
constexpr size_t o_wp   = 0;                                          // int[N]  histogram
constexpr size_t o_off  = al512(o_wp   + (size_t)N_NODES*4);          // int[N+1] CSR offsets
constexpr size_t o_bs   = al512(o_off  + ((size_t)N_NODES+1)*4);      // int[128] scan block sums
constexpr size_t o_gb   = al512(o_bs   + 128*4);                      // int[512] per-bin global write base
constexpr size_t o_srcp = al512(o_gb   + 512*4);                      // int[E] src permuted by dst
constexpr size_t o_epk  = al512(o_srcp + (size_t)N_EDGES*4);          // float4[E] {e0,e1,e2,gate}; DEAD after kinject
constexpr size_t o_U1   = al512(o_epk  + (size_t)N_EDGES*16);         // f[N*16]
constexpr size_t o_U2   = al512(o_U1   + (size_t)N_NODES*16*4);       // f[N*64]
constexpr size_t o_U3   = o_U2 + (size_t)N_NODES*64*4;                // f[N*64] (contiguous after U2)
constexpr size_t o_gs   = al512(o_U3   + (size_t)N_NODES*64*4);       // f[N] gate sums
constexpr size_t o_h1   = al512(o_gs   + (size_t)N_NODES*4);          // f[N*16]
constexpr size_t o_m1   = al512(o_h1   + (size_t)N_NODES*16*4);       // f[N*16]
// aliases into dead regions (sequential-stream liveness):
constexpr size_t o_rec  = o_U2;    // uint4[E] staged records (51.2 MB = U2+U3 exactly); consumed by kbinB before kinject writes U2/U3
constexpr size_t o_h2bf = o_epk;                              // bf16 h2 rows (12.8 MB); epk dead after kinject
constexpr size_t o_h3bf = o_epk + (size_t)N_NODES*128;        // bf16 h3 rows (12.8 MB); fits in 51.2 MB epk region
constexpr size_t o_m2   = o_U2;    // U2 dead after kdense1
constexpr size_t o_m3   = o_U2;    // m2 dead after kdense2

#define BN_RSQRT 0.9999950000374997f   // 1/sqrt(1+1e-5)

__device__ __forceinline__ float4 ld4(const float* p){ return *(const float4*)p; }
__device__ __forceinline__ float fc(const float4& v, int i){ return ((const float*)&v)[i]; }
__device__ __forceinline__ float uf(unsigned u){ return __uint_as_float(u); }

// f32 -> bf16 bits, round-to-nearest-even
__device__ __forceinline__ unsigned f2bf(float x){
    unsigned u = __float_as_uint(x);
    u += 0x7fffu + ((u >> 16) & 1u);
    return u >> 16;
}

// ---------------- CSR build ----------------
__global__ void khist(const int* __restrict__ dst, int* __restrict__ wp){
    int i = blockIdx.x*256 + threadIdx.x;
    if(i < N_EDGES) atomicAdd(&wp[dst[i]], 1);
}

__global__ void kscanA(const int* __restrict__ cnt, int* __restrict__ bs){
    __shared__ int s[256];
    int t = threadIdx.x;
    int base = blockIdx.x*1024 + t*4;
    int v = 0;
    #pragma unroll
    for(int k=0;k<4;k++){ int i = base+k; if(i < N_NODES) v += cnt[i]; }
    s[t] = v; __syncthreads();
    for(int off=128; off>0; off>>=1){ if(t<off) s[t] += s[t+off]; __syncthreads(); }
    if(t==0) bs[blockIdx.x] = s[0];
}

__global__ void kscanB(int* __restrict__ bs){
    __shared__ int s[128];
    int t = threadIdx.x;
    int v = (t < NBLK_SCAN) ? bs[t] : 0;
    s[t] = v; __syncthreads();
    for(int off=1; off<128; off<<=1){
        int add = (t>=off) ? s[t-off] : 0;
        __syncthreads(); s[t] += add; __syncthreads();
    }
    bs[t] = (t==0) ? 0 : s[t-1];
}

__global__ void kscanC(const int* __restrict__ cnt, const int* __restrict__ bs,
                       int* __restrict__ offs){
    __shared__ int s[256];
    int t = threadIdx.x;
    int base = blockIdx.x*1024 + t*4;
    int c0=0,c1=0,c2=0,c3=0;
    if(base+0 < N_NODES) c0 = cnt[base+0];
    if(base+1 < N_NODES) c1 = cnt[base+1];
    if(base+2 < N_NODES) c2 = cnt[base+2];
    if(base+3 < N_NODES) c3 = cnt[base+3];
    int v = c0+c1+c2+c3;
    s[t] = v; __syncthreads();
    for(int off=1; off<256; off<<=1){
        int add = (t>=off) ? s[t-off] : 0;
        __syncthreads(); s[t] += add; __syncthreads();
    }
    int ebase = bs[blockIdx.x] + ((t==0) ? 0 : s[t-1]);
    int run = 0;
    run += c0; if(base+0 < N_NODES) offs[base+1] = ebase+run;
    run += c1; if(base+1 < N_NODES) offs[base+2] = ebase+run;
    run += c2; if(base+2 < N_NODES) offs[base+3] = ebase+run;
    run += c3; if(base+3 < N_NODES) offs[base+4] = ebase+run;
    if(blockIdx.x==0 && t==0) offs[0] = 0;
}

// gbase[b] = CSR start of bin b
__global__ void kginit(const int* __restrict__ offs, int* __restrict__ gbase){
    int b = blockIdx.x*256 + threadIdx.x;
    if(b < NB) gbase[b] = offs[b*256];
}

// ---------------- pass A: LDS-staged binning (all global writes dense) ----------------
// record (16 B, 4 dwords): {src | nib<<17, e0, e1, e2}, nib = dst & 255
__global__ __launch_bounds__(256) void kbinA(const int* __restrict__ src,
                                             const int* __restrict__ dst,
                                             const float* __restrict__ ea,
                                             int* __restrict__ gbase,
                                             unsigned* __restrict__ recD){
    __shared__ int cnt[NB], lofs[NB], gst[NB], lcnt[NB];
    __shared__ int sscan[256];
    __shared__ unsigned stage[CHUNK*4];
    __shared__ unsigned short binOf[CHUNK];
    int t = threadIdx.x;
    long e0i = (long)blockIdx.x*CHUNK;
    int nrem = (int)(N_EDGES - e0i); if(nrem > CHUNK) nrem = CHUNK;
    if(nrem <= 0) return;

    for(int b=t; b<NB; b+=256){ cnt[b]=0; lcnt[b]=0; }
    __syncthreads();
    for(int k=t; k<nrem; k+=256)
        atomicAdd(&cnt[dst[e0i+k] >> 8], 1);
    __syncthreads();
    int c0 = (2*t   < NB) ? cnt[2*t]   : 0;
    int c1 = (2*t+1 < NB) ? cnt[2*t+1] : 0;
    sscan[t] = c0 + c1;
    __syncthreads();
    for(int off=1; off<256; off<<=1){
        int v = (t>=off) ? sscan[t-off] : 0;
        __syncthreads(); sscan[t] += v; __syncthreads();
    }
    int base = (t==0) ? 0 : sscan[t-1];
    if(2*t   < NB) lofs[2*t]   = base;
    if(2*t+1 < NB) lofs[2*t+1] = base + c0;
    for(int b=t; b<NB; b+=256){
        int c = cnt[b];
        gst[b] = c ? atomicAdd(&gbase[b], c) : 0;
    }
    __syncthreads();
    for(int k=t; k<nrem; k+=256){
        long i = e0i + k;
        int d = dst[i];
        int s = src[i];
        float a0 = ea[i*3+0], a1 = ea[i*3+1], a2 = ea[i*3+2];
        int b = d >> 8;
        int p = lofs[b] + atomicAdd(&lcnt[b], 1);
        stage[4*p+0] = (unsigned)s | ((unsigned)(d & 255) << 17);
        stage[4*p+1] = __float_as_uint(a0);
        stage[4*p+2] = __float_as_uint(a1);
        stage[4*p+3] = __float_as_uint(a2);
        binOf[p] = (unsigned short)b;
    }
    __syncthreads();
    int total4 = nrem*4;
    for(int q=t; q<total4; q+=256){
        int p = q >> 2;
        int b = binOf[p];
        int g = gst[b] + (p - lofs[b]);
        recD[(size_t)4*g + (q & 3)] = stage[q];
    }
}

// ---------------- pass B: per-bucket perm sort + gate precompute ----------------
// header pass: compute exact CSR slot per staged record (perm in LDS).
// gather pass: random reads within L2-hot ~131 KB rec window; fully dense writes.
__global__ __launch_bounds__(512) void kbinB(const uint4* __restrict__ rec4,
                                             const int* __restrict__ offs,
                                             int* __restrict__ srcp,
                                             float4* __restrict__ epk){
    __shared__ int nofs[257], lcnt[256];
    __shared__ unsigned short perm[CAPB];
    int t = threadIdx.x;
    int b = blockIdx.x;
    int n0 = b*256;
    int nn = N_NODES - n0; if(nn > 256) nn = 256;
    for(int i=t; i<=nn; i+=512) nofs[i] = offs[n0+i];
    for(int i=t; i<256; i+=512) lcnt[i] = 0;
    __syncthreads();
    int offs0 = nofs[0];
    int m = nofs[nn] - offs0;
    for(int p=t; p<m; p+=512){
        unsigned w0 = ((const unsigned*)rec4)[(size_t)4*(offs0+p)];
        int nib = (int)((w0 >> 17) & 255u);
        int slot = (nofs[nib] - offs0) + atomicAdd(&lcnt[nib], 1);
        if(slot < CAPB) perm[slot] = (unsigned short)p;
    }
    __syncthreads();
    for(int s=t; s<m; s+=512){
        uint4 r = rec4[(size_t)(offs0 + (int)perm[s])];
        float e2 = uf(r.w);
        float gate = __builtin_amdgcn_rcpf(1.f + __expf(-e2));
        srcp[offs0+s] = (int)(r.x & 0x1FFFFu);
        epk [offs0+s] = make_float4(uf(r.y), uf(r.z), e2, gate);
    }
}

// ---------------- fused 3-inject edge accumulation (one wave per node) ----------------
struct InjW { float wa1,wb1,wc1,bb1, wa2,wb2,wc2,bb2, wa3,wb3,wc3,bb3; };

__device__ __forceinline__ void edge_acc(const float4& r, const InjW& W,
                                         float& a1, float& a2, float& a3, float& g){
    // r = {e0, e1, e2, gate}
    float h1 = fmaf(r.z,W.wc1, fmaf(r.y,W.wb1, fmaf(r.x,W.wa1, W.bb1)));
    float h2 = fmaf(r.z,W.wc2, fmaf(r.y,W.wb2, fmaf(r.x,W.wa2, W.bb2)));
    float h3 = fmaf(r.z,W.wc3, fmaf(r.y,W.wb3, fmaf(r.x,W.wa3, W.bb3)));
    a1 = fmaf(fmaxf(h1,0.f), r.w, a1);
    a2 = fmaf(fmaxf(h2,0.f), r.w, a2);
    a3 = fmaf(fmaxf(h3,0.f), r.w, a3);
    g += r.w;
}

__global__ void kinject(const float4* __restrict__ epk, const int* __restrict__ offs,
                        const float* __restrict__ w11, const float* __restrict__ b11,
                        const float* __restrict__ w12, const float* __restrict__ b12,
                        const float* __restrict__ w13, const float* __restrict__ b13,
                        float* __restrict__ U1, float* __restrict__ U2,
                        float* __restrict__ U3, float* __restrict__ gsum){
    int gid = blockIdx.x*blockDim.x + threadIdx.x;
    int node = gid >> 6;
    if(node >= N_NODES) return;
    int lane = threadIdx.x & 63;
    int l16  = lane & 15;
    InjW W;
    W.wa1=w11[l16];  W.wb1=w11[16+l16];  W.wc1=w11[32+l16];  W.bb1=b11[l16];
    W.wa2=w12[lane]; W.wb2=w12[64+lane]; W.wc2=w12[128+lane]; W.bb2=b12[lane];
    W.wa3=w13[lane]; W.wb3=w13[64+lane]; W.wc3=w13[128+lane]; W.bb3=b13[lane];
    int beg = offs[node], end = offs[node+1];
    float a1=0.f, a2=0.f, a3=0.f, g=0.f;
    int e = beg;
    for(; e+2<=end; e+=2){
        float4 r0 = epk[e];
        float4 r1 = epk[e+1];
        edge_acc(r0, W, a1, a2, a3, g);
        edge_acc(r1, W, a1, a2, a3, g);
    }
    if(e < end) edge_acc(epk[e], W, a1, a2, a3, g);
    U2[(size_t)node*64 + lane] = a2;
    U3[(size_t)node*64 + lane] = a3;
    if(lane < 16) U1[node*16 + l16] = a1;
    if(lane == 0) gsum[node] = g;
}

// ---------------- SAGE mean gathers ----------------
__global__ void kgather16(const float* __restrict__ h, const int* __restrict__ srcp,
                          const int* __restrict__ offs, float* __restrict__ m){
    int gid = blockIdx.x*blockDim.x + threadIdx.x;
    int node = gid >> 6;
    if(node >= N_NODES) return;
    int lane = threadIdx.x & 63;
    int q = lane >> 4, d = lane & 15;
    int beg = offs[node], end = offs[node+1];
    float acc = 0.f;
    for(int e=beg+q; e<end; e+=4) acc += h[(size_t)srcp[e]*16 + d];
    acc += __shfl_down(acc, 32);
    acc += __shfl_down(acc, 16);
    if(lane < 16){
        float c = fmaxf((float)(end-beg), 1.f);
        m[node*16 + lane] = acc / c;
    }
}

// bf16 rows (32 uints = 64 dims); 2 edges per wave-iteration (half-wave per edge)
__global__ void kgather64bf(const unsigned* __restrict__ hbf, const int* __restrict__ srcp,
                            const int* __restrict__ offs, float* __restrict__ m){
    int gid = blockIdx.x*blockDim.x + threadIdx.x;
    int node = gid >> 6;
    if(node >= N_NODES) return;
    int lane = threadIdx.x & 63;
    int half = lane >> 5, c = lane & 31;
    int beg = offs[node], end = offs[node+1];
    float acc0 = 0.f, acc1 = 0.f;
    int e = beg;
    for(; e+4<=end; e+=4){
        int s0 = srcp[e+half], s1 = srcp[e+2+half];
        unsigned w0 = hbf[(size_t)s0*32 + c];
        unsigned w1 = hbf[(size_t)s1*32 + c];
        acc0 += uf(w0<<16); acc1 += uf(w0 & 0xffff0000u);
        acc0 += uf(w1<<16); acc1 += uf(w1 & 0xffff0000u);
    }
    for(; e+2<=end; e+=2){
        int s = srcp[e+half];
        unsigned w = hbf[(size_t)s*32 + c];
        acc0 += uf(w<<16); acc1 += uf(w & 0xffff0000u);
    }
    if(e < end && half == 0){
        int s = srcp[e];
        unsigned w = hbf[(size_t)s*32 + c];
        acc0 += uf(w<<16); acc1 += uf(w & 0xffff0000u);
    }
    acc0 += __shfl_down(acc0, 32);
    acc1 += __shfl_down(acc1, 32);
    if(lane < 32){
        float inv = 1.f / fmaxf((float)(end-beg), 1.f);
        float2 o; o.x = acc0*inv; o.y = acc1*inv;
        *(float2*)(m + (size_t)node*64 + 2*c) = o;
    }
}

// ---------------- dense per-node kernels (LDS weights + 4x4 register tiles) ----------------

// h1 = x + U1 @ w2_1 + gs * b2_1            [N,16]
__global__ __launch_bounds__(256) void kdense0(const float* __restrict__ x, const float* __restrict__ U1,
                        const float* __restrict__ gs, const float* __restrict__ w2,
                        const float* __restrict__ b2, float* __restrict__ h1){
    __shared__ float sw[256];
    int t = threadIdx.x;
    sw[t] = w2[t];
    __syncthreads();
    int idx = blockIdx.x*256 + t;
    int n = idx >> 4, j = idx & 15;
    float acc = x[idx] + gs[n]*b2[j];
    const float4* row = (const float4*)(U1 + n*16);
    #pragma unroll
    for(int i4=0;i4<4;i4++){
        float4 r = row[i4];
        acc += r.x*sw[(i4*4+0)*16 + j];
        acc += r.y*sw[(i4*4+1)*16 + j];
        acc += r.z*sw[(i4*4+2)*16 + j];
        acc += r.w*sw[(i4*4+3)*16 + j];
    }
    h1[idx] = acc;
}

// h2bf = bf16( relu(bn1(m1@wl + h1@wr + bl)) + U2@w2_2 + gs*b2_2 )   [N,64]
__global__ __launch_bounds__(256) void kdense1(const float* __restrict__ m1, const float* __restrict__ h1,
                        const float* __restrict__ U2, const float* __restrict__ gs,
                        const float* __restrict__ wl, const float* __restrict__ bl,
                        const float* __restrict__ wr,
                        const float* __restrict__ w2, const float* __restrict__ b2,
                        const float* __restrict__ bnw, const float* __restrict__ bnb,
                        unsigned* __restrict__ h2bf){
    __shared__ float4 swl[16*16];
    __shared__ float4 swr[16*16];
    __shared__ float4 sw2[64*16];
    int t = threadIdx.x;
    swl[t] = ((const float4*)wl)[t];
    swr[t] = ((const float4*)wr)[t];
    #pragma unroll
    for(int k=0;k<4;k++) sw2[t + 256*k] = ((const float4*)w2)[t + 256*k];
    __syncthreads();

    int w = t>>6, l = t&63;
    int jg = l&15, j0 = jg*4, ng = l>>4;
    int nb = blockIdx.x*64 + w*16 + ng*4;
    int nn[4];
    #pragma unroll
    for(int k=0;k<4;k++) nn[k] = (nb+k < N_NODES) ? nb+k : N_NODES-1;

    float a[4][4], b[4][4];
    float4 blv = ld4(bl + j0);
    float4 b2v = ld4(b2 + j0);
    #pragma unroll
    for(int k=0;k<4;k++){
        float g = gs[nn[k]];
        a[k][0]=blv.x; a[k][1]=blv.y; a[k][2]=blv.z; a[k][3]=blv.w;
        b[k][0]=g*b2v.x; b[k][1]=g*b2v.y; b[k][2]=g*b2v.z; b[k][3]=g*b2v.w;
    }
    #pragma unroll
    for(int i=0;i<16;i+=4){
        float4 rm[4], rh[4];
        #pragma unroll
        for(int k=0;k<4;k++){ rm[k] = ld4(m1 + nn[k]*16 + i); rh[k] = ld4(h1 + nn[k]*16 + i); }
        #pragma unroll
        for(int ii=0;ii<4;ii++){
            float4 wL = swl[(i+ii)*16 + jg];
            float4 wR = swr[(i+ii)*16 + jg];
            #pragma unroll
            for(int k=0;k<4;k++){
                float vm = fc(rm[k],ii), vh = fc(rh[k],ii);
                a[k][0] = fmaf(vm,wL.x, fmaf(vh,wR.x, a[k][0]));
                a[k][1] = fmaf(vm,wL.y, fmaf(vh,wR.y, a[k][1]));
                a[k][2] = fmaf(vm,wL.z, fmaf(vh,wR.z, a[k][2]));
                a[k][3] = fmaf(vm,wL.w, fmaf(vh,wR.w, a[k][3]));
            }
        }
    }
    #pragma unroll 4
    for(int i=0;i<64;i+=4){
        float4 ru[4];
        #pragma unroll
        for(int k=0;k<4;k++) ru[k] = ld4(U2 + (size_t)nn[k]*64 + i);
        #pragma unroll
        for(int ii=0;ii<4;ii++){
            float4 wv = sw2[(i+ii)*16 + jg];
            #pragma unroll
            for(int k=0;k<4;k++){
                float vu = fc(ru[k],ii);
                b[k][0] = fmaf(vu,wv.x,b[k][0]);
                b[k][1] = fmaf(vu,wv.y,b[k][1]);
                b[k][2] = fmaf(vu,wv.z,b[k][2]);
                b[k][3] = fmaf(vu,wv.w,b[k][3]);
            }
        }
    }
    float4 bw = ld4(bnw + j0), bb = ld4(bnb + j0);
    #pragma unroll
    for(int k=0;k<4;k++){
        if(nb+k < N_NODES){
            float ox = fmaxf(a[k][0]*(bw.x*BN_RSQRT)+bb.x,0.f) + b[k][0];
            float oy = fmaxf(a[k][1]*(bw.y*BN_RSQRT)+bb.y,0.f) + b[k][1];
            float oz = fmaxf(a[k][2]*(bw.z*BN_RSQRT)+bb.z,0.f) + b[k][2];
            float ow = fmaxf(a[k][3]*(bw.w*BN_RSQRT)+bb.w,0.f) + b[k][3];
            uint2 pk; pk.x = f2bf(ox) | (f2bf(oy)<<16); pk.y = f2bf(oz) | (f2bf(ow)<<16);
            *(uint2*)(h2bf + (size_t)(nb+k)*32 + (j0>>1)) = pk;
        }
    }
}

// h3bf = bf16( relu(bn2(m2@wl + h2@wr + bl)) + U3@w2_3 + gs*b2_3 )   [N,64], h2 from bf16
__global__ __launch_bounds__(256) void kdense2(const float* __restrict__ m2, const unsigned* __restrict__ h2bf,
                        const float* __restrict__ U3, const float* __restrict__ gs,
                        const float* __restrict__ wl, const float* __restrict__ bl,
                        const float* __restrict__ wr,
                        const float* __restrict__ w2, const float* __restrict__ b2,
                        const float* __restrict__ bnw, const float* __restrict__ bnb,
                        unsigned* __restrict__ h3bf){
    __shared__ float4 swl[64*16];
    __shared__ float4 swr[64*16];
    __shared__ float4 sw2[64*16];
    int t = threadIdx.x;
    #pragma unroll
    for(int k=0;k<4;k++){
        swl[t + 256*k] = ((const float4*)wl)[t + 256*k];
        swr[t + 256*k] = ((const float4*)wr)[t + 256*k];
        sw2[t + 256*k] = ((const float4*)w2)[t + 256*k];
    }
    __syncthreads();

    int w = t>>6, l = t&63;
    int jg = l&15, j0 = jg*4, ng = l>>4;
    int nb = blockIdx.x*64 + w*16 + ng*4;
    int nn[4];
    #pragma unroll
    for(int k=0;k<4;k++) nn[k] = (nb+k < N_NODES) ? nb+k : N_NODES-1;

    float a[4][4], b[4][4];
    float4 blv = ld4(bl + j0);
    float4 b2v = ld4(b2 + j0);
    #pragma unroll
    for(int k=0;k<4;k++){
        float g = gs[nn[k]];
        a[k][0]=blv.x; a[k][1]=blv.y; a[k][2]=blv.z; a[k][3]=blv.w;
        b[k][0]=g*b2v.x; b[k][1]=g*b2v.y; b[k][2]=g*b2v.z; b[k][3]=g*b2v.w;
    }
    #pragma unroll 4
    for(int i=0;i<64;i+=4){
        float4 rm[4], rh[4];
        #pragma unroll
        for(int k=0;k<4;k++){
            rm[k] = ld4(m2 + (size_t)nn[k]*64 + i);
            uint2 hw = *(const uint2*)(h2bf + (size_t)nn[k]*32 + (i>>1));
            rh[k].x = uf(hw.x<<16); rh[k].y = uf(hw.x & 0xffff0000u);
            rh[k].z = uf(hw.y<<16); rh[k].w = uf(hw.y & 0xffff0000u);
        }
        #pragma unroll
        for(int ii=0;ii<4;ii++){
            float4 wL = swl[(i+ii)*16 + jg];
            float4 wR = swr[(i+ii)*16 + jg];
            #pragma unroll
            for(int k=0;k<4;k++){
                float vm = fc(rm[k],ii), vh = fc(rh[k],ii);
                a[k][0] = fmaf(vm,wL.x, fmaf(vh,wR.x, a[k][0]));
                a[k][1] = fmaf(vm,wL.y, fmaf(vh,wR.y, a[k][1]));
                a[k][2] = fmaf(vm,wL.z, fmaf(vh,wR.z, a[k][2]));
                a[k][3] = fmaf(vm,wL.w, fmaf(vh,wR.w, a[k][3]));
            }
        }
    }
    #pragma unroll 4
    for(int i=0;i<64;i+=4){
        float4 ru[4];
        #pragma unroll
        for(int k=0;k<4;k++) ru[k] = ld4(U3 + (size_t)nn[k]*64 + i);
        #pragma unroll
        for(int ii=0;ii<4;ii++){
            float4 wv = sw2[(i+ii)*16 + jg];
            #pragma unroll
            for(int k=0;k<4;k++){
                float vu = fc(ru[k],ii);
                b[k][0] = fmaf(vu,wv.x,b[k][0]);
                b[k][1] = fmaf(vu,wv.y,b[k][1]);
                b[k][2] = fmaf(vu,wv.z,b[k][2]);
                b[k][3] = fmaf(vu,wv.w,b[k][3]);
            }
        }
    }
    float4 bw = ld4(bnw + j0), bb = ld4(bnb + j0);
    #pragma unroll
    for(int k=0;k<4;k++){
        if(nb+k < N_NODES){
            float ox = fmaxf(a[k][0]*(bw.x*BN_RSQRT)+bb.x,0.f) + b[k][0];
            float oy = fmaxf(a[k][1]*(bw.y*BN_RSQRT)+bb.y,0.f) + b[k][1];
            float oz = fmaxf(a[k][2]*(bw.z*BN_RSQRT)+bb.z,0.f) + b[k][2];
            float ow = fmaxf(a[k][3]*(bw.w*BN_RSQRT)+bb.w,0.f) + b[k][3];
            uint2 pk; pk.x = f2bf(ox) | (f2bf(oy)<<16); pk.y = f2bf(oz) | (f2bf(ow)<<16);
            *(uint2*)(h3bf + (size_t)(nb+k)*32 + (j0>>1)) = pk;
        }
    }
}

// out = relu(bn3(m3@wl + h3@wr + bl))        [N,32], h3 from bf16
__global__ __launch_bounds__(256) void kdense3(const float* __restrict__ m3, const unsigned* __restrict__ h3bf,
                        const float* __restrict__ wl, const float* __restrict__ bl,
                        const float* __restrict__ wr,
                        const float* __restrict__ bnw, const float* __restrict__ bnb,
                        float* __restrict__ out){
    __shared__ float4 swl[64*8];
    __shared__ float4 swr[64*8];
    int t = threadIdx.x;
    #pragma unroll
    for(int k=0;k<2;k++){
        swl[t + 256*k] = ((const float4*)wl)[t + 256*k];
        swr[t + 256*k] = ((const float4*)wr)[t + 256*k];
    }
    __syncthreads();

    int w = t>>6, l = t&63;
    int jg = l&7, j0 = jg*4, ng = l>>3;
    int nb = blockIdx.x*128 + w*32 + ng*4;
    int nn[4];
    #pragma unroll
    for(int k=0;k<4;k++) nn[k] = (nb+k < N_NODES) ? nb+k : N_NODES-1;

    float a[4][4];
    float4 blv = ld4(bl + j0);
    #pragma unroll
    for(int k=0;k<4;k++){ a[k][0]=blv.x; a[k][1]=blv.y; a[k][2]=blv.z; a[k][3]=blv.w; }
    #pragma unroll 4
    for(int i=0;i<64;i+=4){
        float4 rm[4], rh[4];
        #pragma unroll
        for(int k=0;k<4;k++){
            rm[k] = ld4(m3 + (size_t)nn[k]*64 + i);
            uint2 hw = *(const uint2*)(h3bf + (size_t)nn[k]*32 + (i>>1));
            rh[k].x = uf(hw.x<<16); rh[k].y = uf(hw.x & 0xffff0000u);
            rh[k].z = uf(hw.y<<16); rh[k].w = uf(hw.y & 0xffff0000u);
        }
        #pragma unroll
        for(int ii=0;ii<4;ii++){
            float4 wL = swl[(i+ii)*8 + jg];
            float4 wR = swr[(i+ii)*8 + jg];
            #pragma unroll
            for(int k=0;k<4;k++){
                float vm = fc(rm[k],ii), vh = fc(rh[k],ii);
                a[k][0] = fmaf(vm,wL.x, fmaf(vh,wR.x, a[k][0]));
                a[k][1] = fmaf(vm,wL.y, fmaf(vh,wR.y, a[k][1]));
                a[k][2] = fmaf(vm,wL.z, fmaf(vh,wR.z, a[k][2]));
                a[k][3] = fmaf(vm,wL.w, fmaf(vh,wR.w, a[k][3]));
            }
        }
    }
    float4 bw = ld4(bnw + j0), bb = ld4(bnb + j0);
    #pragma unroll
    for(int k=0;k<4;k++){
        if(nb+k < N_NODES){
            float4 o;
            o.x = fmaxf(a[k][0]*(bw.x*BN_RSQRT)+bb.x,0.f);
            o.y = fmaxf(a[k][1]*(bw.y*BN_RSQRT)+bb.y,0.f);
            o.z = fmaxf(a[k][2]*(bw.z*BN_RSQRT)+bb.z,0.f);
            o.w = fmaxf(a[k][3]*(bw.w*BN_RSQRT)+bb.w,0.f);
            *(float4*)(out + (size_t)(nb+k)*32 + j0) = o;
        }
    }
}

// ---------------- launch ----------------
extern "C" void kernel_launch(void* const* d_in, const int* in_sizes, int n_in,
                              void* d_out, int out_size, void* d_ws, size_t ws_size,
                              hipStream_t stream){
    const float* x    = (const float*)d_in[0];
    const int*   ei   = (const int*)  d_in[1];
    const float* ea   = (const float*)d_in[2];
    const float* i1w1 = (const float*)d_in[3];
    const float* i1b1 = (const float*)d_in[4];
    const float* i1w2 = (const float*)d_in[5];
    const float* i1b2 = (const float*)d_in[6];
    const float* i2w1 = (const float*)d_in[7];
    const float* i2b1 = (const float*)d_in[8];
    const float* i2w2 = (const float*)d_in[9];
    const float* i2b2 = (const float*)d_in[10];
    const float* i3w1 = (const float*)d_in[11];
    const float* i3b1 = (const float*)d_in[12];
    const float* i3w2 = (const float*)d_in[13];
    const float* i3b2 = (const float*)d_in[14];
    const float* c1wl = (const float*)d_in[15];
    const float* c1bl = (const float*)d_in[16];
    const float* c1wr = (const float*)d_in[17];
    const float* c2wl = (const float*)d_in[18];
    const float* c2bl = (const float*)d_in[19];
    const float* c2wr = (const float*)d_in[20];
    const float* c3wl = (const float*)d_in[21];
    const float* c3bl = (const float*)d_in[22];
    const float* c3wr = (const float*)d_in[23];
    const float* bn1w = (const float*)d_in[24];
    const float* bn1b = (const float*)d_in[25];
    const float* bn2w = (const float*)d_in[26];
    const float* bn2b = (const float*)d_in[27];
    const float* bn3w = (const float*)d_in[28];
    const float* bn3b = (const float*)d_in[29];

    char* ws = (char*)d_ws;
    int*      wp   = (int*)     (ws + o_wp);
    int*      offs = (int*)     (ws + o_off);
    int*      bs   = (int*)     (ws + o_bs);
    int*      gb   = (int*)     (ws + o_gb);
    int*      srcp = (int*)     (ws + o_srcp);
    float4*   epk  = (float4*)  (ws + o_epk);
    unsigned* recD = (unsigned*)(ws + o_rec);
    float*    U1   = (float*)   (ws + o_U1);
    float*    U2   = (float*)   (ws + o_U2);
    float*    U3   = (float*)   (ws + o_U3);
    float*    gs   = (float*)   (ws + o_gs);
    float*    h1   = (float*)   (ws + o_h1);
    float*    m1   = (float*)   (ws + o_m1);
    unsigned* h2bf = (unsigned*)(ws + o_h2bf);
    unsigned* h3bf = (unsigned*)(ws + o_h3bf);
    float*    m2   = (float*)   (ws + o_m2);
    float*    m3   = (float*)   (ws + o_m3);

    const int* src = ei;              // edge_index[0]
    const int* dst = ei + N_EDGES;    // edge_index[1]

    // CSR offsets
    hipMemsetAsync(wp, 0, (size_t)N_NODES*4, stream);
    khist  <<<N_EDGES/256, 256, 0, stream>>>(dst, wp);
    kscanA <<<NBLK_SCAN,   256, 0, stream>>>(wp, bs);
    kscanB <<<1,           128, 0, stream>>>(bs);
    kscanC <<<NBLK_SCAN,   256, 0, stream>>>(wp, bs, offs);
    kginit <<<2,           256, 0, stream>>>(offs, gb);
    // two-pass LDS-staged counting sort (dense writes) + gate precompute
    kbinA  <<<NCHUNK, 256, 0, stream>>>(src, dst, ea, gb, recD);
    kbinB  <<<NB,     512, 0, stream>>>((const uint4*)recD, offs, srcp, epk);

    // fused 3x inject edge accumulation (sequential epk reads, gate preloaded)
    kinject <<<N_NODES/4, 256, 0, stream>>>(epk, offs,
                                            i1w1, i1b1, i2w1, i2b1, i3w1, i3b1,
                                            U1, U2, U3, gs);
    // layer 1
    kdense0 <<<N_NODES*16/256, 256, 0, stream>>>(x, U1, gs, i1w2, i1b2, h1);
    kgather16<<<N_NODES/4, 256, 0, stream>>>(h1, srcp, offs, m1);
    kdense1 <<<(N_NODES+63)/64, 256, 0, stream>>>(m1, h1, U2, gs,
                                                 c1wl, c1bl, c1wr, i2w2, i2b2,
                                                 bn1w, bn1b, h2bf);
    // layer 2
    kgather64bf<<<N_NODES/4, 256, 0, stream>>>(h2bf, srcp, offs, m2);
    kdense2 <<<(N_NODES+63)/64, 256, 0, stream>>>(m2, h2bf, U3, gs,
                                                 c2wl, c2bl, c2wr, i3w2, i3b2,
                                                 bn2w, bn2b, h3bf);
    // layer 3
    kgather64bf<<<N_NODES/4, 256, 0, stream>>>(h3bf, srcp, offs, m3);
    kdense3 <<<(N_NODES+127)/128, 256, 0, stream>>>(m3, h3bf, c3wl, c3bl, c3wr,
                                                 bn3w, bn3b, (float*)d_out);
}

// Round 8
// 781.093 us; speedup vs baseline: 1.6107x; 1.1468x over previous
//
#include <hip/hip_runtime.h>
#include <math.h>

#define N_NODES 100000
#define N_EDGES 3200000
#define NB 391         // bins of 256 nodes: ceil(100000/256)
#define CHUNK 3072
#define NCHUNK 1042    // ceil(3200000/3072)
#define HCHUNK 4096
#define NHCHUNK 782    // ceil(3200000/4096)
#define CAPB 10240     // pass-B perm capacity (mean 8184, sigma ~90 -> huge margin)

// ---------------- workspace layout ----------------
constexpr size_t al512(size_t x){ return (x + 511) & ~size_t(511); }
constexpr size_t o_bcnt = 0;                                          // int[512] per-bin counts
constexpr size_t o_bst  = al512(o_bcnt + 512*4);                      // int[512] bin starts (binStart[NB]=E)
constexpr size_t o_gb   = al512(o_bst  + 512*4);                      // int[512] per-bin reservation ptrs
constexpr size_t o_off  = al512(o_gb   + 512*4);                      // int[N+1] CSR offsets (written by kbinB)
constexpr size_t o_srcp = al512(o_off  + ((size_t)N_NODES+1)*4);      // int[E] src permuted by dst
constexpr size_t o_epk  = al512(o_srcp + (size_t)N_EDGES*4);          // float4[E] {e0,e1,e2,gate}; DEAD after kinject
constexpr size_t o_U1   = al512(o_epk  + (size_t)N_EDGES*16);         // f[N*16]
constexpr size_t o_U2   = al512(o_U1   + (size_t)N_NODES*16*4);       // f[N*64]
constexpr size_t o_U3   = o_U2 + (size_t)N_NODES*64*4;                // f[N*64] (contiguous after U2)
constexpr size_t o_gs   = al512(o_U3   + (size_t)N_NODES*64*4);       // f[N] gate sums
constexpr size_t o_h1   = al512(o_gs   + (size_t)N_NODES*4);          // f[N*16]
constexpr size_t o_m1   = al512(o_h1   + (size_t)N_NODES*16*4);       // f[N*16]
// aliases into dead regions (sequential-stream liveness):
constexpr size_t o_rec  = o_U2;    // uint4[E] staged records (51.2 MB = U2+U3 exactly); consumed by kbinB before kinject writes U2/U3
constexpr size_t o_h2bf = o_epk;                              // bf16 h2 rows (12.8 MB); epk dead after kinject
constexpr size_t o_h3bf = o_epk + (size_t)N_NODES*128;        // bf16 h3 rows (12.8 MB); fits in 51.2 MB epk region
constexpr size_t o_m2   = o_U2;    // U2 dead after kdense1
constexpr size_t o_m3   = o_U2;    // m2 dead after kdense2

#define BN_RSQRT 0.9999950000374997f   // 1/sqrt(1+1e-5)

__device__ __forceinline__ float4 ld4(const float* p){ return *(const float4*)p; }
__device__ __forceinline__ float fc(const float4& v, int i){ return ((const float*)&v)[i]; }
__device__ __forceinline__ float uf(unsigned u){ return __uint_as_float(u); }

// f32 -> bf16 bits, round-to-nearest-even
__device__ __forceinline__ unsigned f2bf(float x){
    unsigned u = __float_as_uint(x);
    u += 0x7fffu + ((u >> 16) & 1u);
    return u >> 16;
}

// ---------------- bin histogram (LDS-aggregated: ~300K global atomics, not 3.2M) ----------------
__global__ __launch_bounds__(256) void khistBin(const int* __restrict__ dst,
                                                int* __restrict__ binCnt){
    __shared__ int c[NB];
    int t = threadIdx.x;
    for(int i=t; i<NB; i+=256) c[i] = 0;
    __syncthreads();
    long base = (long)blockIdx.x*HCHUNK;
    int nrem = (int)(N_EDGES - base); if(nrem > HCHUNK) nrem = HCHUNK;
    for(int k=t; k<nrem; k+=256)
        atomicAdd(&c[dst[base+k] >> 8], 1);
    __syncthreads();
    for(int i=t; i<NB; i+=256)
        if(c[i]) atomicAdd(&binCnt[i], c[i]);
}

// single-block exclusive scan of 391 bin counts -> binStart[0..NB], gbase copy
__global__ __launch_bounds__(512) void kscanBin(const int* __restrict__ binCnt,
                                                int* __restrict__ binStart,
                                                int* __restrict__ gbase){
    __shared__ int s[512];
    int t = threadIdx.x;
    int v = (t < NB) ? binCnt[t] : 0;
    s[t] = v; __syncthreads();
    for(int off=1; off<512; off<<=1){
        int a = (t>=off) ? s[t-off] : 0;
        __syncthreads(); s[t] += a; __syncthreads();
    }
    int ex = (t==0) ? 0 : s[t-1];
    if(t < NB){ binStart[t] = ex; gbase[t] = ex; }
    if(t == NB) binStart[NB] = s[NB-1];   // = N_EDGES
}

// ---------------- pass A: LDS-staged binning (all global writes dense) ----------------
// record (16 B, 4 dwords): {src | nib<<17, e0, e1, e2}, nib = dst & 255
__global__ __launch_bounds__(256) void kbinA(const int* __restrict__ src,
                                             const int* __restrict__ dst,
                                             const float* __restrict__ ea,
                                             int* __restrict__ gbase,
                                             unsigned* __restrict__ recD){
    __shared__ int cnt[NB], lofs[NB], gst[NB], lcnt[NB];
    __shared__ int sscan[256];
    __shared__ unsigned stage[CHUNK*4];
    __shared__ unsigned short binOf[CHUNK];
    int t = threadIdx.x;
    long e0i = (long)blockIdx.x*CHUNK;
    int nrem = (int)(N_EDGES - e0i); if(nrem > CHUNK) nrem = CHUNK;
    if(nrem <= 0) return;

    for(int b=t; b<NB; b+=256){ cnt[b]=0; lcnt[b]=0; }
    __syncthreads();
    for(int k=t; k<nrem; k+=256)
        atomicAdd(&cnt[dst[e0i+k] >> 8], 1);
    __syncthreads();
    int c0 = (2*t   < NB) ? cnt[2*t]   : 0;
    int c1 = (2*t+1 < NB) ? cnt[2*t+1] : 0;
    sscan[t] = c0 + c1;
    __syncthreads();
    for(int off=1; off<256; off<<=1){
        int v = (t>=off) ? sscan[t-off] : 0;
        __syncthreads(); sscan[t] += v; __syncthreads();
    }
    int base = (t==0) ? 0 : sscan[t-1];
    if(2*t   < NB) lofs[2*t]   = base;
    if(2*t+1 < NB) lofs[2*t+1] = base + c0;
    for(int b=t; b<NB; b+=256){
        int c = cnt[b];
        gst[b] = c ? atomicAdd(&gbase[b], c) : 0;
    }
    __syncthreads();
    for(int k=t; k<nrem; k+=256){
        long i = e0i + k;
        int d = dst[i];
        int s = src[i];
        float a0 = ea[i*3+0], a1 = ea[i*3+1], a2 = ea[i*3+2];
        int b = d >> 8;
        int p = lofs[b] + atomicAdd(&lcnt[b], 1);
        stage[4*p+0] = (unsigned)s | ((unsigned)(d & 255) << 17);
        stage[4*p+1] = __float_as_uint(a0);
        stage[4*p+2] = __float_as_uint(a1);
        stage[4*p+3] = __float_as_uint(a2);
        binOf[p] = (unsigned short)b;
    }
    __syncthreads();
    int total4 = nrem*4;
    for(int q=t; q<total4; q+=256){
        int p = q >> 2;
        int b = binOf[p];
        int g = gst[b] + (p - lofs[b]);
        recD[(size_t)4*g + (q & 3)] = stage[q];
    }
}

// ---------------- pass B: per-bucket CSR-slice build + perm sort + gate precompute ----------------
// Derives this bucket's per-node offsets from staged records (no global histogram needed),
// writes the offs slice densely, then permutes records to exact CSR order.
__global__ __launch_bounds__(512) void kbinB(const uint4* __restrict__ rec4,
                                             const int* __restrict__ binStart,
                                             int* __restrict__ offs,
                                             int* __restrict__ srcp,
                                             float4* __restrict__ epk){
    __shared__ int pfx[257], lcnt[256];
    __shared__ int sscan[256];
    __shared__ unsigned short perm[CAPB];
    __shared__ unsigned char  nibOf[CAPB];
    int t = threadIdx.x;
    int b = blockIdx.x;
    int n0 = b*256;
    int nn = N_NODES - n0; if(nn > 256) nn = 256;
    int base = binStart[b];
    int m    = binStart[b+1] - base;
    for(int i=t; i<256; i+=512) lcnt[i] = 0;
    __syncthreads();
    // pass 0: per-node counts (cache nib in LDS)
    for(int p=t; p<m; p+=512){
        unsigned w0 = ((const unsigned*)rec4)[(size_t)4*(base+p)];
        int nib = (int)((w0 >> 17) & 255u);
        if(p < CAPB) nibOf[p] = (unsigned char)nib;
        atomicAdd(&lcnt[nib], 1);
    }
    __syncthreads();
    // exclusive scan of 256 counts (in first 256 threads)
    if(t < 256) sscan[t] = lcnt[t];
    __syncthreads();
    if(t < 256){
        for(int off=1; off<256; off<<=1){
            int v = (t>=off) ? sscan[t-off] : 0;
            __syncthreads(); sscan[t] += v; __syncthreads();
        }
        pfx[t+1] = sscan[t];
        if(t==0) pfx[0] = 0;
    } else {
        for(int off=1; off<256; off<<=1){ __syncthreads(); __syncthreads(); }
    }
    __syncthreads();
    // write this bucket's offs slice (dense)
    for(int i=t; i<=nn; i+=512) offs[n0+i] = base + pfx[i];
    for(int i=t; i<256; i+=512) lcnt[i] = 0;
    __syncthreads();
    // pass 1: compute exact slot per record
    for(int p=t; p<m; p+=512){
        int nib = nibOf[p];
        int slot = pfx[nib] + atomicAdd(&lcnt[nib], 1);
        perm[slot] = (unsigned short)p;
    }
    __syncthreads();
    // pass 2: gather (L2-hot ~131 KB window) + fully dense writes, gate precomputed
    for(int s=t; s<m; s+=512){
        uint4 r = rec4[(size_t)(base + (int)perm[s])];
        float e2 = uf(r.w);
        float gate = __builtin_amdgcn_rcpf(1.f + __expf(-e2));
        srcp[base+s] = (int)(r.x & 0x1FFFFu);
        epk [base+s] = make_float4(uf(r.y), uf(r.z), e2, gate);
    }
}

// ---------------- fused 3-inject edge accumulation (one wave per node) ----------------
struct InjW { float wa1,wb1,wc1,bb1, wa2,wb2,wc2,bb2, wa3,wb3,wc3,bb3; };

__device__ __forceinline__ void edge_acc(const float4& r, const InjW& W,
                                         float& a1, float& a2, float& a3, float& g){
    float h1 = fmaf(r.z,W.wc1, fmaf(r.y,W.wb1, fmaf(r.x,W.wa1, W.bb1)));
    float h2 = fmaf(r.z,W.wc2, fmaf(r.y,W.wb2, fmaf(r.x,W.wa2, W.bb2)));
    float h3 = fmaf(r.z,W.wc3, fmaf(r.y,W.wb3, fmaf(r.x,W.wa3, W.bb3)));
    a1 = fmaf(fmaxf(h1,0.f), r.w, a1);
    a2 = fmaf(fmaxf(h2,0.f), r.w, a2);
    a3 = fmaf(fmaxf(h3,0.f), r.w, a3);
    g += r.w;
}

__global__ void kinject(const float4* __restrict__ epk, const int* __restrict__ offs,
                        const float* __restrict__ w11, const float* __restrict__ b11,
                        const float* __restrict__ w12, const float* __restrict__ b12,
                        const float* __restrict__ w13, const float* __restrict__ b13,
                        float* __restrict__ U1, float* __restrict__ U2,
                        float* __restrict__ U3, float* __restrict__ gsum){
    int gid = blockIdx.x*blockDim.x + threadIdx.x;
    int node = gid >> 6;
    if(node >= N_NODES) return;
    int lane = threadIdx.x & 63;
    int l16  = lane & 15;
    InjW W;
    W.wa1=w11[l16];  W.wb1=w11[16+l16];  W.wc1=w11[32+l16];  W.bb1=b11[l16];
    W.wa2=w12[lane]; W.wb2=w12[64+lane]; W.wc2=w12[128+lane]; W.bb2=b12[lane];
    W.wa3=w13[lane]; W.wb3=w13[64+lane]; W.wc3=w13[128+lane]; W.bb3=b13[lane];
    int beg = offs[node], end = offs[node+1];
    float a1=0.f, a2=0.f, a3=0.f, g=0.f;
    int e = beg;
    for(; e+2<=end; e+=2){
        float4 r0 = epk[e];
        float4 r1 = epk[e+1];
        edge_acc(r0, W, a1, a2, a3, g);
        edge_acc(r1, W, a1, a2, a3, g);
    }
    if(e < end) edge_acc(epk[e], W, a1, a2, a3, g);
    U2[(size_t)node*64 + lane] = a2;
    U3[(size_t)node*64 + lane] = a3;
    if(lane < 16) U1[node*16 + l16] = a1;
    if(lane == 0) gsum[node] = g;
}

// ---------------- SAGE mean gathers ----------------
__global__ void kgather16(const float* __restrict__ h, const int* __restrict__ srcp,
                          const int* __restrict__ offs, float* __restrict__ m){
    int gid = blockIdx.x*blockDim.x + threadIdx.x;
    int node = gid >> 6;
    if(node >= N_NODES) return;
    int lane = threadIdx.x & 63;
    int q = lane >> 4, d = lane & 15;
    int beg = offs[node], end = offs[node+1];
    float acc = 0.f;
    for(int e=beg+q; e<end; e+=4) acc += h[(size_t)srcp[e]*16 + d];
    acc += __shfl_down(acc, 32);
    acc += __shfl_down(acc, 16);
    if(lane < 16){
        float c = fmaxf((float)(end-beg), 1.f);
        m[node*16 + lane] = acc / c;
    }
}

// bf16 rows (32 uints = 64 dims); 2 edges per wave-iteration (half-wave per edge)
__global__ void kgather64bf(const unsigned* __restrict__ hbf, const int* __restrict__ srcp,
                            const int* __restrict__ offs, float* __restrict__ m){
    int gid = blockIdx.x*blockDim.x + threadIdx.x;
    int node = gid >> 6;
    if(node >= N_NODES) return;
    int lane = threadIdx.x & 63;
    int half = lane >> 5, c = lane & 31;
    int beg = offs[node], end = offs[node+1];
    float acc0 = 0.f, acc1 = 0.f;
    int e = beg;
    for(; e+4<=end; e+=4){
        int s0 = srcp[e+half], s1 = srcp[e+2+half];
        unsigned w0 = hbf[(size_t)s0*32 + c];
        unsigned w1 = hbf[(size_t)s1*32 + c];
        acc0 += uf(w0<<16); acc1 += uf(w0 & 0xffff0000u);
        acc0 += uf(w1<<16); acc1 += uf(w1 & 0xffff0000u);
    }
    for(; e+2<=end; e+=2){
        int s = srcp[e+half];
        unsigned w = hbf[(size_t)s*32 + c];
        acc0 += uf(w<<16); acc1 += uf(w & 0xffff0000u);
    }
    if(e < end && half == 0){
        int s = srcp[e];
        unsigned w = hbf[(size_t)s*32 + c];
        acc0 += uf(w<<16); acc1 += uf(w & 0xffff0000u);
    }
    acc0 += __shfl_down(acc0, 32);
    acc1 += __shfl_down(acc1, 32);
    if(lane < 32){
        float inv = 1.f / fmaxf((float)(end-beg), 1.f);
        float2 o; o.x = acc0*inv; o.y = acc1*inv;
        *(float2*)(m + (size_t)node*64 + 2*c) = o;
    }
}

// ---------------- dense per-node kernels (LDS weights + 4x4 register tiles) ----------------

// h1 = x + U1 @ w2_1 + gs * b2_1            [N,16]
__global__ __launch_bounds__(256) void kdense0(const float* __restrict__ x, const float* __restrict__ U1,
                        const float* __restrict__ gs, const float* __restrict__ w2,
                        const float* __restrict__ b2, float* __restrict__ h1){
    __shared__ float sw[256];
    int t = threadIdx.x;
    sw[t] = w2[t];
    __syncthreads();
    int idx = blockIdx.x*256 + t;
    int n = idx >> 4, j = idx & 15;
    float acc = x[idx] + gs[n]*b2[j];
    const float4* row = (const float4*)(U1 + n*16);
    #pragma unroll
    for(int i4=0;i4<4;i4++){
        float4 r = row[i4];
        acc += r.x*sw[(i4*4+0)*16 + j];
        acc += r.y*sw[(i4*4+1)*16 + j];
        acc += r.z*sw[(i4*4+2)*16 + j];
        acc += r.w*sw[(i4*4+3)*16 + j];
    }
    h1[idx] = acc;
}

// h2bf = bf16( relu(bn1(m1@wl + h1@wr + bl)) + U2@w2_2 + gs*b2_2 )   [N,64]
__global__ __launch_bounds__(256) void kdense1(const float* __restrict__ m1, const float* __restrict__ h1,
                        const float* __restrict__ U2, const float* __restrict__ gs,
                        const float* __restrict__ wl, const float* __restrict__ bl,
                        const float* __restrict__ wr,
                        const float* __restrict__ w2, const float* __restrict__ b2,
                        const float* __restrict__ bnw, const float* __restrict__ bnb,
                        unsigned* __restrict__ h2bf){
    __shared__ float4 swl[16*16];
    __shared__ float4 swr[16*16];
    __shared__ float4 sw2[64*16];
    int t = threadIdx.x;
    swl[t] = ((const float4*)wl)[t];
    swr[t] = ((const float4*)wr)[t];
    #pragma unroll
    for(int k=0;k<4;k++) sw2[t + 256*k] = ((const float4*)w2)[t + 256*k];
    __syncthreads();

    int w = t>>6, l = t&63;
    int jg = l&15, j0 = jg*4, ng = l>>4;
    int nb = blockIdx.x*64 + w*16 + ng*4;
    int nn[4];
    #pragma unroll
    for(int k=0;k<4;k++) nn[k] = (nb+k < N_NODES) ? nb+k : N_NODES-1;

    float a[4][4], b[4][4];
    float4 blv = ld4(bl + j0);
    float4 b2v = ld4(b2 + j0);
    #pragma unroll
    for(int k=0;k<4;k++){
        float g = gs[nn[k]];
        a[k][0]=blv.x; a[k][1]=blv.y; a[k][2]=blv.z; a[k][3]=blv.w;
        b[k][0]=g*b2v.x; b[k][1]=g*b2v.y; b[k][2]=g*b2v.z; b[k][3]=g*b2v.w;
    }
    #pragma unroll
    for(int i=0;i<16;i+=4){
        float4 rm[4], rh[4];
        #pragma unroll
        for(int k=0;k<4;k++){ rm[k] = ld4(m1 + nn[k]*16 + i); rh[k] = ld4(h1 + nn[k]*16 + i); }
        #pragma unroll
        for(int ii=0;ii<4;ii++){
            float4 wL = swl[(i+ii)*16 + jg];
            float4 wR = swr[(i+ii)*16 + jg];
            #pragma unroll
            for(int k=0;k<4;k++){
                float vm = fc(rm[k],ii), vh = fc(rh[k],ii);
                a[k][0] = fmaf(vm,wL.x, fmaf(vh,wR.x, a[k][0]));
                a[k][1] = fmaf(vm,wL.y, fmaf(vh,wR.y, a[k][1]));
                a[k][2] = fmaf(vm,wL.z, fmaf(vh,wR.z, a[k][2]));
                a[k][3] = fmaf(vm,wL.w, fmaf(vh,wR.w, a[k][3]));
            }
        }
    }
    #pragma unroll 4
    for(int i=0;i<64;i+=4){
        float4 ru[4];
        #pragma unroll
        for(int k=0;k<4;k++) ru[k] = ld4(U2 + (size_t)nn[k]*64 + i);
        #pragma unroll
        for(int ii=0;ii<4;ii++){
            float4 wv = sw2[(i+ii)*16 + jg];
            #pragma unroll
            for(int k=0;k<4;k++){
                float vu = fc(ru[k],ii);
                b[k][0] = fmaf(vu,wv.x,b[k][0]);
                b[k][1] = fmaf(vu,wv.y,b[k][1]);
                b[k][2] = fmaf(vu,wv.z,b[k][2]);
                b[k][3] = fmaf(vu,wv.w,b[k][3]);
            }
        }
    }
    float4 bw = ld4(bnw + j0), bb = ld4(bnb + j0);
    #pragma unroll
    for(int k=0;k<4;k++){
        if(nb+k < N_NODES){
            float ox = fmaxf(a[k][0]*(bw.x*BN_RSQRT)+bb.x,0.f) + b[k][0];
            float oy = fmaxf(a[k][1]*(bw.y*BN_RSQRT)+bb.y,0.f) + b[k][1];
            float oz = fmaxf(a[k][2]*(bw.z*BN_RSQRT)+bb.z,0.f) + b[k][2];
            float ow = fmaxf(a[k][3]*(bw.w*BN_RSQRT)+bb.w,0.f) + b[k][3];
            uint2 pk; pk.x = f2bf(ox) | (f2bf(oy)<<16); pk.y = f2bf(oz) | (f2bf(ow)<<16);
            *(uint2*)(h2bf + (size_t)(nb+k)*32 + (j0>>1)) = pk;
        }
    }
}

// h3bf = bf16( relu(bn2(m2@wl + h2@wr + bl)) + U3@w2_3 + gs*b2_3 )   [N,64], h2 from bf16
__global__ __launch_bounds__(256) void kdense2(const float* __restrict__ m2, const unsigned* __restrict__ h2bf,
                        const float* __restrict__ U3, const float* __restrict__ gs,
                        const float* __restrict__ wl, const float* __restrict__ bl,
                        const float* __restrict__ wr,
                        const float* __restrict__ w2, const float* __restrict__ b2,
                        const float* __restrict__ bnw, const float* __restrict__ bnb,
                        unsigned* __restrict__ h3bf){
    __shared__ float4 swl[64*16];
    __shared__ float4 swr[64*16];
    __shared__ float4 sw2[64*16];
    int t = threadIdx.x;
    #pragma unroll
    for(int k=0;k<4;k++){
        swl[t + 256*k] = ((const float4*)wl)[t + 256*k];
        swr[t + 256*k] = ((const float4*)wr)[t + 256*k];
        sw2[t + 256*k] = ((const float4*)w2)[t + 256*k];
    }
    __syncthreads();

    int w = t>>6, l = t&63;
    int jg = l&15, j0 = jg*4, ng = l>>4;
    int nb = blockIdx.x*64 + w*16 + ng*4;
    int nn[4];
    #pragma unroll
    for(int k=0;k<4;k++) nn[k] = (nb+k < N_NODES) ? nb+k : N_NODES-1;

    float a[4][4], b[4][4];
    float4 blv = ld4(bl + j0);
    float4 b2v = ld4(b2 + j0);
    #pragma unroll
    for(int k=0;k<4;k++){
        float g = gs[nn[k]];
        a[k][0]=blv.x; a[k][1]=blv.y; a[k][2]=blv.z; a[k][3]=blv.w;
        b[k][0]=g*b2v.x; b[k][1]=g*b2v.y; b[k][2]=g*b2v.z; b[k][3]=g*b2v.w;
    }
    #pragma unroll 4
    for(int i=0;i<64;i+=4){
        float4 rm[4], rh[4];
        #pragma unroll
        for(int k=0;k<4;k++){
            rm[k] = ld4(m2 + (size_t)nn[k]*64 + i);
            uint2 hw = *(const uint2*)(h2bf + (size_t)nn[k]*32 + (i>>1));
            rh[k].x = uf(hw.x<<16); rh[k].y = uf(hw.x & 0xffff0000u);
            rh[k].z = uf(hw.y<<16); rh[k].w = uf(hw.y & 0xffff0000u);
        }
        #pragma unroll
        for(int ii=0;ii<4;ii++){
            float4 wL = swl[(i+ii)*16 + jg];
            float4 wR = swr[(i+ii)*16 + jg];
            #pragma unroll
            for(int k=0;k<4;k++){
                float vm = fc(rm[k],ii), vh = fc(rh[k],ii);
                a[k][0] = fmaf(vm,wL.x, fmaf(vh,wR.x, a[k][0]));
                a[k][1] = fmaf(vm,wL.y, fmaf(vh,wR.y, a[k][1]));
                a[k][2] = fmaf(vm,wL.z, fmaf(vh,wR.z, a[k][2]));
                a[k][3] = fmaf(vm,wL.w, fmaf(vh,wR.w, a[k][3]));
            }
        }
    }
    #pragma unroll 4
    for(int i=0;i<64;i+=4){
        float4 ru[4];
        #pragma unroll
        for(int k=0;k<4;k++) ru[k] = ld4(U3 + (size_t)nn[k]*64 + i);
        #pragma unroll
        for(int ii=0;ii<4;ii++){
            float4 wv = sw2[(i+ii)*16 + jg];
            #pragma unroll
            for(int k=0;k<4;k++){
                float vu = fc(ru[k],ii);
                b[k][0] = fmaf(vu,wv.x,b[k][0]);
                b[k][1] = fmaf(vu,wv.y,b[k][1]);
                b[k][2] = fmaf(vu,wv.z,b[k][2]);
                b[k][3] = fmaf(vu,wv.w,b[k][3]);
            }
        }
    }
    float4 bw = ld4(bnw + j0), bb = ld4(bnb + j0);
    #pragma unroll
    for(int k=0;k<4;k++){
        if(nb+k < N_NODES){
            float ox = fmaxf(a[k][0]*(bw.x*BN_RSQRT)+bb.x,0.f) + b[k][0];
            float oy = fmaxf(a[k][1]*(bw.y*BN_RSQRT)+bb.y,0.f) + b[k][1];
            float oz = fmaxf(a[k][2]*(bw.z*BN_RSQRT)+bb.z,0.f) + b[k][2];
            float ow = fmaxf(a[k][3]*(bw.w*BN_RSQRT)+bb.w,0.f) + b[k][3];
            uint2 pk; pk.x = f2bf(ox) | (f2bf(oy)<<16); pk.y = f2bf(oz) | (f2bf(ow)<<16);
            *(uint2*)(h3bf + (size_t)(nb+k)*32 + (j0>>1)) = pk;
        }
    }
}

// out = relu(bn3(m3@wl + h3@wr + bl))        [N,32], h3 from bf16
__global__ __launch_bounds__(256) void kdense3(const float* __restrict__ m3, const unsigned* __restrict__ h3bf,
                        const float* __restrict__ wl, const float* __restrict__ bl,
                        const float* __restrict__ wr,
                        const float* __restrict__ bnw, const float* __restrict__ bnb,
                        float* __restrict__ out){
    __shared__ float4 swl[64*8];
    __shared__ float4 swr[64*8];
    int t = threadIdx.x;
    #pragma unroll
    for(int k=0;k<2;k++){
        swl[t + 256*k] = ((const float4*)wl)[t + 256*k];
        swr[t + 256*k] = ((const float4*)wr)[t + 256*k];
    }
    __syncthreads();

    int w = t>>6, l = t&63;
    int jg = l&7, j0 = jg*4, ng = l>>3;
    int nb = blockIdx.x*128 + w*32 + ng*4;
    int nn[4];
    #pragma unroll
    for(int k=0;k<4;k++) nn[k] = (nb+k < N_NODES) ? nb+k : N_NODES-1;

    float a[4][4];
    float4 blv = ld4(bl + j0);
    #pragma unroll
    for(int k=0;k<4;k++){ a[k][0]=blv.x; a[k][1]=blv.y; a[k][2]=blv.z; a[k][3]=blv.w; }
    #pragma unroll 4
    for(int i=0;i<64;i+=4){
        float4 rm[4], rh[4];
        #pragma unroll
        for(int k=0;k<4;k++){
            rm[k] = ld4(m3 + (size_t)nn[k]*64 + i);
            uint2 hw = *(const uint2*)(h3bf + (size_t)nn[k]*32 + (i>>1));
            rh[k].x = uf(hw.x<<16); rh[k].y = uf(hw.x & 0xffff0000u);
            rh[k].z = uf(hw.y<<16); rh[k].w = uf(hw.y & 0xffff0000u);
        }
        #pragma unroll
        for(int ii=0;ii<4;ii++){
            float4 wL = swl[(i+ii)*8 + jg];
            float4 wR = swr[(i+ii)*8 + jg];
            #pragma unroll
            for(int k=0;k<4;k++){
                float vm = fc(rm[k],ii), vh = fc(rh[k],ii);
                a[k][0] = fmaf(vm,wL.x, fmaf(vh,wR.x, a[k][0]));
                a[k][1] = fmaf(vm,wL.y, fmaf(vh,wR.y, a[k][1]));
                a[k][2] = fmaf(vm,wL.z, fmaf(vh,wR.z, a[k][2]));
                a[k][3] = fmaf(vm,wL.w, fmaf(vh,wR.w, a[k][3]));
            }
        }
    }
    float4 bw = ld4(bnw + j0), bb = ld4(bnb + j0);
    #pragma unroll
    for(int k=0;k<4;k++){
        if(nb+k < N_NODES){
            float4 o;
            o.x = fmaxf(a[k][0]*(bw.x*BN_RSQRT)+bb.x,0.f);
            o.y = fmaxf(a[k][1]*(bw.y*BN_RSQRT)+bb.y,0.f);
            o.z = fmaxf(a[k][2]*(bw.z*BN_RSQRT)+bb.z,0.f);
            o.w = fmaxf(a[k][3]*(bw.w*BN_RSQRT)+bb.w,0.f);
            *(float4*)(out + (size_t)(nb+k)*32 + j0) = o;
        }
    }
}

// ---------------- launch ----------------
extern "C" void kernel_launch(void* const* d_in, const int* in_sizes, int n_in,
                              void* d_out, int out_size, void* d_ws, size_t ws_size,
                              hipStream_t stream){
    const float* x    = (const float*)d_in[0];
    const int*   ei   = (const int*)  d_in[1];
    const float* ea   = (const float*)d_in[2];
    const float* i1w1 = (const float*)d_in[3];
    const float* i1b1 = (const float*)d_in[4];
    const float* i1w2 = (const float*)d_in[5];
    const float* i1b2 = (const float*)d_in[6];
    const float* i2w1 = (const float*)d_in[7];
    const float* i2b1 = (const float*)d_in[8];
    const float* i2w2 = (const float*)d_in[9];
    const float* i2b2 = (const float*)d_in[10];
    const float* i3w1 = (const float*)d_in[11];
    const float* i3b1 = (const float*)d_in[12];
    const float* i3w2 = (const float*)d_in[13];
    const float* i3b2 = (const float*)d_in[14];
    const float* c1wl = (const float*)d_in[15];
    const float* c1bl = (const float*)d_in[16];
    const float* c1wr = (const float*)d_in[17];
    const float* c2wl = (const float*)d_in[18];
    const float* c2bl = (const float*)d_in[19];
    const float* c2wr = (const float*)d_in[20];
    const float* c3wl = (const float*)d_in[21];
    const float* c3bl = (const float*)d_in[22];
    const float* c3wr = (const float*)d_in[23];
    const float* bn1w = (const float*)d_in[24];
    const float* bn1b = (const float*)d_in[25];
    const float* bn2w = (const float*)d_in[26];
    const float* bn2b = (const float*)d_in[27];
    const float* bn3w = (const float*)d_in[28];
    const float* bn3b = (const float*)d_in[29];

    char* ws = (char*)d_ws;
    int*      bcnt = (int*)     (ws + o_bcnt);
    int*      bst  = (int*)     (ws + o_bst);
    int*      gb   = (int*)     (ws + o_gb);
    int*      offs = (int*)     (ws + o_off);
    int*      srcp = (int*)     (ws + o_srcp);
    float4*   epk  = (float4*)  (ws + o_epk);
    unsigned* recD = (unsigned*)(ws + o_rec);
    float*    U1   = (float*)   (ws + o_U1);
    float*    U2   = (float*)   (ws + o_U2);
    float*    U3   = (float*)   (ws + o_U3);
    float*    gs   = (float*)   (ws + o_gs);
    float*    h1   = (float*)   (ws + o_h1);
    float*    m1   = (float*)   (ws + o_m1);
    unsigned* h2bf = (unsigned*)(ws + o_h2bf);
    unsigned* h3bf = (unsigned*)(ws + o_h3bf);
    float*    m2   = (float*)   (ws + o_m2);
    float*    m3   = (float*)   (ws + o_m3);

    const int* src = ei;              // edge_index[0]
    const int* dst = ei + N_EDGES;    // edge_index[1]

    // bin counts -> bin starts (no per-node global histogram)
    hipMemsetAsync(bcnt, 0, 512*4, stream);
    khistBin <<<NHCHUNK, 256, 0, stream>>>(dst, bcnt);
    kscanBin <<<1,       512, 0, stream>>>(bcnt, bst, gb);
    // two-pass LDS-staged counting sort (dense writes); kbinB also emits the CSR offs
    kbinA  <<<NCHUNK, 256, 0, stream>>>(src, dst, ea, gb, recD);
    kbinB  <<<NB,     512, 0, stream>>>((const uint4*)recD, bst, offs, srcp, epk);

    // fused 3x inject edge accumulation (sequential epk reads, gate preloaded)
    kinject <<<N_NODES/4, 256, 0, stream>>>(epk, offs,
                                            i1w1, i1b1, i2w1, i2b1, i3w1, i3b1,
                                            U1, U2, U3, gs);
    // layer 1
    kdense0 <<<N_NODES*16/256, 256, 0, stream>>>(x, U1, gs, i1w2, i1b2, h1);
    kgather16<<<N_NODES/4, 256, 0, stream>>>(h1, srcp, offs, m1);
    kdense1 <<<(N_NODES+63)/64, 256, 0, stream>>>(m1, h1, U2, gs,
                                                 c1wl, c1bl, c1wr, i2w2, i2b2,
                                                 bn1w, bn1b, h2bf);
    // layer 2
    kgather64bf<<<N_NODES/4, 256, 0, stream>>>(h2bf, srcp, offs, m2);
    kdense2 <<<(N_NODES+63)/64, 256, 0, stream>>>(m2, h2bf, U3, gs,
                                                 c2wl, c2bl, c2wr, i3w2, i3b2,
                                                 bn2w, bn2b, h3bf);
    // layer 3
    kgather64bf<<<N_NODES/4, 256, 0, stream>>>(h3bf, srcp, offs, m3);
    kdense3 <<<(N_NODES+127)/128, 256, 0, stream>>>(m3, h3bf, c3wl, c3bl, c3wr,
                                                 bn3w, bn3b, (float*)d_out);
}

// Round 9
// 750.257 us; speedup vs baseline: 1.6769x; 1.0411x over previous
//
#include <hip/hip_runtime.h>
#include <math.h>

#define N_NODES 100000
#define N_EDGES 3200000
#define NB 391         // bins of 256 nodes: ceil(100000/256)
#define CHUNK 4096
#define NCHUNK 782     // ceil(3200000/4096)
#define HCHUNK 4096
#define NHCHUNK 782
#define CAPB 10240     // pass-B perm capacity (mean 8184, sigma ~90)

// ---------------- workspace layout ----------------
constexpr size_t al512(size_t x){ return (x + 511) & ~size_t(511); }
constexpr size_t o_bcnt = 0;                                          // int[512] per-bin counts
constexpr size_t o_bst  = al512(o_bcnt + 512*4);                      // int[512] bin starts
constexpr size_t o_gb   = al512(o_bst  + 512*4);                      // int[512] per-bin reservation ptrs
constexpr size_t o_off  = al512(o_gb   + 512*4);                      // int[N+1] CSR offsets (written by kbinB)
constexpr size_t o_srcp = al512(o_off  + ((size_t)N_NODES+1)*4);      // int[E] src permuted by dst
constexpr size_t o_epk  = al512(o_srcp + (size_t)N_EDGES*4);          // float4[E] {e0,e1,e2,gate}; DEAD after kinject
constexpr size_t o_U1   = al512(o_epk  + (size_t)N_EDGES*16);         // f[N*16]
constexpr size_t o_U2   = al512(o_U1   + (size_t)N_NODES*16*4);       // f[N*64]
constexpr size_t o_U3   = o_U2 + (size_t)N_NODES*64*4;                // f[N*64]
constexpr size_t o_gs   = al512(o_U3   + (size_t)N_NODES*64*4);       // f[N] gate sums
constexpr size_t o_h1   = al512(o_gs   + (size_t)N_NODES*4);          // f[N*16]
constexpr size_t o_m1   = al512(o_h1   + (size_t)N_NODES*16*4);       // f[N*16]
// aliases into dead regions (sequential-stream liveness):
constexpr size_t o_rec  = o_U2;    // dword[3E] staged records (38.4 MB < U2+U3 51.2 MB); dead before kinject writes U2/U3
constexpr size_t o_h2bf = o_epk;                              // bf16 h2 rows (12.8 MB); epk dead after kinject
constexpr size_t o_h3bf = o_epk + (size_t)N_NODES*128;        // bf16 h3 rows (12.8 MB)
constexpr size_t o_m2   = o_U2;    // f32 [N,64]; U2 dead after kdense1
constexpr size_t o_y3   = o_U3;    // bf16 [N,32] (6.4 MB); U3 dead after kdense2
constexpr size_t o_m3p  = o_U2;    // f32 [N,32] (12.8 MB); m2 dead after kdense2

#define BN_RSQRT 0.9999950000374997f   // 1/sqrt(1+1e-5)

__device__ __forceinline__ float4 ld4(const float* p){ return *(const float4*)p; }
__device__ __forceinline__ float fc(const float4& v, int i){ return ((const float*)&v)[i]; }
__device__ __forceinline__ float uf(unsigned u){ return __uint_as_float(u); }

// f32 -> bf16 bits, round-to-nearest-even
__device__ __forceinline__ unsigned f2bf(float x){
    unsigned u = __float_as_uint(x);
    u += 0x7fffu + ((u >> 16) & 1u);
    return u >> 16;
}

// ---------------- bin histogram (LDS-aggregated) ----------------
__global__ __launch_bounds__(256) void khistBin(const int* __restrict__ dst,
                                                int* __restrict__ binCnt){
    __shared__ int c[NB];
    int t = threadIdx.x;
    for(int i=t; i<NB; i+=256) c[i] = 0;
    __syncthreads();
    long base = (long)blockIdx.x*HCHUNK;
    int nrem = (int)(N_EDGES - base); if(nrem > HCHUNK) nrem = HCHUNK;
    for(int k=t; k<nrem; k+=256)
        atomicAdd(&c[dst[base+k] >> 8], 1);
    __syncthreads();
    for(int i=t; i<NB; i+=256)
        if(c[i]) atomicAdd(&binCnt[i], c[i]);
}

__global__ __launch_bounds__(512) void kscanBin(const int* __restrict__ binCnt,
                                                int* __restrict__ binStart,
                                                int* __restrict__ gbase){
    __shared__ int s[512];
    int t = threadIdx.x;
    int v = (t < NB) ? binCnt[t] : 0;
    s[t] = v; __syncthreads();
    for(int off=1; off<512; off<<=1){
        int a = (t>=off) ? s[t-off] : 0;
        __syncthreads(); s[t] += a; __syncthreads();
    }
    int ex = (t==0) ? 0 : s[t-1];
    if(t < NB){ binStart[t] = ex; gbase[t] = ex; }
    if(t == NB) binStart[NB] = s[NB-1];
}

// ---------------- pass A: LDS-staged binning, 12-B records ----------------
// record (3 dwords): {src | nib<<17, (e1|e0) bf16x2, e2 f32}, nib = dst & 255
__global__ __launch_bounds__(256) void kbinA(const int* __restrict__ src,
                                             const int* __restrict__ dst,
                                             const float* __restrict__ ea,
                                             int* __restrict__ gbase,
                                             unsigned* __restrict__ recD){
    __shared__ int cnt[NB], lofs[NB], gst[NB], lcnt[NB];
    __shared__ int sscan[256];
    __shared__ unsigned stage[CHUNK*3];
    __shared__ unsigned short binOf[CHUNK];
    int t = threadIdx.x;
    long e0i = (long)blockIdx.x*CHUNK;
    int nrem = (int)(N_EDGES - e0i); if(nrem > CHUNK) nrem = CHUNK;
    if(nrem <= 0) return;

    for(int b=t; b<NB; b+=256){ cnt[b]=0; lcnt[b]=0; }
    __syncthreads();
    for(int k=t; k<nrem; k+=256)
        atomicAdd(&cnt[dst[e0i+k] >> 8], 1);
    __syncthreads();
    int c0 = (2*t   < NB) ? cnt[2*t]   : 0;
    int c1 = (2*t+1 < NB) ? cnt[2*t+1] : 0;
    sscan[t] = c0 + c1;
    __syncthreads();
    for(int off=1; off<256; off<<=1){
        int v = (t>=off) ? sscan[t-off] : 0;
        __syncthreads(); sscan[t] += v; __syncthreads();
    }
    int base = (t==0) ? 0 : sscan[t-1];
    if(2*t   < NB) lofs[2*t]   = base;
    if(2*t+1 < NB) lofs[2*t+1] = base + c0;
    for(int b=t; b<NB; b+=256){
        int c = cnt[b];
        gst[b] = c ? atomicAdd(&gbase[b], c) : 0;
    }
    __syncthreads();
    for(int k=t; k<nrem; k+=256){
        long i = e0i + k;
        int d = dst[i];
        int s = src[i];
        float a0 = ea[i*3+0], a1 = ea[i*3+1], a2 = ea[i*3+2];
        int b = d >> 8;
        int p = lofs[b] + atomicAdd(&lcnt[b], 1);
        stage[3*p+0] = (unsigned)s | ((unsigned)(d & 255) << 17);
        stage[3*p+1] = (f2bf(a1)<<16) | f2bf(a0);
        stage[3*p+2] = __float_as_uint(a2);
        binOf[p] = (unsigned short)b;
    }
    __syncthreads();
    int total3 = nrem*3;
    for(int q=t; q<total3; q+=256){
        int p = q/3;
        int r = q - 3*p;
        int b = binOf[p];
        int g = gst[b] + (p - lofs[b]);
        recD[(size_t)3*g + r] = stage[q];
    }
}

// ---------------- pass B: per-bucket CSR-slice build + perm sort + gate precompute ----------------
__global__ __launch_bounds__(512) void kbinB(const unsigned* __restrict__ recD,
                                             const int* __restrict__ binStart,
                                             int* __restrict__ offs,
                                             int* __restrict__ srcp,
                                             float4* __restrict__ epk){
    __shared__ int pfx[257], lcnt[256];
    __shared__ int sscan[256];
    __shared__ unsigned short perm[CAPB];
    __shared__ unsigned char  nibOf[CAPB];
    int t = threadIdx.x;
    int b = blockIdx.x;
    int n0 = b*256;
    int nn = N_NODES - n0; if(nn > 256) nn = 256;
    int base = binStart[b];
    int m    = binStart[b+1] - base;
    for(int i=t; i<256; i+=512) lcnt[i] = 0;
    __syncthreads();
    for(int p=t; p<m; p+=512){
        unsigned w0 = recD[(size_t)3*(base+p)];
        int nib = (int)((w0 >> 17) & 255u);
        if(p < CAPB) nibOf[p] = (unsigned char)nib;
        atomicAdd(&lcnt[nib], 1);
    }
    __syncthreads();
    if(t < 256) sscan[t] = lcnt[t];
    __syncthreads();
    if(t < 256){
        for(int off=1; off<256; off<<=1){
            int v = (t>=off) ? sscan[t-off] : 0;
            __syncthreads(); sscan[t] += v; __syncthreads();
        }
        pfx[t+1] = sscan[t];
        if(t==0) pfx[0] = 0;
    } else {
        for(int off=1; off<256; off<<=1){ __syncthreads(); __syncthreads(); }
    }
    __syncthreads();
    for(int i=t; i<=nn; i+=512) offs[n0+i] = base + pfx[i];
    for(int i=t; i<256; i+=512) lcnt[i] = 0;
    __syncthreads();
    for(int p=t; p<m; p+=512){
        int nib = nibOf[p];
        int slot = pfx[nib] + atomicAdd(&lcnt[nib], 1);
        perm[slot] = (unsigned short)p;
    }
    __syncthreads();
    for(int s=t; s<m; s+=512){
        size_t q = (size_t)3*(base + (int)perm[s]);
        unsigned w0 = recD[q], w1 = recD[q+1], w2 = recD[q+2];
        float e2 = uf(w2);
        float gate = __builtin_amdgcn_rcpf(1.f + __expf(-e2));
        srcp[base+s] = (int)(w0 & 0x1FFFFu);
        epk [base+s] = make_float4(uf(w1<<16), uf(w1 & 0xffff0000u), e2, gate);
    }
}

// ---------------- fused 3-inject: 4 edges per wave (16-lane groups) ----------------
__global__ __launch_bounds__(256) void kinject(const float4* __restrict__ epk, const int* __restrict__ offs,
                        const float* __restrict__ w11, const float* __restrict__ b11,
                        const float* __restrict__ w12, const float* __restrict__ b12,
                        const float* __restrict__ w13, const float* __restrict__ b13,
                        float* __restrict__ U1, float* __restrict__ U2,
                        float* __restrict__ U3, float* __restrict__ gsum){
    int gid = blockIdx.x*blockDim.x + threadIdx.x;
    int node = gid >> 6;
    if(node >= N_NODES) return;
    int lane = threadIdx.x & 63;
    int q = lane >> 4, j = lane & 15;
    // inj1: output col j; inj2/inj3: cols j+16k, k=0..3
    float wa1=w11[j], wb1=w11[16+j], wc1=w11[32+j], bb1=b11[j];
    float wa2[4], wb2[4], wc2[4], bv2[4], wa3[4], wb3[4], wc3[4], bv3[4];
    #pragma unroll
    for(int k=0;k<4;k++){
        int c = j + 16*k;
        wa2[k]=w12[c]; wb2[k]=w12[64+c]; wc2[k]=w12[128+c]; bv2[k]=b12[c];
        wa3[k]=w13[c]; wb3[k]=w13[64+c]; wc3[k]=w13[128+c]; bv3[k]=b13[c];
    }
    int beg = offs[node], end = offs[node+1];
    float a1=0.f, g=0.f;
    float a2[4] = {0.f,0.f,0.f,0.f};
    float a3[4] = {0.f,0.f,0.f,0.f};
    for(int e=beg; e<end; e+=8){
        int ee0 = e + q, ee1 = e + 4 + q;
        float4 r0 = make_float4(0.f,0.f,0.f,0.f);
        float4 r1 = make_float4(0.f,0.f,0.f,0.f);
        if(ee0 < end) r0 = epk[ee0];
        if(ee1 < end) r1 = epk[ee1];
        {
            float h = fmaf(r0.z,wc1, fmaf(r0.y,wb1, fmaf(r0.x,wa1, bb1)));
            a1 = fmaf(fmaxf(h,0.f), r0.w, a1);
            #pragma unroll
            for(int k=0;k<4;k++){
                float h2 = fmaf(r0.z,wc2[k], fmaf(r0.y,wb2[k], fmaf(r0.x,wa2[k], bv2[k])));
                a2[k] = fmaf(fmaxf(h2,0.f), r0.w, a2[k]);
                float h3 = fmaf(r0.z,wc3[k], fmaf(r0.y,wb3[k], fmaf(r0.x,wa3[k], bv3[k])));
                a3[k] = fmaf(fmaxf(h3,0.f), r0.w, a3[k]);
            }
            g += r0.w;
        }
        {
            float h = fmaf(r1.z,wc1, fmaf(r1.y,wb1, fmaf(r1.x,wa1, bb1)));
            a1 = fmaf(fmaxf(h,0.f), r1.w, a1);
            #pragma unroll
            for(int k=0;k<4;k++){
                float h2 = fmaf(r1.z,wc2[k], fmaf(r1.y,wb2[k], fmaf(r1.x,wa2[k], bv2[k])));
                a2[k] = fmaf(fmaxf(h2,0.f), r1.w, a2[k]);
                float h3 = fmaf(r1.z,wc3[k], fmaf(r1.y,wb3[k], fmaf(r1.x,wa3[k], bv3[k])));
                a3[k] = fmaf(fmaxf(h3,0.f), r1.w, a3[k]);
            }
            g += r1.w;
        }
    }
    // cross-group reduction (sum over the 4 edge-slots)
    #pragma unroll
    for(int k=0;k<4;k++){
        a2[k] += __shfl_xor(a2[k], 16); a2[k] += __shfl_xor(a2[k], 32);
        a3[k] += __shfl_xor(a3[k], 16); a3[k] += __shfl_xor(a3[k], 32);
    }
    a1 += __shfl_xor(a1, 16); a1 += __shfl_xor(a1, 32);
    g  += __shfl_xor(g, 16);  g  += __shfl_xor(g, 32);
    // lane 'lane' owns dim lane = j + 16q -> register index q
    float v2 = (q==0) ? a2[0] : (q==1) ? a2[1] : (q==2) ? a2[2] : a2[3];
    float v3 = (q==0) ? a3[0] : (q==1) ? a3[1] : (q==2) ? a3[2] : a3[3];
    U2[(size_t)node*64 + lane] = v2;
    U3[(size_t)node*64 + lane] = v3;
    if(lane < 16) U1[node*16 + j] = a1;
    if(lane == 0) gsum[node] = g;
}

// ---------------- SAGE mean gathers ----------------
__global__ void kgather16(const float* __restrict__ h, const int* __restrict__ srcp,
                          const int* __restrict__ offs, float* __restrict__ m){
    int gid = blockIdx.x*blockDim.x + threadIdx.x;
    int node = gid >> 6;
    if(node >= N_NODES) return;
    int lane = threadIdx.x & 63;
    int q = lane >> 4, d = lane & 15;
    int beg = offs[node], end = offs[node+1];
    float acc = 0.f;
    for(int e=beg+q; e<end; e+=4) acc += h[(size_t)srcp[e]*16 + d];
    acc += __shfl_down(acc, 32);
    acc += __shfl_down(acc, 16);
    if(lane < 16){
        float c = fmaxf((float)(end-beg), 1.f);
        m[node*16 + lane] = acc / c;
    }
}

// bf16 64-dim rows; 4 edges/iter: 16-lane group per edge, uint2 (4 dims) per lane
__global__ void kgather64bf(const unsigned* __restrict__ hbf, const int* __restrict__ srcp,
                            const int* __restrict__ offs, float* __restrict__ m){
    int gid = blockIdx.x*blockDim.x + threadIdx.x;
    int node = gid >> 6;
    if(node >= N_NODES) return;
    int lane = threadIdx.x & 63;
    int q = lane >> 4, j = lane & 15;
    int beg = offs[node], end = offs[node+1];
    float4 acc = make_float4(0.f,0.f,0.f,0.f);
    for(int e=beg; e<end; e+=4){
        int ee = e + q;
        if(ee < end){
            int s = srcp[ee];
            uint2 w = *(const uint2*)(hbf + (size_t)s*32 + 2*j);
            acc.x += uf(w.x<<16); acc.y += uf(w.x & 0xffff0000u);
            acc.z += uf(w.y<<16); acc.w += uf(w.y & 0xffff0000u);
        }
    }
    acc.x += __shfl_xor(acc.x,16); acc.x += __shfl_xor(acc.x,32);
    acc.y += __shfl_xor(acc.y,16); acc.y += __shfl_xor(acc.y,32);
    acc.z += __shfl_xor(acc.z,16); acc.z += __shfl_xor(acc.z,32);
    acc.w += __shfl_xor(acc.w,16); acc.w += __shfl_xor(acc.w,32);
    if(lane < 16){
        float inv = 1.f / fmaxf((float)(end-beg), 1.f);
        float4 o; o.x=acc.x*inv; o.y=acc.y*inv; o.z=acc.z*inv; o.w=acc.w*inv;
        *(float4*)(m + (size_t)node*64 + 4*j) = o;
    }
}

// bf16 32-dim rows (y3); 8 edges/iter (2-deep ILP), uint (2 dims) per lane
__global__ void kgather32bf(const unsigned* __restrict__ y3, const int* __restrict__ srcp,
                            const int* __restrict__ offs, float* __restrict__ m){
    int gid = blockIdx.x*blockDim.x + threadIdx.x;
    int node = gid >> 6;
    if(node >= N_NODES) return;
    int lane = threadIdx.x & 63;
    int q = lane >> 4, j = lane & 15;
    int beg = offs[node], end = offs[node+1];
    float ax=0.f, ay=0.f;
    for(int e=beg; e<end; e+=8){
        int ee0 = e + q, ee1 = e + 4 + q;
        if(ee0 < end){
            unsigned w = y3[(size_t)srcp[ee0]*16 + j];
            ax += uf(w<<16); ay += uf(w & 0xffff0000u);
        }
        if(ee1 < end){
            unsigned w = y3[(size_t)srcp[ee1]*16 + j];
            ax += uf(w<<16); ay += uf(w & 0xffff0000u);
        }
    }
    ax += __shfl_xor(ax,16); ax += __shfl_xor(ax,32);
    ay += __shfl_xor(ay,16); ay += __shfl_xor(ay,32);
    if(lane < 16){
        float inv = 1.f / fmaxf((float)(end-beg), 1.f);
        float2 o; o.x = ax*inv; o.y = ay*inv;
        *(float2*)(m + (size_t)node*32 + 2*j) = o;
    }
}

// ---------------- dense per-node kernels ----------------

// h1 = x + U1 @ w2_1 + gs * b2_1            [N,16]
__global__ __launch_bounds__(256) void kdense0(const float* __restrict__ x, const float* __restrict__ U1,
                        const float* __restrict__ gs, const float* __restrict__ w2,
                        const float* __restrict__ b2, float* __restrict__ h1){
    __shared__ float sw[256];
    int t = threadIdx.x;
    sw[t] = w2[t];
    __syncthreads();
    int idx = blockIdx.x*256 + t;
    int n = idx >> 4, j = idx & 15;
    float acc = x[idx] + gs[n]*b2[j];
    const float4* row = (const float4*)(U1 + n*16);
    #pragma unroll
    for(int i4=0;i4<4;i4++){
        float4 r = row[i4];
        acc += r.x*sw[(i4*4+0)*16 + j];
        acc += r.y*sw[(i4*4+1)*16 + j];
        acc += r.z*sw[(i4*4+2)*16 + j];
        acc += r.w*sw[(i4*4+3)*16 + j];
    }
    h1[idx] = acc;
}

// h2bf = bf16( relu(bn1(m1@wl + h1@wr + bl)) + U2@w2_2 + gs*b2_2 )   [N,64]
__global__ __launch_bounds__(256) void kdense1(const float* __restrict__ m1, const float* __restrict__ h1,
                        const float* __restrict__ U2, const float* __restrict__ gs,
                        const float* __restrict__ wl, const float* __restrict__ bl,
                        const float* __restrict__ wr,
                        const float* __restrict__ w2, const float* __restrict__ b2,
                        const float* __restrict__ bnw, const float* __restrict__ bnb,
                        unsigned* __restrict__ h2bf){
    __shared__ float4 swl[16*16];
    __shared__ float4 swr[16*16];
    __shared__ float4 sw2[64*16];
    int t = threadIdx.x;
    swl[t] = ((const float4*)wl)[t];
    swr[t] = ((const float4*)wr)[t];
    #pragma unroll
    for(int k=0;k<4;k++) sw2[t + 256*k] = ((const float4*)w2)[t + 256*k];
    __syncthreads();

    int w = t>>6, l = t&63;
    int jg = l&15, j0 = jg*4, ng = l>>4;
    int nb = blockIdx.x*64 + w*16 + ng*4;
    int nn[4];
    #pragma unroll
    for(int k=0;k<4;k++) nn[k] = (nb+k < N_NODES) ? nb+k : N_NODES-1;

    float a[4][4], b[4][4];
    float4 blv = ld4(bl + j0);
    float4 b2v = ld4(b2 + j0);
    #pragma unroll
    for(int k=0;k<4;k++){
        float g = gs[nn[k]];
        a[k][0]=blv.x; a[k][1]=blv.y; a[k][2]=blv.z; a[k][3]=blv.w;
        b[k][0]=g*b2v.x; b[k][1]=g*b2v.y; b[k][2]=g*b2v.z; b[k][3]=g*b2v.w;
    }
    #pragma unroll
    for(int i=0;i<16;i+=4){
        float4 rm[4], rh[4];
        #pragma unroll
        for(int k=0;k<4;k++){ rm[k] = ld4(m1 + nn[k]*16 + i); rh[k] = ld4(h1 + nn[k]*16 + i); }
        #pragma unroll
        for(int ii=0;ii<4;ii++){
            float4 wL = swl[(i+ii)*16 + jg];
            float4 wR = swr[(i+ii)*16 + jg];
            #pragma unroll
            for(int k=0;k<4;k++){
                float vm = fc(rm[k],ii), vh = fc(rh[k],ii);
                a[k][0] = fmaf(vm,wL.x, fmaf(vh,wR.x, a[k][0]));
                a[k][1] = fmaf(vm,wL.y, fmaf(vh,wR.y, a[k][1]));
                a[k][2] = fmaf(vm,wL.z, fmaf(vh,wR.z, a[k][2]));
                a[k][3] = fmaf(vm,wL.w, fmaf(vh,wR.w, a[k][3]));
            }
        }
    }
    #pragma unroll 4
    for(int i=0;i<64;i+=4){
        float4 ru[4];
        #pragma unroll
        for(int k=0;k<4;k++) ru[k] = ld4(U2 + (size_t)nn[k]*64 + i);
        #pragma unroll
        for(int ii=0;ii<4;ii++){
            float4 wv = sw2[(i+ii)*16 + jg];
            #pragma unroll
            for(int k=0;k<4;k++){
                float vu = fc(ru[k],ii);
                b[k][0] = fmaf(vu,wv.x,b[k][0]);
                b[k][1] = fmaf(vu,wv.y,b[k][1]);
                b[k][2] = fmaf(vu,wv.z,b[k][2]);
                b[k][3] = fmaf(vu,wv.w,b[k][3]);
            }
        }
    }
    float4 bw = ld4(bnw + j0), bb = ld4(bnb + j0);
    #pragma unroll
    for(int k=0;k<4;k++){
        if(nb+k < N_NODES){
            float ox = fmaxf(a[k][0]*(bw.x*BN_RSQRT)+bb.x,0.f) + b[k][0];
            float oy = fmaxf(a[k][1]*(bw.y*BN_RSQRT)+bb.y,0.f) + b[k][1];
            float oz = fmaxf(a[k][2]*(bw.z*BN_RSQRT)+bb.z,0.f) + b[k][2];
            float ow = fmaxf(a[k][3]*(bw.w*BN_RSQRT)+bb.w,0.f) + b[k][3];
            uint2 pk; pk.x = f2bf(ox) | (f2bf(oy)<<16); pk.y = f2bf(oz) | (f2bf(ow)<<16);
            *(uint2*)(h2bf + (size_t)(nb+k)*32 + (j0>>1)) = pk;
        }
    }
}

// h3bf = bf16( relu(bn2(m2@wl + h2@wr + bl)) + U3@w2_3 + gs*b2_3 )   [N,64]
__global__ __launch_bounds__(256) void kdense2(const float* __restrict__ m2, const unsigned* __restrict__ h2bf,
                        const float* __restrict__ U3, const float* __restrict__ gs,
                        const float* __restrict__ wl, const float* __restrict__ bl,
                        const float* __restrict__ wr,
                        const float* __restrict__ w2, const float* __restrict__ b2,
                        const float* __restrict__ bnw, const float* __restrict__ bnb,
                        unsigned* __restrict__ h3bf){
    __shared__ float4 swl[64*16];
    __shared__ float4 swr[64*16];
    __shared__ float4 sw2[64*16];
    int t = threadIdx.x;
    #pragma unroll
    for(int k=0;k<4;k++){
        swl[t + 256*k] = ((const float4*)wl)[t + 256*k];
        swr[t + 256*k] = ((const float4*)wr)[t + 256*k];
        sw2[t + 256*k] = ((const float4*)w2)[t + 256*k];
    }
    __syncthreads();

    int w = t>>6, l = t&63;
    int jg = l&15, j0 = jg*4, ng = l>>4;
    int nb = blockIdx.x*64 + w*16 + ng*4;
    int nn[4];
    #pragma unroll
    for(int k=0;k<4;k++) nn[k] = (nb+k < N_NODES) ? nb+k : N_NODES-1;

    float a[4][4], b[4][4];
    float4 blv = ld4(bl + j0);
    float4 b2v = ld4(b2 + j0);
    #pragma unroll
    for(int k=0;k<4;k++){
        float g = gs[nn[k]];
        a[k][0]=blv.x; a[k][1]=blv.y; a[k][2]=blv.z; a[k][3]=blv.w;
        b[k][0]=g*b2v.x; b[k][1]=g*b2v.y; b[k][2]=g*b2v.z; b[k][3]=g*b2v.w;
    }
    #pragma unroll 4
    for(int i=0;i<64;i+=4){
        float4 rm[4], rh[4];
        #pragma unroll
        for(int k=0;k<4;k++){
            rm[k] = ld4(m2 + (size_t)nn[k]*64 + i);
            uint2 hw = *(const uint2*)(h2bf + (size_t)nn[k]*32 + (i>>1));
            rh[k].x = uf(hw.x<<16); rh[k].y = uf(hw.x & 0xffff0000u);
            rh[k].z = uf(hw.y<<16); rh[k].w = uf(hw.y & 0xffff0000u);
        }
        #pragma unroll
        for(int ii=0;ii<4;ii++){
            float4 wL = swl[(i+ii)*16 + jg];
            float4 wR = swr[(i+ii)*16 + jg];
            #pragma unroll
            for(int k=0;k<4;k++){
                float vm = fc(rm[k],ii), vh = fc(rh[k],ii);
                a[k][0] = fmaf(vm,wL.x, fmaf(vh,wR.x, a[k][0]));
                a[k][1] = fmaf(vm,wL.y, fmaf(vh,wR.y, a[k][1]));
                a[k][2] = fmaf(vm,wL.z, fmaf(vh,wR.z, a[k][2]));
                a[k][3] = fmaf(vm,wL.w, fmaf(vh,wR.w, a[k][3]));
            }
        }
    }
    #pragma unroll 4
    for(int i=0;i<64;i+=4){
        float4 ru[4];
        #pragma unroll
        for(int k=0;k<4;k++) ru[k] = ld4(U3 + (size_t)nn[k]*64 + i);
        #pragma unroll
        for(int ii=0;ii<4;ii++){
            float4 wv = sw2[(i+ii)*16 + jg];
            #pragma unroll
            for(int k=0;k<4;k++){
                float vu = fc(ru[k],ii);
                b[k][0] = fmaf(vu,wv.x,b[k][0]);
                b[k][1] = fmaf(vu,wv.y,b[k][1]);
                b[k][2] = fmaf(vu,wv.z,b[k][2]);
                b[k][3] = fmaf(vu,wv.w,b[k][3]);
            }
        }
    }
    float4 bw = ld4(bnw + j0), bb = ld4(bnb + j0);
    #pragma unroll
    for(int k=0;k<4;k++){
        if(nb+k < N_NODES){
            float ox = fmaxf(a[k][0]*(bw.x*BN_RSQRT)+bb.x,0.f) + b[k][0];
            float oy = fmaxf(a[k][1]*(bw.y*BN_RSQRT)+bb.y,0.f) + b[k][1];
            float oz = fmaxf(a[k][2]*(bw.z*BN_RSQRT)+bb.z,0.f) + b[k][2];
            float ow = fmaxf(a[k][3]*(bw.w*BN_RSQRT)+bb.w,0.f) + b[k][3];
            uint2 pk; pk.x = f2bf(ox) | (f2bf(oy)<<16); pk.y = f2bf(oz) | (f2bf(ow)<<16);
            *(uint2*)(h3bf + (size_t)(nb+k)*32 + (j0>>1)) = pk;
        }
    }
}

// y3 = bf16( h3 @ wl3 )  [N,32] — pre-projection so the layer-3 gather moves half the bytes
__global__ __launch_bounds__(256) void kproj3(const unsigned* __restrict__ h3bf,
                                              const float* __restrict__ wl,
                                              unsigned* __restrict__ y3){
    __shared__ float4 swl[64*8];
    int t = threadIdx.x;
    #pragma unroll
    for(int k=0;k<2;k++) swl[t + 256*k] = ((const float4*)wl)[t + 256*k];
    __syncthreads();

    int w = t>>6, l = t&63;
    int jg = l&7, j0 = jg*4, ng = l>>3;
    int nb = blockIdx.x*128 + w*32 + ng*4;
    int nn[4];
    #pragma unroll
    for(int k=0;k<4;k++) nn[k] = (nb+k < N_NODES) ? nb+k : N_NODES-1;

    float a[4][4];
    #pragma unroll
    for(int k=0;k<4;k++){ a[k][0]=0.f; a[k][1]=0.f; a[k][2]=0.f; a[k][3]=0.f; }
    #pragma unroll 4
    for(int i=0;i<64;i+=4){
        float4 rh[4];
        #pragma unroll
        for(int k=0;k<4;k++){
            uint2 hw = *(const uint2*)(h3bf + (size_t)nn[k]*32 + (i>>1));
            rh[k].x = uf(hw.x<<16); rh[k].y = uf(hw.x & 0xffff0000u);
            rh[k].z = uf(hw.y<<16); rh[k].w = uf(hw.y & 0xffff0000u);
        }
        #pragma unroll
        for(int ii=0;ii<4;ii++){
            float4 wL = swl[(i+ii)*8 + jg];
            #pragma unroll
            for(int k=0;k<4;k++){
                float vh = fc(rh[k],ii);
                a[k][0] = fmaf(vh,wL.x,a[k][0]);
                a[k][1] = fmaf(vh,wL.y,a[k][1]);
                a[k][2] = fmaf(vh,wL.z,a[k][2]);
                a[k][3] = fmaf(vh,wL.w,a[k][3]);
            }
        }
    }
    #pragma unroll
    for(int k=0;k<4;k++){
        if(nb+k < N_NODES){
            uint2 pk;
            pk.x = f2bf(a[k][0]) | (f2bf(a[k][1])<<16);
            pk.y = f2bf(a[k][2]) | (f2bf(a[k][3])<<16);
            *(uint2*)(y3 + (size_t)(nb+k)*16 + (j0>>1)) = pk;
        }
    }
}

// out = relu(bn3(m3p + h3@wr + bl))        [N,32]; m3p already includes the @wl projection
__global__ __launch_bounds__(256) void kdense3(const float* __restrict__ m3p, const unsigned* __restrict__ h3bf,
                        const float* __restrict__ bl,
                        const float* __restrict__ wr,
                        const float* __restrict__ bnw, const float* __restrict__ bnb,
                        float* __restrict__ out){
    __shared__ float4 swr[64*8];
    int t = threadIdx.x;
    #pragma unroll
    for(int k=0;k<2;k++) swr[t + 256*k] = ((const float4*)wr)[t + 256*k];
    __syncthreads();

    int w = t>>6, l = t&63;
    int jg = l&7, j0 = jg*4, ng = l>>3;
    int nb = blockIdx.x*128 + w*32 + ng*4;
    int nn[4];
    #pragma unroll
    for(int k=0;k<4;k++) nn[k] = (nb+k < N_NODES) ? nb+k : N_NODES-1;

    float a[4][4];
    float4 blv = ld4(bl + j0);
    #pragma unroll
    for(int k=0;k<4;k++){
        float4 mp = ld4(m3p + (size_t)nn[k]*32 + j0);
        a[k][0]=blv.x+mp.x; a[k][1]=blv.y+mp.y; a[k][2]=blv.z+mp.z; a[k][3]=blv.w+mp.w;
    }
    #pragma unroll 4
    for(int i=0;i<64;i+=4){
        float4 rh[4];
        #pragma unroll
        for(int k=0;k<4;k++){
            uint2 hw = *(const uint2*)(h3bf + (size_t)nn[k]*32 + (i>>1));
            rh[k].x = uf(hw.x<<16); rh[k].y = uf(hw.x & 0xffff0000u);
            rh[k].z = uf(hw.y<<16); rh[k].w = uf(hw.y & 0xffff0000u);
        }
        #pragma unroll
        for(int ii=0;ii<4;ii++){
            float4 wR = swr[(i+ii)*8 + jg];
            #pragma unroll
            for(int k=0;k<4;k++){
                float vh = fc(rh[k],ii);
                a[k][0] = fmaf(vh,wR.x,a[k][0]);
                a[k][1] = fmaf(vh,wR.y,a[k][1]);
                a[k][2] = fmaf(vh,wR.z,a[k][2]);
                a[k][3] = fmaf(vh,wR.w,a[k][3]);
            }
        }
    }
    float4 bw = ld4(bnw + j0), bb = ld4(bnb + j0);
    #pragma unroll
    for(int k=0;k<4;k++){
        if(nb+k < N_NODES){
            float4 o;
            o.x = fmaxf(a[k][0]*(bw.x*BN_RSQRT)+bb.x,0.f);
            o.y = fmaxf(a[k][1]*(bw.y*BN_RSQRT)+bb.y,0.f);
            o.z = fmaxf(a[k][2]*(bw.z*BN_RSQRT)+bb.z,0.f);
            o.w = fmaxf(a[k][3]*(bw.w*BN_RSQRT)+bb.w,0.f);
            *(float4*)(out + (size_t)(nb+k)*32 + j0) = o;
        }
    }
}

// ---------------- launch ----------------
extern "C" void kernel_launch(void* const* d_in, const int* in_sizes, int n_in,
                              void* d_out, int out_size, void* d_ws, size_t ws_size,
                              hipStream_t stream){
    const float* x    = (const float*)d_in[0];
    const int*   ei   = (const int*)  d_in[1];
    const float* ea   = (const float*)d_in[2];
    const float* i1w1 = (const float*)d_in[3];
    const float* i1b1 = (const float*)d_in[4];
    const float* i1w2 = (const float*)d_in[5];
    const float* i1b2 = (const float*)d_in[6];
    const float* i2w1 = (const float*)d_in[7];
    const float* i2b1 = (const float*)d_in[8];
    const float* i2w2 = (const float*)d_in[9];
    const float* i2b2 = (const float*)d_in[10];
    const float* i3w1 = (const float*)d_in[11];
    const float* i3b1 = (const float*)d_in[12];
    const float* i3w2 = (const float*)d_in[13];
    const float* i3b2 = (const float*)d_in[14];
    const float* c1wl = (const float*)d_in[15];
    const float* c1bl = (const float*)d_in[16];
    const float* c1wr = (const float*)d_in[17];
    const float* c2wl = (const float*)d_in[18];
    const float* c2bl = (const float*)d_in[19];
    const float* c2wr = (const float*)d_in[20];
    const float* c3wl = (const float*)d_in[21];
    const float* c3bl = (const float*)d_in[22];
    const float* c3wr = (const float*)d_in[23];
    const float* bn1w = (const float*)d_in[24];
    const float* bn1b = (const float*)d_in[25];
    const float* bn2w = (const float*)d_in[26];
    const float* bn2b = (const float*)d_in[27];
    const float* bn3w = (const float*)d_in[28];
    const float* bn3b = (const float*)d_in[29];

    char* ws = (char*)d_ws;
    int*      bcnt = (int*)     (ws + o_bcnt);
    int*      bst  = (int*)     (ws + o_bst);
    int*      gb   = (int*)     (ws + o_gb);
    int*      offs = (int*)     (ws + o_off);
    int*      srcp = (int*)     (ws + o_srcp);
    float4*   epk  = (float4*)  (ws + o_epk);
    unsigned* recD = (unsigned*)(ws + o_rec);
    float*    U1   = (float*)   (ws + o_U1);
    float*    U2   = (float*)   (ws + o_U2);
    float*    U3   = (float*)   (ws + o_U3);
    float*    gs   = (float*)   (ws + o_gs);
    float*    h1   = (float*)   (ws + o_h1);
    float*    m1   = (float*)   (ws + o_m1);
    unsigned* h2bf = (unsigned*)(ws + o_h2bf);
    unsigned* h3bf = (unsigned*)(ws + o_h3bf);
    float*    m2   = (float*)   (ws + o_m2);
    unsigned* y3   = (unsigned*)(ws + o_y3);
    float*    m3p  = (float*)   (ws + o_m3p);

    const int* src = ei;              // edge_index[0]
    const int* dst = ei + N_EDGES;    // edge_index[1]

    // bin counts -> bin starts
    hipMemsetAsync(bcnt, 0, 512*4, stream);
    khistBin <<<NHCHUNK, 256, 0, stream>>>(dst, bcnt);
    kscanBin <<<1,       512, 0, stream>>>(bcnt, bst, gb);
    // two-pass LDS-staged counting sort (dense writes); kbinB also emits the CSR offs
    kbinA  <<<NCHUNK, 256, 0, stream>>>(src, dst, ea, gb, recD);
    kbinB  <<<NB,     512, 0, stream>>>(recD, bst, offs, srcp, epk);

    // fused 3x inject edge accumulation (4 edges/wave)
    kinject <<<N_NODES/4, 256, 0, stream>>>(epk, offs,
                                            i1w1, i1b1, i2w1, i2b1, i3w1, i3b1,
                                            U1, U2, U3, gs);
    // layer 1
    kdense0 <<<N_NODES*16/256, 256, 0, stream>>>(x, U1, gs, i1w2, i1b2, h1);
    kgather16<<<N_NODES/4, 256, 0, stream>>>(h1, srcp, offs, m1);
    kdense1 <<<(N_NODES+63)/64, 256, 0, stream>>>(m1, h1, U2, gs,
                                                 c1wl, c1bl, c1wr, i2w2, i2b2,
                                                 bn1w, bn1b, h2bf);
    // layer 2
    kgather64bf<<<N_NODES/4, 256, 0, stream>>>(h2bf, srcp, offs, m2);
    kdense2 <<<(N_NODES+63)/64, 256, 0, stream>>>(m2, h2bf, U3, gs,
                                                 c2wl, c2bl, c2wr, i3w2, i3b2,
                                                 bn2w, bn2b, h3bf);
    // layer 3: pre-project h3@wl, gather 32-dim, then finish
    kproj3  <<<(N_NODES+127)/128, 256, 0, stream>>>(h3bf, c3wl, y3);
    kgather32bf<<<N_NODES/4, 256, 0, stream>>>(y3, srcp, offs, m3p);
    kdense3 <<<(N_NODES+127)/128, 256, 0, stream>>>(m3p, h3bf, c3bl, c3wr,
                                                 bn3w, bn3b, (float*)d_out);
}

// Round 10
// 685.605 us; speedup vs baseline: 1.8350x; 1.0943x over previous
//
#include <hip/hip_runtime.h>
#include <math.h>

#define N_NODES 100000
#define N_EDGES 3200000
#define NB 391         // bins of 256 nodes: ceil(100000/256)
#define CHUNK 4096
#define NCHUNK 782     // ceil(3200000/4096)
#define HCHUNK 4096
#define NHCHUNK 782
#define CAPB 10240     // pass-B perm capacity (mean 8184, sigma ~90)

// ---------------- workspace layout ----------------
constexpr size_t al512(size_t x){ return (x + 511) & ~size_t(511); }
constexpr size_t o_bcnt = 0;                                          // int[512] per-bin counts
constexpr size_t o_bst  = al512(o_bcnt + 512*4);                      // int[512] bin starts
constexpr size_t o_gb   = al512(o_bst  + 512*4);                      // int[512] per-bin reservation ptrs
constexpr size_t o_off  = al512(o_gb   + 512*4);                      // int[N+1] CSR offsets (written by kbinB)
constexpr size_t o_srcp = al512(o_off  + ((size_t)N_NODES+1)*4);      // int[E] src permuted by dst
constexpr size_t o_epk  = al512(o_srcp + (size_t)N_EDGES*4);          // float4[E] {e0,e1,e2,gate}; DEAD after kinject
constexpr size_t o_U1   = al512(o_epk  + (size_t)N_EDGES*16);         // f[N*16]; DEAD after kdense0
constexpr size_t o_U2   = al512(o_U1   + (size_t)N_NODES*16*4);       // f[N*64]
constexpr size_t o_U3   = o_U2 + (size_t)N_NODES*64*4;                // f[N*64]
constexpr size_t o_gs   = al512(o_U3   + (size_t)N_NODES*64*4);       // f[N] gate sums
constexpr size_t o_h1   = al512(o_gs   + (size_t)N_NODES*4);          // f[N*16]
constexpr size_t o_m1   = al512(o_h1   + (size_t)N_NODES*16*4);       // f[N*16]
// aliases into dead regions (sequential-stream liveness):
constexpr size_t o_rec  = o_U2;    // dword[3E] staged records (38.4 MB < U2+U3 51.2 MB); dead before kinject writes U2/U3
constexpr size_t o_h2bf = o_epk;                              // bf16 h2 rows (12.8 MB); epk dead after kinject
constexpr size_t o_h3bf = o_epk + (size_t)N_NODES*128;        // bf16 h3 rows (12.8 MB)
constexpr size_t o_m2   = o_U2;    // f32 [N,64]; U2 dead after kdense1
constexpr size_t o_y3   = o_U1;    // bf16 [N,32] (6.4 MB = U1 exactly); U1 dead after kdense0; written by kdense2 epilogue
constexpr size_t o_m3p  = o_U2;    // f32 [N,32]; m2 dead after kdense2

#define BN_RSQRT 0.9999950000374997f   // 1/sqrt(1+1e-5)

__device__ __forceinline__ float4 ld4(const float* p){ return *(const float4*)p; }
__device__ __forceinline__ float fc(const float4& v, int i){ return ((const float*)&v)[i]; }
__device__ __forceinline__ float uf(unsigned u){ return __uint_as_float(u); }

// f32 -> bf16 bits, round-to-nearest-even
__device__ __forceinline__ unsigned f2bf(float x){
    unsigned u = __float_as_uint(x);
    u += 0x7fffu + ((u >> 16) & 1u);
    return u >> 16;
}

// ---------------- bin histogram (LDS-aggregated) ----------------
__global__ __launch_bounds__(256) void khistBin(const int* __restrict__ dst,
                                                int* __restrict__ binCnt){
    __shared__ int c[NB];
    int t = threadIdx.x;
    for(int i=t; i<NB; i+=256) c[i] = 0;
    __syncthreads();
    long base = (long)blockIdx.x*HCHUNK;
    int nrem = (int)(N_EDGES - base); if(nrem > HCHUNK) nrem = HCHUNK;
    for(int k=t; k<nrem; k+=256)
        atomicAdd(&c[dst[base+k] >> 8], 1);
    __syncthreads();
    for(int i=t; i<NB; i+=256)
        if(c[i]) atomicAdd(&binCnt[i], c[i]);
}

__global__ __launch_bounds__(512) void kscanBin(const int* __restrict__ binCnt,
                                                int* __restrict__ binStart,
                                                int* __restrict__ gbase){
    __shared__ int s[512];
    int t = threadIdx.x;
    int v = (t < NB) ? binCnt[t] : 0;
    s[t] = v; __syncthreads();
    for(int off=1; off<512; off<<=1){
        int a = (t>=off) ? s[t-off] : 0;
        __syncthreads(); s[t] += a; __syncthreads();
    }
    int ex = (t==0) ? 0 : s[t-1];
    if(t < NB){ binStart[t] = ex; gbase[t] = ex; }
    if(t == NB) binStart[NB] = s[NB-1];
}

// ---------------- pass A: LDS-staged binning, 12-B records ----------------
// record (3 dwords): {src | nib<<17, (e1|e0) bf16x2, e2 f32}, nib = dst & 255
__global__ __launch_bounds__(256) void kbinA(const int* __restrict__ src,
                                             const int* __restrict__ dst,
                                             const float* __restrict__ ea,
                                             int* __restrict__ gbase,
                                             unsigned* __restrict__ recD){
    __shared__ int cnt[NB], lofs[NB], gst[NB], lcnt[NB];
    __shared__ int sscan[256];
    __shared__ unsigned stage[CHUNK*3];
    __shared__ unsigned short binOf[CHUNK];
    int t = threadIdx.x;
    long e0i = (long)blockIdx.x*CHUNK;
    int nrem = (int)(N_EDGES - e0i); if(nrem > CHUNK) nrem = CHUNK;
    if(nrem <= 0) return;

    for(int b=t; b<NB; b+=256){ cnt[b]=0; lcnt[b]=0; }
    __syncthreads();
    for(int k=t; k<nrem; k+=256)
        atomicAdd(&cnt[dst[e0i+k] >> 8], 1);
    __syncthreads();
    int c0 = (2*t   < NB) ? cnt[2*t]   : 0;
    int c1 = (2*t+1 < NB) ? cnt[2*t+1] : 0;
    sscan[t] = c0 + c1;
    __syncthreads();
    for(int off=1; off<256; off<<=1){
        int v = (t>=off) ? sscan[t-off] : 0;
        __syncthreads(); sscan[t] += v; __syncthreads();
    }
    int base = (t==0) ? 0 : sscan[t-1];
    if(2*t   < NB) lofs[2*t]   = base;
    if(2*t+1 < NB) lofs[2*t+1] = base + c0;
    for(int b=t; b<NB; b+=256){
        int c = cnt[b];
        gst[b] = c ? atomicAdd(&gbase[b], c) : 0;
    }
    __syncthreads();
    for(int k=t; k<nrem; k+=256){
        long i = e0i + k;
        int d = dst[i];
        int s = src[i];
        float a0 = ea[i*3+0], a1 = ea[i*3+1], a2 = ea[i*3+2];
        int b = d >> 8;
        int p = lofs[b] + atomicAdd(&lcnt[b], 1);
        stage[3*p+0] = (unsigned)s | ((unsigned)(d & 255) << 17);
        stage[3*p+1] = (f2bf(a1)<<16) | f2bf(a0);
        stage[3*p+2] = __float_as_uint(a2);
        binOf[p] = (unsigned short)b;
    }
    __syncthreads();
    int total3 = nrem*3;
    for(int q=t; q<total3; q+=256){
        int p = q/3;
        int r = q - 3*p;
        int b = binOf[p];
        int g = gst[b] + (p - lofs[b]);
        recD[(size_t)3*g + r] = stage[q];
    }
}

// ---------------- pass B: per-bucket CSR-slice build + perm sort + gate precompute ----------------
__global__ __launch_bounds__(512) void kbinB(const unsigned* __restrict__ recD,
                                             const int* __restrict__ binStart,
                                             int* __restrict__ offs,
                                             int* __restrict__ srcp,
                                             float4* __restrict__ epk){
    __shared__ int pfx[257], lcnt[256];
    __shared__ int sscan[256];
    __shared__ unsigned short perm[CAPB];
    __shared__ unsigned char  nibOf[CAPB];
    int t = threadIdx.x;
    int b = blockIdx.x;
    int n0 = b*256;
    int nn = N_NODES - n0; if(nn > 256) nn = 256;
    int base = binStart[b];
    int m    = binStart[b+1] - base;
    for(int i=t; i<256; i+=512) lcnt[i] = 0;
    __syncthreads();
    for(int p=t; p<m; p+=512){
        unsigned w0 = recD[(size_t)3*(base+p)];
        int nib = (int)((w0 >> 17) & 255u);
        if(p < CAPB) nibOf[p] = (unsigned char)nib;
        atomicAdd(&lcnt[nib], 1);
    }
    __syncthreads();
    if(t < 256) sscan[t] = lcnt[t];
    __syncthreads();
    if(t < 256){
        for(int off=1; off<256; off<<=1){
            int v = (t>=off) ? sscan[t-off] : 0;
            __syncthreads(); sscan[t] += v; __syncthreads();
        }
        pfx[t+1] = sscan[t];
        if(t==0) pfx[0] = 0;
    } else {
        for(int off=1; off<256; off<<=1){ __syncthreads(); __syncthreads(); }
    }
    __syncthreads();
    for(int i=t; i<=nn; i+=512) offs[n0+i] = base + pfx[i];
    for(int i=t; i<256; i+=512) lcnt[i] = 0;
    __syncthreads();
    for(int p=t; p<m; p+=512){
        int nib = nibOf[p];
        int slot = pfx[nib] + atomicAdd(&lcnt[nib], 1);
        perm[slot] = (unsigned short)p;
    }
    __syncthreads();
    for(int s=t; s<m; s+=512){
        size_t q = (size_t)3*(base + (int)perm[s]);
        unsigned w0 = recD[q], w1 = recD[q+1], w2 = recD[q+2];
        float e2 = uf(w2);
        float gate = __builtin_amdgcn_rcpf(1.f + __expf(-e2));
        srcp[base+s] = (int)(w0 & 0x1FFFFu);
        epk [base+s] = make_float4(uf(w1<<16), uf(w1 & 0xffff0000u), e2, gate);
    }
}

// ---------------- fused 3-inject: 4 edges per wave (16-lane groups) ----------------
// __launch_bounds__(256,4): allow up to ~128 VGPRs so the 36 weight scalars +
// 9 accumulators + 2 in-flight records stay register-resident (R9 ran at
// VGPR=36 -> spill/reload bloat: 36 wave-instr/edge vs ~14 expected).
#define EDGE_ACC(r) { \
    float h_ = fmaf((r).z,wc1, fmaf((r).y,wb1, fmaf((r).x,wa1, bb1))); \
    a1 = fmaf(fmaxf(h_,0.f), (r).w, a1); \
    _Pragma("unroll") \
    for(int k_=0;k_<4;k_++){ \
        float h2_ = fmaf((r).z,wc2[k_], fmaf((r).y,wb2[k_], fmaf((r).x,wa2[k_], bv2[k_]))); \
        a2[k_] = fmaf(fmaxf(h2_,0.f), (r).w, a2[k_]); \
        float h3_ = fmaf((r).z,wc3[k_], fmaf((r).y,wb3[k_], fmaf((r).x,wa3[k_], bv3[k_]))); \
        a3[k_] = fmaf(fmaxf(h3_,0.f), (r).w, a3[k_]); \
    } \
    g += (r).w; }

__global__ __launch_bounds__(256,4) void kinject(const float4* __restrict__ epk, const int* __restrict__ offs,
                        const float* __restrict__ w11, const float* __restrict__ b11,
                        const float* __restrict__ w12, const float* __restrict__ b12,
                        const float* __restrict__ w13, const float* __restrict__ b13,
                        float* __restrict__ U1, float* __restrict__ U2,
                        float* __restrict__ U3, float* __restrict__ gsum){
    int gid = blockIdx.x*blockDim.x + threadIdx.x;
    int node = gid >> 6;
    if(node >= N_NODES) return;
    int lane = threadIdx.x & 63;
    int q = lane >> 4, j = lane & 15;
    float wa1=w11[j], wb1=w11[16+j], wc1=w11[32+j], bb1=b11[j];
    float wa2[4], wb2[4], wc2[4], bv2[4], wa3[4], wb3[4], wc3[4], bv3[4];
    #pragma unroll
    for(int k=0;k<4;k++){
        int c = j + 16*k;
        wa2[k]=w12[c]; wb2[k]=w12[64+c]; wc2[k]=w12[128+c]; bv2[k]=b12[c];
        wa3[k]=w13[c]; wb3[k]=w13[64+c]; wc3[k]=w13[128+c]; bv3[k]=b13[c];
    }
    int beg = offs[node], end = offs[node+1];
    float a1=0.f, g=0.f;
    float a2[4] = {0.f,0.f,0.f,0.f};
    float a3[4] = {0.f,0.f,0.f,0.f};
    int e = beg;
    int efull = beg + ((end - beg) & ~7);
    for(; e < efull; e+=8){                 // unchecked main body: full 8-edge blocks
        float4 r0 = epk[e + q];
        float4 r1 = epk[e + 4 + q];
        EDGE_ACC(r0);
        EDGE_ACC(r1);
    }
    if(e < end){                            // single masked tail
        int ee0 = e + q, ee1 = e + 4 + q;
        float4 r0 = (ee0 < end) ? epk[ee0] : make_float4(0.f,0.f,0.f,0.f);
        float4 r1 = (ee1 < end) ? epk[ee1] : make_float4(0.f,0.f,0.f,0.f);
        EDGE_ACC(r0);
        EDGE_ACC(r1);
    }
    #pragma unroll
    for(int k=0;k<4;k++){
        a2[k] += __shfl_xor(a2[k], 16); a2[k] += __shfl_xor(a2[k], 32);
        a3[k] += __shfl_xor(a3[k], 16); a3[k] += __shfl_xor(a3[k], 32);
    }
    a1 += __shfl_xor(a1, 16); a1 += __shfl_xor(a1, 32);
    g  += __shfl_xor(g, 16);  g  += __shfl_xor(g, 32);
    float v2 = (q==0) ? a2[0] : (q==1) ? a2[1] : (q==2) ? a2[2] : a2[3];
    float v3 = (q==0) ? a3[0] : (q==1) ? a3[1] : (q==2) ? a3[2] : a3[3];
    U2[(size_t)node*64 + lane] = v2;
    U3[(size_t)node*64 + lane] = v3;
    if(lane < 16) U1[node*16 + j] = a1;
    if(lane == 0) gsum[node] = g;
}

// ---------------- SAGE mean gathers ----------------
__global__ void kgather16(const float* __restrict__ h, const int* __restrict__ srcp,
                          const int* __restrict__ offs, float* __restrict__ m){
    int gid = blockIdx.x*blockDim.x + threadIdx.x;
    int node = gid >> 6;
    if(node >= N_NODES) return;
    int lane = threadIdx.x & 63;
    int q = lane >> 4, d = lane & 15;
    int beg = offs[node], end = offs[node+1];
    float acc = 0.f;
    for(int e=beg+q; e<end; e+=4) acc += h[(size_t)srcp[e]*16 + d];
    acc += __shfl_down(acc, 32);
    acc += __shfl_down(acc, 16);
    if(lane < 16){
        float c = fmaxf((float)(end-beg), 1.f);
        m[node*16 + lane] = acc / c;
    }
}

// bf16 64-dim rows; 8 edges/iter (2-deep ILP), 16-lane group per edge, uint2 per lane
__global__ void kgather64bf(const unsigned* __restrict__ hbf, const int* __restrict__ srcp,
                            const int* __restrict__ offs, float* __restrict__ m){
    int gid = blockIdx.x*blockDim.x + threadIdx.x;
    int node = gid >> 6;
    if(node >= N_NODES) return;
    int lane = threadIdx.x & 63;
    int q = lane >> 4, j = lane & 15;
    int beg = offs[node], end = offs[node+1];
    float4 acc = make_float4(0.f,0.f,0.f,0.f);
    int e = beg;
    int efull = beg + ((end - beg) & ~7);
    for(; e < efull; e+=8){
        int s0 = srcp[e + q], s1 = srcp[e + 4 + q];
        uint2 w0 = *(const uint2*)(hbf + (size_t)s0*32 + 2*j);
        uint2 w1 = *(const uint2*)(hbf + (size_t)s1*32 + 2*j);
        acc.x += uf(w0.x<<16); acc.y += uf(w0.x & 0xffff0000u);
        acc.z += uf(w0.y<<16); acc.w += uf(w0.y & 0xffff0000u);
        acc.x += uf(w1.x<<16); acc.y += uf(w1.x & 0xffff0000u);
        acc.z += uf(w1.y<<16); acc.w += uf(w1.y & 0xffff0000u);
    }
    for(; e < end; e+=4){
        int ee = e + q;
        if(ee < end){
            int s = srcp[ee];
            uint2 w = *(const uint2*)(hbf + (size_t)s*32 + 2*j);
            acc.x += uf(w.x<<16); acc.y += uf(w.x & 0xffff0000u);
            acc.z += uf(w.y<<16); acc.w += uf(w.y & 0xffff0000u);
        }
    }
    acc.x += __shfl_xor(acc.x,16); acc.x += __shfl_xor(acc.x,32);
    acc.y += __shfl_xor(acc.y,16); acc.y += __shfl_xor(acc.y,32);
    acc.z += __shfl_xor(acc.z,16); acc.z += __shfl_xor(acc.z,32);
    acc.w += __shfl_xor(acc.w,16); acc.w += __shfl_xor(acc.w,32);
    if(lane < 16){
        float inv = 1.f / fmaxf((float)(end-beg), 1.f);
        float4 o; o.x=acc.x*inv; o.y=acc.y*inv; o.z=acc.z*inv; o.w=acc.w*inv;
        *(float4*)(m + (size_t)node*64 + 4*j) = o;
    }
}

// bf16 32-dim rows (y3); 8 edges/iter (2-deep ILP), uint (2 dims) per lane
__global__ void kgather32bf(const unsigned* __restrict__ y3, const int* __restrict__ srcp,
                            const int* __restrict__ offs, float* __restrict__ m){
    int gid = blockIdx.x*blockDim.x + threadIdx.x;
    int node = gid >> 6;
    if(node >= N_NODES) return;
    int lane = threadIdx.x & 63;
    int q = lane >> 4, j = lane & 15;
    int beg = offs[node], end = offs[node+1];
    float ax=0.f, ay=0.f;
    int e = beg;
    int efull = beg + ((end - beg) & ~7);
    for(; e < efull; e+=8){
        unsigned w0 = y3[(size_t)srcp[e + q]*16 + j];
        unsigned w1 = y3[(size_t)srcp[e + 4 + q]*16 + j];
        ax += uf(w0<<16); ay += uf(w0 & 0xffff0000u);
        ax += uf(w1<<16); ay += uf(w1 & 0xffff0000u);
    }
    for(; e < end; e+=4){
        int ee = e + q;
        if(ee < end){
            unsigned w = y3[(size_t)srcp[ee]*16 + j];
            ax += uf(w<<16); ay += uf(w & 0xffff0000u);
        }
    }
    ax += __shfl_xor(ax,16); ax += __shfl_xor(ax,32);
    ay += __shfl_xor(ay,16); ay += __shfl_xor(ay,32);
    if(lane < 16){
        float inv = 1.f / fmaxf((float)(end-beg), 1.f);
        float2 o; o.x = ax*inv; o.y = ay*inv;
        *(float2*)(m + (size_t)node*32 + 2*j) = o;
    }
}

// ---------------- dense per-node kernels ----------------

// h1 = x + U1 @ w2_1 + gs * b2_1            [N,16]
__global__ __launch_bounds__(256) void kdense0(const float* __restrict__ x, const float* __restrict__ U1,
                        const float* __restrict__ gs, const float* __restrict__ w2,
                        const float* __restrict__ b2, float* __restrict__ h1){
    __shared__ float sw[256];
    int t = threadIdx.x;
    sw[t] = w2[t];
    __syncthreads();
    int idx = blockIdx.x*256 + t;
    int n = idx >> 4, j = idx & 15;
    float acc = x[idx] + gs[n]*b2[j];
    const float4* row = (const float4*)(U1 + n*16);
    #pragma unroll
    for(int i4=0;i4<4;i4++){
        float4 r = row[i4];
        acc += r.x*sw[(i4*4+0)*16 + j];
        acc += r.y*sw[(i4*4+1)*16 + j];
        acc += r.z*sw[(i4*4+2)*16 + j];
        acc += r.w*sw[(i4*4+3)*16 + j];
    }
    h1[idx] = acc;
}

// h2bf = bf16( relu(bn1(m1@wl + h1@wr + bl)) + U2@w2_2 + gs*b2_2 )   [N,64]
__global__ __launch_bounds__(256) void kdense1(const float* __restrict__ m1, const float* __restrict__ h1,
                        const float* __restrict__ U2, const float* __restrict__ gs,
                        const float* __restrict__ wl, const float* __restrict__ bl,
                        const float* __restrict__ wr,
                        const float* __restrict__ w2, const float* __restrict__ b2,
                        const float* __restrict__ bnw, const float* __restrict__ bnb,
                        unsigned* __restrict__ h2bf){
    __shared__ float4 swl[16*16];
    __shared__ float4 swr[16*16];
    __shared__ float4 sw2[64*16];
    int t = threadIdx.x;
    swl[t] = ((const float4*)wl)[t];
    swr[t] = ((const float4*)wr)[t];
    #pragma unroll
    for(int k=0;k<4;k++) sw2[t + 256*k] = ((const float4*)w2)[t + 256*k];
    __syncthreads();

    int w = t>>6, l = t&63;
    int jg = l&15, j0 = jg*4, ng = l>>4;
    int nb = blockIdx.x*64 + w*16 + ng*4;
    int nn[4];
    #pragma unroll
    for(int k=0;k<4;k++) nn[k] = (nb+k < N_NODES) ? nb+k : N_NODES-1;

    float a[4][4], b[4][4];
    float4 blv = ld4(bl + j0);
    float4 b2v = ld4(b2 + j0);
    #pragma unroll
    for(int k=0;k<4;k++){
        float g = gs[nn[k]];
        a[k][0]=blv.x; a[k][1]=blv.y; a[k][2]=blv.z; a[k][3]=blv.w;
        b[k][0]=g*b2v.x; b[k][1]=g*b2v.y; b[k][2]=g*b2v.z; b[k][3]=g*b2v.w;
    }
    #pragma unroll
    for(int i=0;i<16;i+=4){
        float4 rm[4], rh[4];
        #pragma unroll
        for(int k=0;k<4;k++){ rm[k] = ld4(m1 + nn[k]*16 + i); rh[k] = ld4(h1 + nn[k]*16 + i); }
        #pragma unroll
        for(int ii=0;ii<4;ii++){
            float4 wL = swl[(i+ii)*16 + jg];
            float4 wR = swr[(i+ii)*16 + jg];
            #pragma unroll
            for(int k=0;k<4;k++){
                float vm = fc(rm[k],ii), vh = fc(rh[k],ii);
                a[k][0] = fmaf(vm,wL.x, fmaf(vh,wR.x, a[k][0]));
                a[k][1] = fmaf(vm,wL.y, fmaf(vh,wR.y, a[k][1]));
                a[k][2] = fmaf(vm,wL.z, fmaf(vh,wR.z, a[k][2]));
                a[k][3] = fmaf(vm,wL.w, fmaf(vh,wR.w, a[k][3]));
            }
        }
    }
    #pragma unroll 4
    for(int i=0;i<64;i+=4){
        float4 ru[4];
        #pragma unroll
        for(int k=0;k<4;k++) ru[k] = ld4(U2 + (size_t)nn[k]*64 + i);
        #pragma unroll
        for(int ii=0;ii<4;ii++){
            float4 wv = sw2[(i+ii)*16 + jg];
            #pragma unroll
            for(int k=0;k<4;k++){
                float vu = fc(ru[k],ii);
                b[k][0] = fmaf(vu,wv.x,b[k][0]);
                b[k][1] = fmaf(vu,wv.y,b[k][1]);
                b[k][2] = fmaf(vu,wv.z,b[k][2]);
                b[k][3] = fmaf(vu,wv.w,b[k][3]);
            }
        }
    }
    float4 bw = ld4(bnw + j0), bb = ld4(bnb + j0);
    #pragma unroll
    for(int k=0;k<4;k++){
        if(nb+k < N_NODES){
            float ox = fmaxf(a[k][0]*(bw.x*BN_RSQRT)+bb.x,0.f) + b[k][0];
            float oy = fmaxf(a[k][1]*(bw.y*BN_RSQRT)+bb.y,0.f) + b[k][1];
            float oz = fmaxf(a[k][2]*(bw.z*BN_RSQRT)+bb.z,0.f) + b[k][2];
            float ow = fmaxf(a[k][3]*(bw.w*BN_RSQRT)+bb.w,0.f) + b[k][3];
            uint2 pk; pk.x = f2bf(ox) | (f2bf(oy)<<16); pk.y = f2bf(oz) | (f2bf(ow)<<16);
            *(uint2*)(h2bf + (size_t)(nb+k)*32 + (j0>>1)) = pk;
        }
    }
}

// h3bf = bf16( relu(bn2(m2@wl + h2@wr + bl)) + U3@w2_3 + gs*b2_3 )   [N,64]
// + fused epilogue: y3 = bf16( h3 @ wl3 )  [N,32]  (was kproj3)
__global__ __launch_bounds__(256) void kdense2(const float* __restrict__ m2, const unsigned* __restrict__ h2bf,
                        const float* __restrict__ U3, const float* __restrict__ gs,
                        const float* __restrict__ wl, const float* __restrict__ bl,
                        const float* __restrict__ wr,
                        const float* __restrict__ w2, const float* __restrict__ b2,
                        const float* __restrict__ bnw, const float* __restrict__ bnb,
                        const float* __restrict__ wl3,
                        unsigned* __restrict__ h3bf, unsigned* __restrict__ y3){
    __shared__ float4 swl[64*16];
    __shared__ float4 swr[64*16];
    __shared__ float4 sw2[64*16];
    __shared__ float4 swl3[64*8];        // 64x32 wl3
    __shared__ unsigned sh3[64*32];      // this block's h3 tile, bf16-packed
    int t = threadIdx.x;
    #pragma unroll
    for(int k=0;k<4;k++){
        swl[t + 256*k] = ((const float4*)wl)[t + 256*k];
        swr[t + 256*k] = ((const float4*)wr)[t + 256*k];
        sw2[t + 256*k] = ((const float4*)w2)[t + 256*k];
    }
    swl3[t] = ((const float4*)wl3)[t];
    swl3[t+256] = ((const float4*)wl3)[t+256];
    __syncthreads();

    int w = t>>6, l = t&63;
    int jg = l&15, j0 = jg*4, ng = l>>4;
    int ln0 = w*16 + ng*4;               // local node base within block tile
    int nb = blockIdx.x*64 + ln0;
    int nn[4];
    #pragma unroll
    for(int k=0;k<4;k++) nn[k] = (nb+k < N_NODES) ? nb+k : N_NODES-1;

    float a[4][4], b[4][4];
    float4 blv = ld4(bl + j0);
    float4 b2v = ld4(b2 + j0);
    #pragma unroll
    for(int k=0;k<4;k++){
        float g = gs[nn[k]];
        a[k][0]=blv.x; a[k][1]=blv.y; a[k][2]=blv.z; a[k][3]=blv.w;
        b[k][0]=g*b2v.x; b[k][1]=g*b2v.y; b[k][2]=g*b2v.z; b[k][3]=g*b2v.w;
    }
    #pragma unroll 4
    for(int i=0;i<64;i+=4){
        float4 rm[4], rh[4];
        #pragma unroll
        for(int k=0;k<4;k++){
            rm[k] = ld4(m2 + (size_t)nn[k]*64 + i);
            uint2 hw = *(const uint2*)(h2bf + (size_t)nn[k]*32 + (i>>1));
            rh[k].x = uf(hw.x<<16); rh[k].y = uf(hw.x & 0xffff0000u);
            rh[k].z = uf(hw.y<<16); rh[k].w = uf(hw.y & 0xffff0000u);
        }
        #pragma unroll
        for(int ii=0;ii<4;ii++){
            float4 wL = swl[(i+ii)*16 + jg];
            float4 wR = swr[(i+ii)*16 + jg];
            #pragma unroll
            for(int k=0;k<4;k++){
                float vm = fc(rm[k],ii), vh = fc(rh[k],ii);
                a[k][0] = fmaf(vm,wL.x, fmaf(vh,wR.x, a[k][0]));
                a[k][1] = fmaf(vm,wL.y, fmaf(vh,wR.y, a[k][1]));
                a[k][2] = fmaf(vm,wL.z, fmaf(vh,wR.z, a[k][2]));
                a[k][3] = fmaf(vm,wL.w, fmaf(vh,wR.w, a[k][3]));
            }
        }
    }
    #pragma unroll 4
    for(int i=0;i<64;i+=4){
        float4 ru[4];
        #pragma unroll
        for(int k=0;k<4;k++) ru[k] = ld4(U3 + (size_t)nn[k]*64 + i);
        #pragma unroll
        for(int ii=0;ii<4;ii++){
            float4 wv = sw2[(i+ii)*16 + jg];
            #pragma unroll
            for(int k=0;k<4;k++){
                float vu = fc(ru[k],ii);
                b[k][0] = fmaf(vu,wv.x,b[k][0]);
                b[k][1] = fmaf(vu,wv.y,b[k][1]);
                b[k][2] = fmaf(vu,wv.z,b[k][2]);
                b[k][3] = fmaf(vu,wv.w,b[k][3]);
            }
        }
    }
    float4 bw = ld4(bnw + j0), bb = ld4(bnb + j0);
    #pragma unroll
    for(int k=0;k<4;k++){
        float ox = fmaxf(a[k][0]*(bw.x*BN_RSQRT)+bb.x,0.f) + b[k][0];
        float oy = fmaxf(a[k][1]*(bw.y*BN_RSQRT)+bb.y,0.f) + b[k][1];
        float oz = fmaxf(a[k][2]*(bw.z*BN_RSQRT)+bb.z,0.f) + b[k][2];
        float ow = fmaxf(a[k][3]*(bw.w*BN_RSQRT)+bb.w,0.f) + b[k][3];
        uint2 pk; pk.x = f2bf(ox) | (f2bf(oy)<<16); pk.y = f2bf(oz) | (f2bf(ow)<<16);
        *(uint2*)(sh3 + (ln0+k)*32 + (j0>>1)) = pk;               // LDS tile (always)
        if(nb+k < N_NODES)
            *(uint2*)(h3bf + (size_t)(nb+k)*32 + (j0>>1)) = pk;   // global
    }
    __syncthreads();
    // y3 phase: 4 threads/node, 8 cols each
    int nl = t >> 2, jc = t & 3;
    int gnode = blockIdx.x*64 + nl;
    if(gnode < N_NODES){
        float y[8] = {0.f,0.f,0.f,0.f,0.f,0.f,0.f,0.f};
        #pragma unroll 8
        for(int i2=0; i2<32; ++i2){
            unsigned hw = sh3[nl*32 + i2];
            float h0 = uf(hw<<16), h1 = uf(hw & 0xffff0000u);
            float4 A0 = swl3[(2*i2)*8 + jc*2];
            float4 A1 = swl3[(2*i2)*8 + jc*2 + 1];
            float4 B0 = swl3[(2*i2+1)*8 + jc*2];
            float4 B1 = swl3[(2*i2+1)*8 + jc*2 + 1];
            y[0] = fmaf(h0,A0.x, fmaf(h1,B0.x, y[0]));
            y[1] = fmaf(h0,A0.y, fmaf(h1,B0.y, y[1]));
            y[2] = fmaf(h0,A0.z, fmaf(h1,B0.z, y[2]));
            y[3] = fmaf(h0,A0.w, fmaf(h1,B0.w, y[3]));
            y[4] = fmaf(h0,A1.x, fmaf(h1,B1.x, y[4]));
            y[5] = fmaf(h0,A1.y, fmaf(h1,B1.y, y[5]));
            y[6] = fmaf(h0,A1.z, fmaf(h1,B1.z, y[6]));
            y[7] = fmaf(h0,A1.w, fmaf(h1,B1.w, y[7]));
        }
        uint4 pk;
        pk.x = f2bf(y[0]) | (f2bf(y[1])<<16);
        pk.y = f2bf(y[2]) | (f2bf(y[3])<<16);
        pk.z = f2bf(y[4]) | (f2bf(y[5])<<16);
        pk.w = f2bf(y[6]) | (f2bf(y[7])<<16);
        *(uint4*)(y3 + (size_t)gnode*16 + jc*4) = pk;
    }
}

// out = relu(bn3(m3p + h3@wr + bl))        [N,32]; m3p already includes the @wl projection
__global__ __launch_bounds__(256) void kdense3(const float* __restrict__ m3p, const unsigned* __restrict__ h3bf,
                        const float* __restrict__ bl,
                        const float* __restrict__ wr,
                        const float* __restrict__ bnw, const float* __restrict__ bnb,
                        float* __restrict__ out){
    __shared__ float4 swr[64*8];
    int t = threadIdx.x;
    #pragma unroll
    for(int k=0;k<2;k++) swr[t + 256*k] = ((const float4*)wr)[t + 256*k];
    __syncthreads();

    int w = t>>6, l = t&63;
    int jg = l&7, j0 = jg*4, ng = l>>3;
    int nb = blockIdx.x*128 + w*32 + ng*4;
    int nn[4];
    #pragma unroll
    for(int k=0;k<4;k++) nn[k] = (nb+k < N_NODES) ? nb+k : N_NODES-1;

    float a[4][4];
    float4 blv = ld4(bl + j0);
    #pragma unroll
    for(int k=0;k<4;k++){
        float4 mp = ld4(m3p + (size_t)nn[k]*32 + j0);
        a[k][0]=blv.x+mp.x; a[k][1]=blv.y+mp.y; a[k][2]=blv.z+mp.z; a[k][3]=blv.w+mp.w;
    }
    #pragma unroll 4
    for(int i=0;i<64;i+=4){
        float4 rh[4];
        #pragma unroll
        for(int k=0;k<4;k++){
            uint2 hw = *(const uint2*)(h3bf + (size_t)nn[k]*32 + (i>>1));
            rh[k].x = uf(hw.x<<16); rh[k].y = uf(hw.x & 0xffff0000u);
            rh[k].z = uf(hw.y<<16); rh[k].w = uf(hw.y & 0xffff0000u);
        }
        #pragma unroll
        for(int ii=0;ii<4;ii++){
            float4 wR = swr[(i+ii)*8 + jg];
            #pragma unroll
            for(int k=0;k<4;k++){
                float vh = fc(rh[k],ii);
                a[k][0] = fmaf(vh,wR.x,a[k][0]);
                a[k][1] = fmaf(vh,wR.y,a[k][1]);
                a[k][2] = fmaf(vh,wR.z,a[k][2]);
                a[k][3] = fmaf(vh,wR.w,a[k][3]);
            }
        }
    }
    float4 bw = ld4(bnw + j0), bb = ld4(bnb + j0);
    #pragma unroll
    for(int k=0;k<4;k++){
        if(nb+k < N_NODES){
            float4 o;
            o.x = fmaxf(a[k][0]*(bw.x*BN_RSQRT)+bb.x,0.f);
            o.y = fmaxf(a[k][1]*(bw.y*BN_RSQRT)+bb.y,0.f);
            o.z = fmaxf(a[k][2]*(bw.z*BN_RSQRT)+bb.z,0.f);
            o.w = fmaxf(a[k][3]*(bw.w*BN_RSQRT)+bb.w,0.f);
            *(float4*)(out + (size_t)(nb+k)*32 + j0) = o;
        }
    }
}

// ---------------- launch ----------------
extern "C" void kernel_launch(void* const* d_in, const int* in_sizes, int n_in,
                              void* d_out, int out_size, void* d_ws, size_t ws_size,
                              hipStream_t stream){
    const float* x    = (const float*)d_in[0];
    const int*   ei   = (const int*)  d_in[1];
    const float* ea   = (const float*)d_in[2];
    const float* i1w1 = (const float*)d_in[3];
    const float* i1b1 = (const float*)d_in[4];
    const float* i1w2 = (const float*)d_in[5];
    const float* i1b2 = (const float*)d_in[6];
    const float* i2w1 = (const float*)d_in[7];
    const float* i2b1 = (const float*)d_in[8];
    const float* i2w2 = (const float*)d_in[9];
    const float* i2b2 = (const float*)d_in[10];
    const float* i3w1 = (const float*)d_in[11];
    const float* i3b1 = (const float*)d_in[12];
    const float* i3w2 = (const float*)d_in[13];
    const float* i3b2 = (const float*)d_in[14];
    const float* c1wl = (const float*)d_in[15];
    const float* c1bl = (const float*)d_in[16];
    const float* c1wr = (const float*)d_in[17];
    const float* c2wl = (const float*)d_in[18];
    const float* c2bl = (const float*)d_in[19];
    const float* c2wr = (const float*)d_in[20];
    const float* c3wl = (const float*)d_in[21];
    const float* c3bl = (const float*)d_in[22];
    const float* c3wr = (const float*)d_in[23];
    const float* bn1w = (const float*)d_in[24];
    const float* bn1b = (const float*)d_in[25];
    const float* bn2w = (const float*)d_in[26];
    const float* bn2b = (const float*)d_in[27];
    const float* bn3w = (const float*)d_in[28];
    const float* bn3b = (const float*)d_in[29];

    char* ws = (char*)d_ws;
    int*      bcnt = (int*)     (ws + o_bcnt);
    int*      bst  = (int*)     (ws + o_bst);
    int*      gb   = (int*)     (ws + o_gb);
    int*      offs = (int*)     (ws + o_off);
    int*      srcp = (int*)     (ws + o_srcp);
    float4*   epk  = (float4*)  (ws + o_epk);
    unsigned* recD = (unsigned*)(ws + o_rec);
    float*    U1   = (float*)   (ws + o_U1);
    float*    U2   = (float*)   (ws + o_U2);
    float*    U3   = (float*)   (ws + o_U3);
    float*    gs   = (float*)   (ws + o_gs);
    float*    h1   = (float*)   (ws + o_h1);
    float*    m1   = (float*)   (ws + o_m1);
    unsigned* h2bf = (unsigned*)(ws + o_h2bf);
    unsigned* h3bf = (unsigned*)(ws + o_h3bf);
    float*    m2   = (float*)   (ws + o_m2);
    unsigned* y3   = (unsigned*)(ws + o_y3);
    float*    m3p  = (float*)   (ws + o_m3p);

    const int* src = ei;              // edge_index[0]
    const int* dst = ei + N_EDGES;    // edge_index[1]

    // bin counts -> bin starts
    hipMemsetAsync(bcnt, 0, 512*4, stream);
    khistBin <<<NHCHUNK, 256, 0, stream>>>(dst, bcnt);
    kscanBin <<<1,       512, 0, stream>>>(bcnt, bst, gb);
    // two-pass LDS-staged counting sort (dense writes); kbinB also emits the CSR offs
    kbinA  <<<NCHUNK, 256, 0, stream>>>(src, dst, ea, gb, recD);
    kbinB  <<<NB,     512, 0, stream>>>(recD, bst, offs, srcp, epk);

    // fused 3x inject edge accumulation (4 edges/wave)
    kinject <<<N_NODES/4, 256, 0, stream>>>(epk, offs,
                                            i1w1, i1b1, i2w1, i2b1, i3w1, i3b1,
                                            U1, U2, U3, gs);
    // layer 1
    kdense0 <<<N_NODES*16/256, 256, 0, stream>>>(x, U1, gs, i1w2, i1b2, h1);
    kgather16<<<N_NODES/4, 256, 0, stream>>>(h1, srcp, offs, m1);
    kdense1 <<<(N_NODES+63)/64, 256, 0, stream>>>(m1, h1, U2, gs,
                                                 c1wl, c1bl, c1wr, i2w2, i2b2,
                                                 bn1w, bn1b, h2bf);
    // layer 2
    kgather64bf<<<N_NODES/4, 256, 0, stream>>>(h2bf, srcp, offs, m2);
    kdense2 <<<(N_NODES+63)/64, 256, 0, stream>>>(m2, h2bf, U3, gs,
                                                 c2wl, c2bl, c2wr, i3w2, i3b2,
                                                 bn2w, bn2b, c3wl, h3bf, y3);
    // layer 3: gather pre-projected 32-dim rows, then finish
    kgather32bf<<<N_NODES/4, 256, 0, stream>>>(y3, srcp, offs, m3p);
    kdense3 <<<(N_NODES+127)/128, 256, 0, stream>>>(m3p, h3bf, c3bl, c3wr,
                                                 bn3w, bn3b, (float*)d_out);
}

// Round 11
// 685.067 us; speedup vs baseline: 1.8365x; 1.0008x over previous
//
#include <hip/hip_runtime.h>
#include <math.h>

#define N_NODES 100000
#define N_EDGES 3200000
#define NB 391         // bins of 256 nodes: ceil(100000/256)
#define CHUNK 4096
#define NCHUNK 782     // ceil(3200000/4096)
#define HCHUNK 4096
#define NHCHUNK 782
#define CAPB 10240     // pass-B perm capacity (mean 8184, sigma ~90)
#define NPW 8          // kinject: nodes per wave
#define NWAVES ((N_NODES + NPW - 1)/NPW)   // 12500
#define NBLK_INJ ((NWAVES + 3)/4)          // 3125 blocks of 4 waves

// ---------------- workspace layout ----------------
constexpr size_t al512(size_t x){ return (x + 511) & ~size_t(511); }
constexpr size_t o_bcnt = 0;                                          // int[512] per-bin counts
constexpr size_t o_bst  = al512(o_bcnt + 512*4);                      // int[512] bin starts
constexpr size_t o_gb   = al512(o_bst  + 512*4);                      // int[512] per-bin reservation ptrs
constexpr size_t o_off  = al512(o_gb   + 512*4);                      // int[N+1] CSR offsets (written by kbinB)
constexpr size_t o_srcp = al512(o_off  + ((size_t)N_NODES+1)*4);      // int[E] src permuted by dst
constexpr size_t o_epk  = al512(o_srcp + (size_t)N_EDGES*4);          // float4[E] {e0,e1,e2,gate}; DEAD after kinject
constexpr size_t o_U1   = al512(o_epk  + (size_t)N_EDGES*16);         // f[N*16]; DEAD after kdense0
constexpr size_t o_U2   = al512(o_U1   + (size_t)N_NODES*16*4);       // f[N*64]
constexpr size_t o_U3   = o_U2 + (size_t)N_NODES*64*4;                // f[N*64]
constexpr size_t o_gs   = al512(o_U3   + (size_t)N_NODES*64*4);       // f[N] gate sums
constexpr size_t o_h1   = al512(o_gs   + (size_t)N_NODES*4);          // f[N*16]
constexpr size_t o_m1   = al512(o_h1   + (size_t)N_NODES*16*4);       // f[N*16]
// aliases into dead regions (sequential-stream liveness):
constexpr size_t o_rec  = o_U2;    // dword[3E] staged records (38.4 MB < U2+U3 51.2 MB); dead before kinject writes U2/U3
constexpr size_t o_h2bf = o_epk;                              // bf16 h2 rows (12.8 MB); epk dead after kinject
constexpr size_t o_h3bf = o_epk + (size_t)N_NODES*128;        // bf16 h3 rows (12.8 MB)
constexpr size_t o_m2   = o_U2;    // f32 [N,64]; U2 dead after kdense1
constexpr size_t o_y3   = o_U1;    // bf16 [N,32] (6.4 MB = U1 exactly); U1 dead after kdense0; written by kdense2 epilogue
constexpr size_t o_m3p  = o_U2;    // f32 [N,32]; m2 dead after kdense2

#define BN_RSQRT 0.9999950000374997f   // 1/sqrt(1+1e-5)

__device__ __forceinline__ float4 ld4(const float* p){ return *(const float4*)p; }
__device__ __forceinline__ float fc(const float4& v, int i){ return ((const float*)&v)[i]; }
__device__ __forceinline__ float uf(unsigned u){ return __uint_as_float(u); }

// f32 -> bf16 bits, round-to-nearest-even
__device__ __forceinline__ unsigned f2bf(float x){
    unsigned u = __float_as_uint(x);
    u += 0x7fffu + ((u >> 16) & 1u);
    return u >> 16;
}

// ---------------- bin histogram (LDS-aggregated) ----------------
__global__ __launch_bounds__(256) void khistBin(const int* __restrict__ dst,
                                                int* __restrict__ binCnt){
    __shared__ int c[NB];
    int t = threadIdx.x;
    for(int i=t; i<NB; i+=256) c[i] = 0;
    __syncthreads();
    long base = (long)blockIdx.x*HCHUNK;
    int nrem = (int)(N_EDGES - base); if(nrem > HCHUNK) nrem = HCHUNK;
    for(int k=t; k<nrem; k+=256)
        atomicAdd(&c[dst[base+k] >> 8], 1);
    __syncthreads();
    for(int i=t; i<NB; i+=256)
        if(c[i]) atomicAdd(&binCnt[i], c[i]);
}

__global__ __launch_bounds__(512) void kscanBin(const int* __restrict__ binCnt,
                                                int* __restrict__ binStart,
                                                int* __restrict__ gbase){
    __shared__ int s[512];
    int t = threadIdx.x;
    int v = (t < NB) ? binCnt[t] : 0;
    s[t] = v; __syncthreads();
    for(int off=1; off<512; off<<=1){
        int a = (t>=off) ? s[t-off] : 0;
        __syncthreads(); s[t] += a; __syncthreads();
    }
    int ex = (t==0) ? 0 : s[t-1];
    if(t < NB){ binStart[t] = ex; gbase[t] = ex; }
    if(t == NB) binStart[NB] = s[NB-1];
}

// ---------------- pass A: LDS-staged binning, 12-B records ----------------
// record (3 dwords): {src | nib<<17, (e1|e0) bf16x2, e2 f32}, nib = dst & 255
__global__ __launch_bounds__(256) void kbinA(const int* __restrict__ src,
                                             const int* __restrict__ dst,
                                             const float* __restrict__ ea,
                                             int* __restrict__ gbase,
                                             unsigned* __restrict__ recD){
    __shared__ int cnt[NB], lofs[NB], gst[NB], lcnt[NB];
    __shared__ int sscan[256];
    __shared__ unsigned stage[CHUNK*3];
    __shared__ unsigned short binOf[CHUNK];
    int t = threadIdx.x;
    long e0i = (long)blockIdx.x*CHUNK;
    int nrem = (int)(N_EDGES - e0i); if(nrem > CHUNK) nrem = CHUNK;
    if(nrem <= 0) return;

    for(int b=t; b<NB; b+=256){ cnt[b]=0; lcnt[b]=0; }
    __syncthreads();
    for(int k=t; k<nrem; k+=256)
        atomicAdd(&cnt[dst[e0i+k] >> 8], 1);
    __syncthreads();
    int c0 = (2*t   < NB) ? cnt[2*t]   : 0;
    int c1 = (2*t+1 < NB) ? cnt[2*t+1] : 0;
    sscan[t] = c0 + c1;
    __syncthreads();
    for(int off=1; off<256; off<<=1){
        int v = (t>=off) ? sscan[t-off] : 0;
        __syncthreads(); sscan[t] += v; __syncthreads();
    }
    int base = (t==0) ? 0 : sscan[t-1];
    if(2*t   < NB) lofs[2*t]   = base;
    if(2*t+1 < NB) lofs[2*t+1] = base + c0;
    for(int b=t; b<NB; b+=256){
        int c = cnt[b];
        gst[b] = c ? atomicAdd(&gbase[b], c) : 0;
    }
    __syncthreads();
    for(int k=t; k<nrem; k+=256){
        long i = e0i + k;
        int d = dst[i];
        int s = src[i];
        float a0 = ea[i*3+0], a1 = ea[i*3+1], a2 = ea[i*3+2];
        int b = d >> 8;
        int p = lofs[b] + atomicAdd(&lcnt[b], 1);
        stage[3*p+0] = (unsigned)s | ((unsigned)(d & 255) << 17);
        stage[3*p+1] = (f2bf(a1)<<16) | f2bf(a0);
        stage[3*p+2] = __float_as_uint(a2);
        binOf[p] = (unsigned short)b;
    }
    __syncthreads();
    int total3 = nrem*3;
    for(int q=t; q<total3; q+=256){
        int p = q/3;
        int r = q - 3*p;
        int b = binOf[p];
        int g = gst[b] + (p - lofs[b]);
        recD[(size_t)3*g + r] = stage[q];
    }
}

// ---------------- pass B: per-bucket CSR-slice build + perm sort + gate precompute ----------------
__global__ __launch_bounds__(512) void kbinB(const unsigned* __restrict__ recD,
                                             const int* __restrict__ binStart,
                                             int* __restrict__ offs,
                                             int* __restrict__ srcp,
                                             float4* __restrict__ epk){
    __shared__ int pfx[257], lcnt[256];
    __shared__ int sscan[256];
    __shared__ unsigned short perm[CAPB];
    __shared__ unsigned char  nibOf[CAPB];
    int t = threadIdx.x;
    int b = blockIdx.x;
    int n0 = b*256;
    int nn = N_NODES - n0; if(nn > 256) nn = 256;
    int base = binStart[b];
    int m    = binStart[b+1] - base;
    for(int i=t; i<256; i+=512) lcnt[i] = 0;
    __syncthreads();
    for(int p=t; p<m; p+=512){
        unsigned w0 = recD[(size_t)3*(base+p)];
        int nib = (int)((w0 >> 17) & 255u);
        if(p < CAPB) nibOf[p] = (unsigned char)nib;
        atomicAdd(&lcnt[nib], 1);
    }
    __syncthreads();
    if(t < 256) sscan[t] = lcnt[t];
    __syncthreads();
    if(t < 256){
        for(int off=1; off<256; off<<=1){
            int v = (t>=off) ? sscan[t-off] : 0;
            __syncthreads(); sscan[t] += v; __syncthreads();
        }
        pfx[t+1] = sscan[t];
        if(t==0) pfx[0] = 0;
    } else {
        for(int off=1; off<256; off<<=1){ __syncthreads(); __syncthreads(); }
    }
    __syncthreads();
    for(int i=t; i<=nn; i+=512) offs[n0+i] = base + pfx[i];
    for(int i=t; i<256; i+=512) lcnt[i] = 0;
    __syncthreads();
    for(int p=t; p<m; p+=512){
        int nib = nibOf[p];
        int slot = pfx[nib] + atomicAdd(&lcnt[nib], 1);
        perm[slot] = (unsigned short)p;
    }
    __syncthreads();
    for(int s=t; s<m; s+=512){
        size_t q = (size_t)3*(base + (int)perm[s]);
        unsigned w0 = recD[q], w1 = recD[q+1], w2 = recD[q+2];
        float e2 = uf(w2);
        float gate = __builtin_amdgcn_rcpf(1.f + __expf(-e2));
        srcp[base+s] = (int)(w0 & 0x1FFFFu);
        epk [base+s] = make_float4(uf(w1<<16), uf(w1 & 0xffff0000u), e2, gate);
    }
}

// ---------------- fused 3-inject: 2 edges per wave (32-lane groups), 8 nodes per wave ----------------
// Each lane holds only 20 weight scalars (inj1 col j&15; inj2/inj3 cols j and j+32)
// so the live set fits the allocator's budget; weight loads amortize over NPW nodes.
#define ACC2(r) { \
    float h1_ = fmaf((r).z,wc1, fmaf((r).y,wb1, fmaf((r).x,wa1, bb1))); \
    a1 = fmaf(fmaxf(h1_,0.f), (r).w, a1); \
    float h2a_ = fmaf((r).z,wc2a, fmaf((r).y,wb2a, fmaf((r).x,wa2a, bv2a))); \
    a2a = fmaf(fmaxf(h2a_,0.f), (r).w, a2a); \
    float h2b_ = fmaf((r).z,wc2b, fmaf((r).y,wb2b, fmaf((r).x,wa2b, bv2b))); \
    a2b = fmaf(fmaxf(h2b_,0.f), (r).w, a2b); \
    float h3a_ = fmaf((r).z,wc3a, fmaf((r).y,wb3a, fmaf((r).x,wa3a, bv3a))); \
    a3a = fmaf(fmaxf(h3a_,0.f), (r).w, a3a); \
    float h3b_ = fmaf((r).z,wc3b, fmaf((r).y,wb3b, fmaf((r).x,wa3b, bv3b))); \
    a3b = fmaf(fmaxf(h3b_,0.f), (r).w, a3b); \
    g += (r).w; }

__global__ __launch_bounds__(256) void kinject(const float4* __restrict__ epk, const int* __restrict__ offs,
                        const float* __restrict__ w11, const float* __restrict__ b11,
                        const float* __restrict__ w12, const float* __restrict__ b12,
                        const float* __restrict__ w13, const float* __restrict__ b13,
                        float* __restrict__ U1, float* __restrict__ U2,
                        float* __restrict__ U3, float* __restrict__ gsum){
    int wid = (blockIdx.x*256 + threadIdx.x) >> 6;
    int n0 = wid * NPW;
    if(n0 >= N_NODES) return;
    int n1 = n0 + NPW; if(n1 > N_NODES) n1 = N_NODES;
    int lane = threadIdx.x & 63;
    int half = lane >> 5, j = lane & 31, j16 = lane & 15;
    // 20 weight scalars per lane
    float wa1=w11[j16], wb1=w11[16+j16], wc1=w11[32+j16], bb1=b11[j16];
    float wa2a=w12[j],    wb2a=w12[64+j],  wc2a=w12[128+j],  bv2a=b12[j];
    float wa2b=w12[32+j], wb2b=w12[96+j],  wc2b=w12[160+j],  bv2b=b12[32+j];
    float wa3a=w13[j],    wb3a=w13[64+j],  wc3a=w13[128+j],  bv3a=b13[j];
    float wa3b=w13[32+j], wb3b=w13[96+j],  wc3b=w13[160+j],  bv3b=b13[32+j];

    for(int node=n0; node<n1; ++node){
        int beg = offs[node], end = offs[node+1];
        float a1=0.f, a2a=0.f, a2b=0.f, a3a=0.f, a3b=0.f, g=0.f;
        int e = beg;
        int efull = beg + ((end - beg) & ~3);
        for(; e < efull; e+=4){             // unchecked main body: full 4-edge blocks
            float4 r0 = epk[e + half];
            float4 r1 = epk[e + 2 + half];
            ACC2(r0);
            ACC2(r1);
        }
        if(e < end){                        // single masked tail
            int ee0 = e + half, ee1 = e + 2 + half;
            float4 r0 = (ee0 < end) ? epk[ee0] : make_float4(0.f,0.f,0.f,0.f);
            float4 r1 = (ee1 < end) ? epk[ee1] : make_float4(0.f,0.f,0.f,0.f);
            ACC2(r0);
            ACC2(r1);
        }
        // combine the two 32-lane groups
        a2a += __shfl_xor(a2a, 32); a2b += __shfl_xor(a2b, 32);
        a3a += __shfl_xor(a3a, 32); a3b += __shfl_xor(a3b, 32);
        a1  += __shfl_xor(a1, 16);  a1  += __shfl_xor(a1, 32);
        g   += __shfl_xor(g, 32);
        float v2 = half ? a2b : a2a;
        float v3 = half ? a3b : a3a;
        int col = j + 32*half;
        U2[(size_t)node*64 + col] = v2;
        U3[(size_t)node*64 + col] = v3;
        if(lane < 16) U1[node*16 + j16] = a1;
        if(lane == 0) gsum[node] = g;
    }
}

// ---------------- SAGE mean gathers ----------------
__global__ void kgather16(const float* __restrict__ h, const int* __restrict__ srcp,
                          const int* __restrict__ offs, float* __restrict__ m){
    int gid = blockIdx.x*blockDim.x + threadIdx.x;
    int node = gid >> 6;
    if(node >= N_NODES) return;
    int lane = threadIdx.x & 63;
    int q = lane >> 4, d = lane & 15;
    int beg = offs[node], end = offs[node+1];
    float acc = 0.f;
    for(int e=beg+q; e<end; e+=4) acc += h[(size_t)srcp[e]*16 + d];
    acc += __shfl_down(acc, 32);
    acc += __shfl_down(acc, 16);
    if(lane < 16){
        float c = fmaxf((float)(end-beg), 1.f);
        m[node*16 + lane] = acc / c;
    }
}

// bf16 64-dim rows; 8 edges/iter (2-deep ILP), 16-lane group per edge, uint2 per lane
__global__ void kgather64bf(const unsigned* __restrict__ hbf, const int* __restrict__ srcp,
                            const int* __restrict__ offs, float* __restrict__ m){
    int gid = blockIdx.x*blockDim.x + threadIdx.x;
    int node = gid >> 6;
    if(node >= N_NODES) return;
    int lane = threadIdx.x & 63;
    int q = lane >> 4, j = lane & 15;
    int beg = offs[node], end = offs[node+1];
    float4 acc = make_float4(0.f,0.f,0.f,0.f);
    int e = beg;
    int efull = beg + ((end - beg) & ~7);
    for(; e < efull; e+=8){
        int s0 = srcp[e + q], s1 = srcp[e + 4 + q];
        uint2 w0 = *(const uint2*)(hbf + (size_t)s0*32 + 2*j);
        uint2 w1 = *(const uint2*)(hbf + (size_t)s1*32 + 2*j);
        acc.x += uf(w0.x<<16); acc.y += uf(w0.x & 0xffff0000u);
        acc.z += uf(w0.y<<16); acc.w += uf(w0.y & 0xffff0000u);
        acc.x += uf(w1.x<<16); acc.y += uf(w1.x & 0xffff0000u);
        acc.z += uf(w1.y<<16); acc.w += uf(w1.y & 0xffff0000u);
    }
    for(; e < end; e+=4){
        int ee = e + q;
        if(ee < end){
            int s = srcp[ee];
            uint2 w = *(const uint2*)(hbf + (size_t)s*32 + 2*j);
            acc.x += uf(w.x<<16); acc.y += uf(w.x & 0xffff0000u);
            acc.z += uf(w.y<<16); acc.w += uf(w.y & 0xffff0000u);
        }
    }
    acc.x += __shfl_xor(acc.x,16); acc.x += __shfl_xor(acc.x,32);
    acc.y += __shfl_xor(acc.y,16); acc.y += __shfl_xor(acc.y,32);
    acc.z += __shfl_xor(acc.z,16); acc.z += __shfl_xor(acc.z,32);
    acc.w += __shfl_xor(acc.w,16); acc.w += __shfl_xor(acc.w,32);
    if(lane < 16){
        float inv = 1.f / fmaxf((float)(end-beg), 1.f);
        float4 o; o.x=acc.x*inv; o.y=acc.y*inv; o.z=acc.z*inv; o.w=acc.w*inv;
        *(float4*)(m + (size_t)node*64 + 4*j) = o;
    }
}

// bf16 32-dim rows (y3); 8 edges/iter (2-deep ILP), uint (2 dims) per lane
__global__ void kgather32bf(const unsigned* __restrict__ y3, const int* __restrict__ srcp,
                            const int* __restrict__ offs, float* __restrict__ m){
    int gid = blockIdx.x*blockDim.x + threadIdx.x;
    int node = gid >> 6;
    if(node >= N_NODES) return;
    int lane = threadIdx.x & 63;
    int q = lane >> 4, j = lane & 15;
    int beg = offs[node], end = offs[node+1];
    float ax=0.f, ay=0.f;
    int e = beg;
    int efull = beg + ((end - beg) & ~7);
    for(; e < efull; e+=8){
        unsigned w0 = y3[(size_t)srcp[e + q]*16 + j];
        unsigned w1 = y3[(size_t)srcp[e + 4 + q]*16 + j];
        ax += uf(w0<<16); ay += uf(w0 & 0xffff0000u);
        ax += uf(w1<<16); ay += uf(w1 & 0xffff0000u);
    }
    for(; e < end; e+=4){
        int ee = e + q;
        if(ee < end){
            unsigned w = y3[(size_t)srcp[ee]*16 + j];
            ax += uf(w<<16); ay += uf(w & 0xffff0000u);
        }
    }
    ax += __shfl_xor(ax,16); ax += __shfl_xor(ax,32);
    ay += __shfl_xor(ay,16); ay += __shfl_xor(ay,32);
    if(lane < 16){
        float inv = 1.f / fmaxf((float)(end-beg), 1.f);
        float2 o; o.x = ax*inv; o.y = ay*inv;
        *(float2*)(m + (size_t)node*32 + 2*j) = o;
    }
}

// ---------------- dense per-node kernels ----------------

// h1 = x + U1 @ w2_1 + gs * b2_1            [N,16]
__global__ __launch_bounds__(256) void kdense0(const float* __restrict__ x, const float* __restrict__ U1,
                        const float* __restrict__ gs, const float* __restrict__ w2,
                        const float* __restrict__ b2, float* __restrict__ h1){
    __shared__ float sw[256];
    int t = threadIdx.x;
    sw[t] = w2[t];
    __syncthreads();
    int idx = blockIdx.x*256 + t;
    int n = idx >> 4, j = idx & 15;
    float acc = x[idx] + gs[n]*b2[j];
    const float4* row = (const float4*)(U1 + n*16);
    #pragma unroll
    for(int i4=0;i4<4;i4++){
        float4 r = row[i4];
        acc += r.x*sw[(i4*4+0)*16 + j];
        acc += r.y*sw[(i4*4+1)*16 + j];
        acc += r.z*sw[(i4*4+2)*16 + j];
        acc += r.w*sw[(i4*4+3)*16 + j];
    }
    h1[idx] = acc;
}

// h2bf = bf16( relu(bn1(m1@wl + h1@wr + bl)) + U2@w2_2 + gs*b2_2 )   [N,64]
__global__ __launch_bounds__(256) void kdense1(const float* __restrict__ m1, const float* __restrict__ h1,
                        const float* __restrict__ U2, const float* __restrict__ gs,
                        const float* __restrict__ wl, const float* __restrict__ bl,
                        const float* __restrict__ wr,
                        const float* __restrict__ w2, const float* __restrict__ b2,
                        const float* __restrict__ bnw, const float* __restrict__ bnb,
                        unsigned* __restrict__ h2bf){
    __shared__ float4 swl[16*16];
    __shared__ float4 swr[16*16];
    __shared__ float4 sw2[64*16];
    int t = threadIdx.x;
    swl[t] = ((const float4*)wl)[t];
    swr[t] = ((const float4*)wr)[t];
    #pragma unroll
    for(int k=0;k<4;k++) sw2[t + 256*k] = ((const float4*)w2)[t + 256*k];
    __syncthreads();

    int w = t>>6, l = t&63;
    int jg = l&15, j0 = jg*4, ng = l>>4;
    int nb = blockIdx.x*64 + w*16 + ng*4;
    int nn[4];
    #pragma unroll
    for(int k=0;k<4;k++) nn[k] = (nb+k < N_NODES) ? nb+k : N_NODES-1;

    float a[4][4], b[4][4];
    float4 blv = ld4(bl + j0);
    float4 b2v = ld4(b2 + j0);
    #pragma unroll
    for(int k=0;k<4;k++){
        float g = gs[nn[k]];
        a[k][0]=blv.x; a[k][1]=blv.y; a[k][2]=blv.z; a[k][3]=blv.w;
        b[k][0]=g*b2v.x; b[k][1]=g*b2v.y; b[k][2]=g*b2v.z; b[k][3]=g*b2v.w;
    }
    #pragma unroll
    for(int i=0;i<16;i+=4){
        float4 rm[4], rh[4];
        #pragma unroll
        for(int k=0;k<4;k++){ rm[k] = ld4(m1 + nn[k]*16 + i); rh[k] = ld4(h1 + nn[k]*16 + i); }
        #pragma unroll
        for(int ii=0;ii<4;ii++){
            float4 wL = swl[(i+ii)*16 + jg];
            float4 wR = swr[(i+ii)*16 + jg];
            #pragma unroll
            for(int k=0;k<4;k++){
                float vm = fc(rm[k],ii), vh = fc(rh[k],ii);
                a[k][0] = fmaf(vm,wL.x, fmaf(vh,wR.x, a[k][0]));
                a[k][1] = fmaf(vm,wL.y, fmaf(vh,wR.y, a[k][1]));
                a[k][2] = fmaf(vm,wL.z, fmaf(vh,wR.z, a[k][2]));
                a[k][3] = fmaf(vm,wL.w, fmaf(vh,wR.w, a[k][3]));
            }
        }
    }
    #pragma unroll 4
    for(int i=0;i<64;i+=4){
        float4 ru[4];
        #pragma unroll
        for(int k=0;k<4;k++) ru[k] = ld4(U2 + (size_t)nn[k]*64 + i);
        #pragma unroll
        for(int ii=0;ii<4;ii++){
            float4 wv = sw2[(i+ii)*16 + jg];
            #pragma unroll
            for(int k=0;k<4;k++){
                float vu = fc(ru[k],ii);
                b[k][0] = fmaf(vu,wv.x,b[k][0]);
                b[k][1] = fmaf(vu,wv.y,b[k][1]);
                b[k][2] = fmaf(vu,wv.z,b[k][2]);
                b[k][3] = fmaf(vu,wv.w,b[k][3]);
            }
        }
    }
    float4 bw = ld4(bnw + j0), bb = ld4(bnb + j0);
    #pragma unroll
    for(int k=0;k<4;k++){
        if(nb+k < N_NODES){
            float ox = fmaxf(a[k][0]*(bw.x*BN_RSQRT)+bb.x,0.f) + b[k][0];
            float oy = fmaxf(a[k][1]*(bw.y*BN_RSQRT)+bb.y,0.f) + b[k][1];
            float oz = fmaxf(a[k][2]*(bw.z*BN_RSQRT)+bb.z,0.f) + b[k][2];
            float ow = fmaxf(a[k][3]*(bw.w*BN_RSQRT)+bb.w,0.f) + b[k][3];
            uint2 pk; pk.x = f2bf(ox) | (f2bf(oy)<<16); pk.y = f2bf(oz) | (f2bf(ow)<<16);
            *(uint2*)(h2bf + (size_t)(nb+k)*32 + (j0>>1)) = pk;
        }
    }
}

// h3bf = bf16( relu(bn2(m2@wl + h2@wr + bl)) + U3@w2_3 + gs*b2_3 )   [N,64]
// + fused epilogue: y3 = bf16( h3 @ wl3 )  [N,32]
__global__ __launch_bounds__(256) void kdense2(const float* __restrict__ m2, const unsigned* __restrict__ h2bf,
                        const float* __restrict__ U3, const float* __restrict__ gs,
                        const float* __restrict__ wl, const float* __restrict__ bl,
                        const float* __restrict__ wr,
                        const float* __restrict__ w2, const float* __restrict__ b2,
                        const float* __restrict__ bnw, const float* __restrict__ bnb,
                        const float* __restrict__ wl3,
                        unsigned* __restrict__ h3bf, unsigned* __restrict__ y3){
    __shared__ float4 swl[64*16];
    __shared__ float4 swr[64*16];
    __shared__ float4 sw2[64*16];
    __shared__ float4 swl3[64*8];        // 64x32 wl3
    __shared__ unsigned sh3[64*32];      // this block's h3 tile, bf16-packed
    int t = threadIdx.x;
    #pragma unroll
    for(int k=0;k<4;k++){
        swl[t + 256*k] = ((const float4*)wl)[t + 256*k];
        swr[t + 256*k] = ((const float4*)wr)[t + 256*k];
        sw2[t + 256*k] = ((const float4*)w2)[t + 256*k];
    }
    swl3[t] = ((const float4*)wl3)[t];
    swl3[t+256] = ((const float4*)wl3)[t+256];
    __syncthreads();

    int w = t>>6, l = t&63;
    int jg = l&15, j0 = jg*4, ng = l>>4;
    int ln0 = w*16 + ng*4;
    int nb = blockIdx.x*64 + ln0;
    int nn[4];
    #pragma unroll
    for(int k=0;k<4;k++) nn[k] = (nb+k < N_NODES) ? nb+k : N_NODES-1;

    float a[4][4], b[4][4];
    float4 blv = ld4(bl + j0);
    float4 b2v = ld4(b2 + j0);
    #pragma unroll
    for(int k=0;k<4;k++){
        float g = gs[nn[k]];
        a[k][0]=blv.x; a[k][1]=blv.y; a[k][2]=blv.z; a[k][3]=blv.w;
        b[k][0]=g*b2v.x; b[k][1]=g*b2v.y; b[k][2]=g*b2v.z; b[k][3]=g*b2v.w;
    }
    #pragma unroll 4
    for(int i=0;i<64;i+=4){
        float4 rm[4], rh[4];
        #pragma unroll
        for(int k=0;k<4;k++){
            rm[k] = ld4(m2 + (size_t)nn[k]*64 + i);
            uint2 hw = *(const uint2*)(h2bf + (size_t)nn[k]*32 + (i>>1));
            rh[k].x = uf(hw.x<<16); rh[k].y = uf(hw.x & 0xffff0000u);
            rh[k].z = uf(hw.y<<16); rh[k].w = uf(hw.y & 0xffff0000u);
        }
        #pragma unroll
        for(int ii=0;ii<4;ii++){
            float4 wL = swl[(i+ii)*16 + jg];
            float4 wR = swr[(i+ii)*16 + jg];
            #pragma unroll
            for(int k=0;k<4;k++){
                float vm = fc(rm[k],ii), vh = fc(rh[k],ii);
                a[k][0] = fmaf(vm,wL.x, fmaf(vh,wR.x, a[k][0]));
                a[k][1] = fmaf(vm,wL.y, fmaf(vh,wR.y, a[k][1]));
                a[k][2] = fmaf(vm,wL.z, fmaf(vh,wR.z, a[k][2]));
                a[k][3] = fmaf(vm,wL.w, fmaf(vh,wR.w, a[k][3]));
            }
        }
    }
    #pragma unroll 4
    for(int i=0;i<64;i+=4){
        float4 ru[4];
        #pragma unroll
        for(int k=0;k<4;k++) ru[k] = ld4(U3 + (size_t)nn[k]*64 + i);
        #pragma unroll
        for(int ii=0;ii<4;ii++){
            float4 wv = sw2[(i+ii)*16 + jg];
            #pragma unroll
            for(int k=0;k<4;k++){
                float vu = fc(ru[k],ii);
                b[k][0] = fmaf(vu,wv.x,b[k][0]);
                b[k][1] = fmaf(vu,wv.y,b[k][1]);
                b[k][2] = fmaf(vu,wv.z,b[k][2]);
                b[k][3] = fmaf(vu,wv.w,b[k][3]);
            }
        }
    }
    float4 bw = ld4(bnw + j0), bb = ld4(bnb + j0);
    #pragma unroll
    for(int k=0;k<4;k++){
        float ox = fmaxf(a[k][0]*(bw.x*BN_RSQRT)+bb.x,0.f) + b[k][0];
        float oy = fmaxf(a[k][1]*(bw.y*BN_RSQRT)+bb.y,0.f) + b[k][1];
        float oz = fmaxf(a[k][2]*(bw.z*BN_RSQRT)+bb.z,0.f) + b[k][2];
        float ow = fmaxf(a[k][3]*(bw.w*BN_RSQRT)+bb.w,0.f) + b[k][3];
        uint2 pk; pk.x = f2bf(ox) | (f2bf(oy)<<16); pk.y = f2bf(oz) | (f2bf(ow)<<16);
        *(uint2*)(sh3 + (ln0+k)*32 + (j0>>1)) = pk;
        if(nb+k < N_NODES)
            *(uint2*)(h3bf + (size_t)(nb+k)*32 + (j0>>1)) = pk;
    }
    __syncthreads();
    // y3 phase: 4 threads/node, 8 cols each
    int nl = t >> 2, jc = t & 3;
    int gnode = blockIdx.x*64 + nl;
    if(gnode < N_NODES){
        float y[8] = {0.f,0.f,0.f,0.f,0.f,0.f,0.f,0.f};
        #pragma unroll 8
        for(int i2=0; i2<32; ++i2){
            unsigned hw = sh3[nl*32 + i2];
            float h0 = uf(hw<<16), h1 = uf(hw & 0xffff0000u);
            float4 A0 = swl3[(2*i2)*8 + jc*2];
            float4 A1 = swl3[(2*i2)*8 + jc*2 + 1];
            float4 B0 = swl3[(2*i2+1)*8 + jc*2];
            float4 B1 = swl3[(2*i2+1)*8 + jc*2 + 1];
            y[0] = fmaf(h0,A0.x, fmaf(h1,B0.x, y[0]));
            y[1] = fmaf(h0,A0.y, fmaf(h1,B0.y, y[1]));
            y[2] = fmaf(h0,A0.z, fmaf(h1,B0.z, y[2]));
            y[3] = fmaf(h0,A0.w, fmaf(h1,B0.w, y[3]));
            y[4] = fmaf(h0,A1.x, fmaf(h1,B1.x, y[4]));
            y[5] = fmaf(h0,A1.y, fmaf(h1,B1.y, y[5]));
            y[6] = fmaf(h0,A1.z, fmaf(h1,B1.z, y[6]));
            y[7] = fmaf(h0,A1.w, fmaf(h1,B1.w, y[7]));
        }
        uint4 pk;
        pk.x = f2bf(y[0]) | (f2bf(y[1])<<16);
        pk.y = f2bf(y[2]) | (f2bf(y[3])<<16);
        pk.z = f2bf(y[4]) | (f2bf(y[5])<<16);
        pk.w = f2bf(y[6]) | (f2bf(y[7])<<16);
        *(uint4*)(y3 + (size_t)gnode*16 + jc*4) = pk;
    }
}

// out = relu(bn3(m3p + h3@wr + bl))        [N,32]; m3p already includes the @wl projection
__global__ __launch_bounds__(256) void kdense3(const float* __restrict__ m3p, const unsigned* __restrict__ h3bf,
                        const float* __restrict__ bl,
                        const float* __restrict__ wr,
                        const float* __restrict__ bnw, const float* __restrict__ bnb,
                        float* __restrict__ out){
    __shared__ float4 swr[64*8];
    int t = threadIdx.x;
    #pragma unroll
    for(int k=0;k<2;k++) swr[t + 256*k] = ((const float4*)wr)[t + 256*k];
    __syncthreads();

    int w = t>>6, l = t&63;
    int jg = l&7, j0 = jg*4, ng = l>>3;
    int nb = blockIdx.x*128 + w*32 + ng*4;
    int nn[4];
    #pragma unroll
    for(int k=0;k<4;k++) nn[k] = (nb+k < N_NODES) ? nb+k : N_NODES-1;

    float a[4][4];
    float4 blv = ld4(bl + j0);
    #pragma unroll
    for(int k=0;k<4;k++){
        float4 mp = ld4(m3p + (size_t)nn[k]*32 + j0);
        a[k][0]=blv.x+mp.x; a[k][1]=blv.y+mp.y; a[k][2]=blv.z+mp.z; a[k][3]=blv.w+mp.w;
    }
    #pragma unroll 4
    for(int i=0;i<64;i+=4){
        float4 rh[4];
        #pragma unroll
        for(int k=0;k<4;k++){
            uint2 hw = *(const uint2*)(h3bf + (size_t)nn[k]*32 + (i>>1));
            rh[k].x = uf(hw.x<<16); rh[k].y = uf(hw.x & 0xffff0000u);
            rh[k].z = uf(hw.y<<16); rh[k].w = uf(hw.y & 0xffff0000u);
        }
        #pragma unroll
        for(int ii=0;ii<4;ii++){
            float4 wR = swr[(i+ii)*8 + jg];
            #pragma unroll
            for(int k=0;k<4;k++){
                float vh = fc(rh[k],ii);
                a[k][0] = fmaf(vh,wR.x,a[k][0]);
                a[k][1] = fmaf(vh,wR.y,a[k][1]);
                a[k][2] = fmaf(vh,wR.z,a[k][2]);
                a[k][3] = fmaf(vh,wR.w,a[k][3]);
            }
        }
    }
    float4 bw = ld4(bnw + j0), bb = ld4(bnb + j0);
    #pragma unroll
    for(int k=0;k<4;k++){
        if(nb+k < N_NODES){
            float4 o;
            o.x = fmaxf(a[k][0]*(bw.x*BN_RSQRT)+bb.x,0.f);
            o.y = fmaxf(a[k][1]*(bw.y*BN_RSQRT)+bb.y,0.f);
            o.z = fmaxf(a[k][2]*(bw.z*BN_RSQRT)+bb.z,0.f);
            o.w = fmaxf(a[k][3]*(bw.w*BN_RSQRT)+bb.w,0.f);
            *(float4*)(out + (size_t)(nb+k)*32 + j0) = o;
        }
    }
}

// ---------------- launch ----------------
extern "C" void kernel_launch(void* const* d_in, const int* in_sizes, int n_in,
                              void* d_out, int out_size, void* d_ws, size_t ws_size,
                              hipStream_t stream){
    const float* x    = (const float*)d_in[0];
    const int*   ei   = (const int*)  d_in[1];
    const float* ea   = (const float*)d_in[2];
    const float* i1w1 = (const float*)d_in[3];
    const float* i1b1 = (const float*)d_in[4];
    const float* i1w2 = (const float*)d_in[5];
    const float* i1b2 = (const float*)d_in[6];
    const float* i2w1 = (const float*)d_in[7];
    const float* i2b1 = (const float*)d_in[8];
    const float* i2w2 = (const float*)d_in[9];
    const float* i2b2 = (const float*)d_in[10];
    const float* i3w1 = (const float*)d_in[11];
    const float* i3b1 = (const float*)d_in[12];
    const float* i3w2 = (const float*)d_in[13];
    const float* i3b2 = (const float*)d_in[14];
    const float* c1wl = (const float*)d_in[15];
    const float* c1bl = (const float*)d_in[16];
    const float* c1wr = (const float*)d_in[17];
    const float* c2wl = (const float*)d_in[18];
    const float* c2bl = (const float*)d_in[19];
    const float* c2wr = (const float*)d_in[20];
    const float* c3wl = (const float*)d_in[21];
    const float* c3bl = (const float*)d_in[22];
    const float* c3wr = (const float*)d_in[23];
    const float* bn1w = (const float*)d_in[24];
    const float* bn1b = (const float*)d_in[25];
    const float* bn2w = (const float*)d_in[26];
    const float* bn2b = (const float*)d_in[27];
    const float* bn3w = (const float*)d_in[28];
    const float* bn3b = (const float*)d_in[29];

    char* ws = (char*)d_ws;
    int*      bcnt = (int*)     (ws + o_bcnt);
    int*      bst  = (int*)     (ws + o_bst);
    int*      gb   = (int*)     (ws + o_gb);
    int*      offs = (int*)     (ws + o_off);
    int*      srcp = (int*)     (ws + o_srcp);
    float4*   epk  = (float4*)  (ws + o_epk);
    unsigned* recD = (unsigned*)(ws + o_rec);
    float*    U1   = (float*)   (ws + o_U1);
    float*    U2   = (float*)   (ws + o_U2);
    float*    U3   = (float*)   (ws + o_U3);
    float*    gs   = (float*)   (ws + o_gs);
    float*    h1   = (float*)   (ws + o_h1);
    float*    m1   = (float*)   (ws + o_m1);
    unsigned* h2bf = (unsigned*)(ws + o_h2bf);
    unsigned* h3bf = (unsigned*)(ws + o_h3bf);
    float*    m2   = (float*)   (ws + o_m2);
    unsigned* y3   = (unsigned*)(ws + o_y3);
    float*    m3p  = (float*)   (ws + o_m3p);

    const int* src = ei;              // edge_index[0]
    const int* dst = ei + N_EDGES;    // edge_index[1]

    // bin counts -> bin starts
    hipMemsetAsync(bcnt, 0, 512*4, stream);
    khistBin <<<NHCHUNK, 256, 0, stream>>>(dst, bcnt);
    kscanBin <<<1,       512, 0, stream>>>(bcnt, bst, gb);
    // two-pass LDS-staged counting sort (dense writes); kbinB also emits the CSR offs
    kbinA  <<<NCHUNK, 256, 0, stream>>>(src, dst, ea, gb, recD);
    kbinB  <<<NB,     512, 0, stream>>>(recD, bst, offs, srcp, epk);

    // fused 3x inject edge accumulation (2 edges/wave, 8 nodes/wave)
    kinject <<<NBLK_INJ, 256, 0, stream>>>(epk, offs,
                                           i1w1, i1b1, i2w1, i2b1, i3w1, i3b1,
                                           U1, U2, U3, gs);
    // layer 1
    kdense0 <<<N_NODES*16/256, 256, 0, stream>>>(x, U1, gs, i1w2, i1b2, h1);
    kgather16<<<N_NODES/4, 256, 0, stream>>>(h1, srcp, offs, m1);
    kdense1 <<<(N_NODES+63)/64, 256, 0, stream>>>(m1, h1, U2, gs,
                                                 c1wl, c1bl, c1wr, i2w2, i2b2,
                                                 bn1w, bn1b, h2bf);
    // layer 2
    kgather64bf<<<N_NODES/4, 256, 0, stream>>>(h2bf, srcp, offs, m2);
    kdense2 <<<(N_NODES+63)/64, 256, 0, stream>>>(m2, h2bf, U3, gs,
                                                 c2wl, c2bl, c2wr, i3w2, i3b2,
                                                 bn2w, bn2b, c3wl, h3bf, y3);
    // layer 3: gather pre-projected 32-dim rows, then finish
    kgather32bf<<<N_NODES/4, 256, 0, stream>>>(y3, srcp, offs, m3p);
    kdense3 <<<(N_NODES+127)/128, 256, 0, stream>>>(m3p, h3bf, c3bl, c3wr,
                                                 bn3w, bn3b, (float*)d_out);
}